// Round 1
// baseline (860.982 us; speedup 1.0000x reference)
//
#include <hip/hip_runtime.h>

#define NN 50000
#define EE 400000
#define EB 450000   // EE + NN (edges incl. self-loops)
#define HID 128
#define ED 64

static __device__ __forceinline__ float wave_reduce_sum(float v) {
#pragma unroll
  for (int o = 32; o > 0; o >>= 1) v += __shfl_xor(v, o, 64);
  return v;
}

// ---------------- setup kernels ----------------

__global__ void k_zero(int* __restrict__ cnt, float* __restrict__ vnsum) {
  int t = blockIdx.x * blockDim.x + threadIdx.x;
  if (t < NN) cnt[t] = 0;
  if (t < HID) vnsum[t] = 0.f;
}

__global__ void k_count(const int* __restrict__ dst, int* __restrict__ cnt) {
  int e = blockIdx.x * blockDim.x + threadIdx.x;
  if (e < EE) atomicAdd(&cnt[dst[e]], 1);
}

// single-block exclusive scan of cnt[NN] -> off[NN+1], cursor copy
__global__ void k_scan(const int* __restrict__ cnt, int* __restrict__ off,
                       int* __restrict__ cursor) {
  const int C = 49;  // ceil(50000/1024)
  __shared__ int s[1024];
  int tid = threadIdx.x;
  int start = tid * C;
  int sum = 0;
  for (int j = 0; j < C; ++j) {
    int i = start + j;
    if (i < NN) sum += cnt[i];
  }
  s[tid] = sum;
  __syncthreads();
  for (int d = 1; d < 1024; d <<= 1) {
    int t = (tid >= d) ? s[tid - d] : 0;
    __syncthreads();
    s[tid] += t;
    __syncthreads();
  }
  int run = s[tid] - sum;  // exclusive prefix
  for (int j = 0; j < C; ++j) {
    int i = start + j;
    if (i < NN) {
      off[i] = run;
      cursor[i] = run;
      run += cnt[i];
    }
  }
  if (tid == 1023) off[NN] = s[1023];
}

__global__ void k_scatter(const int* __restrict__ dst, int* __restrict__ cursor,
                          int* __restrict__ eid) {
  int e = blockIdx.x * blockDim.x + threadIdx.x;
  if (e < EE) {
    int p = atomicAdd(&cursor[dst[e]], 1);
    eid[p] = e;
  }
}

// self-loop edge_attr = mean of incoming edge_attr; wave per node, lane = dim
__global__ __launch_bounds__(256) void k_loopattr(
    const float* __restrict__ edge_attr, const int* __restrict__ off,
    const int* __restrict__ eid, float* __restrict__ lattr) {
  int i = blockIdx.x * 4 + (threadIdx.x >> 6);
  int lane = threadIdx.x & 63;
  if (i >= NN) return;
  int s0 = off[i], s1 = off[i + 1];
  float acc = 0.f;
  for (int p = s0; p < s1; ++p) {
    int e = eid[p];
    acc += edge_attr[(size_t)e * ED + lane];
  }
  int deg = s1 - s0;
  lattr[(size_t)i * ED + lane] = acc / (float)(deg > 1 ? deg : 1);
}

// we_ae[l] = We_l @ ae_l  (64-vector per layer)
__global__ void k_weae(const float* __restrict__ We0, const float* __restrict__ We1,
                       const float* __restrict__ We2, const float* __restrict__ ae0,
                       const float* __restrict__ ae1, const float* __restrict__ ae2,
                       float* __restrict__ weae) {
  int t = threadIdx.x;
  if (t >= 192) return;
  int l = t >> 6, j = t & 63;
  const float* We = (l == 0) ? We0 : (l == 1) ? We1 : We2;
  const float* ae = (l == 0) ? ae0 : (l == 1) ? ae1 : ae2;
  float acc = 0.f;
  for (int k = 0; k < HID; ++k) acc += We[j * HID + k] * ae[k];
  weae[l * ED + j] = acc;
}

// per-edge (incl self-loop rows) scalar: esc[l][e] = ea_e . weae[l]
__global__ __launch_bounds__(256) void k_esc(
    const float* __restrict__ edge_attr, const float* __restrict__ lattr,
    const float* __restrict__ weae, float* __restrict__ esc) {
  int item = blockIdx.x * 4 + (threadIdx.x >> 6);
  int lane = threadIdx.x & 63;
  if (item >= EB) return;
  const float* base = (item < EE) ? (edge_attr + (size_t)item * ED)
                                  : (lattr + (size_t)(item - EE) * ED);
  float v = base[lane];
#pragma unroll
  for (int l = 0; l < 3; ++l) {
    float pv = wave_reduce_sum(v * weae[l * ED + lane]);
    if (lane == 0) esc[(size_t)l * EB + item] = pv;
  }
}

// ---------------- per-layer kernels ----------------

// O[NN x 128] = X[NN x 128] @ W[128 x 128] (+ bias). 32 rows per block.
__global__ __launch_bounds__(256) void k_gemm128(
    const float* __restrict__ X, const float* __restrict__ W,
    const float* __restrict__ bias, float* __restrict__ O, int use_bias) {
  __shared__ float sX[32][HID];
  __shared__ float sW[64][HID];
  int tid = threadIdx.x;
  int row0 = blockIdx.x * 32;
  {
    const float4* xs = (const float4*)(X + (size_t)row0 * HID);
    float4* xd = (float4*)(&sX[0][0]);
#pragma unroll
    for (int v = 0; v < 4; ++v) {
      int idx = tid + v * 256;       // 0..1023, 32 float4 per row
      int grow = row0 + (idx >> 5);
      xd[idx] = (grow < NN) ? xs[idx] : make_float4(0.f, 0.f, 0.f, 0.f);
    }
  }
  int colg = (tid & 31) * 4;
  int rowg = (tid >> 5) * 4;
  float acc[4][4] = {{0.f}};
  for (int kc = 0; kc < 2; ++kc) {
    __syncthreads();
    {
      const float4* wsp = (const float4*)(W + (size_t)kc * 64 * HID);
      float4* wd = (float4*)(&sW[0][0]);
#pragma unroll
      for (int v = 0; v < 8; ++v) wd[tid + v * 256] = wsp[tid + v * 256];
    }
    __syncthreads();
#pragma unroll 8
    for (int k = 0; k < 64; ++k) {
      float4 wv = *(const float4*)(&sW[k][colg]);
#pragma unroll
      for (int r = 0; r < 4; ++r) {
        float xv = sX[rowg + r][kc * 64 + k];
        acc[r][0] += xv * wv.x;
        acc[r][1] += xv * wv.y;
        acc[r][2] += xv * wv.z;
        acc[r][3] += xv * wv.w;
      }
    }
  }
#pragma unroll
  for (int r = 0; r < 4; ++r) {
    int grow = row0 + rowg + r;
    if (grow < NN) {
      float4 o;
      o.x = acc[r][0]; o.y = acc[r][1]; o.z = acc[r][2]; o.w = acc[r][3];
      if (use_bias) {
        o.x += bias[colg + 0];
        o.y += bias[colg + 1];
        o.z += bias[colg + 2];
        o.w += bias[colg + 3];
      }
      *(float4*)(O + (size_t)grow * HID + colg) = o;
    }
  }
}

// hs[i] = h[i].a_s ; hd[i] = h[i].a_d   (wave per node)
__global__ __launch_bounds__(256) void k_hsd(
    const float* __restrict__ h, const float* __restrict__ as_,
    const float* __restrict__ ad_, float* __restrict__ hs,
    float* __restrict__ hd) {
  int i = blockIdx.x * 4 + (threadIdx.x >> 6);
  int lane = threadIdx.x & 63;
  if (i >= NN) return;
  float v0 = h[(size_t)i * HID + lane];
  float v1 = h[(size_t)i * HID + 64 + lane];
  float s = wave_reduce_sum(v0 * as_[lane] + v1 * as_[64 + lane]);
  float d = wave_reduce_sum(v0 * ad_[lane] + v1 * ad_[64 + lane]);
  if (lane == 0) {
    hs[i] = s;
    hd[i] = d;
  }
}

// wave per dst node: softmax over incoming edges (+self loop), aggregate h[src]
__global__ __launch_bounds__(256) void k_aggregate(
    const float* __restrict__ h, const float* __restrict__ hs,
    const float* __restrict__ hd, const float* __restrict__ escl,
    const int* __restrict__ src, const int* __restrict__ off,
    const int* __restrict__ eid, const float* __restrict__ bias,
    float* __restrict__ out, int act) {
  int i = blockIdx.x * 4 + (threadIdx.x >> 6);
  int lane = threadIdx.x & 63;
  if (i >= NN) return;
  int s0 = off[i], s1 = off[i + 1];
  float hdi = hd[i];
  // pass 1: max alpha
  float m = -1e30f;
  for (int p = s0; p < s1; ++p) {
    int e = eid[p];
    int s = src[e];
    float a = hs[s] + hdi + escl[e];
    a = (a > 0.f) ? a : 0.2f * a;
    m = fmaxf(m, a);
  }
  float aself = hs[i] + hdi + escl[EE + i];
  aself = (aself > 0.f) ? aself : 0.2f * aself;
  m = fmaxf(m, aself);
  // pass 2: exp-sum and weighted aggregation
  float den = 0.f, acc0 = 0.f, acc1 = 0.f;
  for (int p = s0; p < s1; ++p) {
    int e = eid[p];
    int s = src[e];
    float a = hs[s] + hdi + escl[e];
    a = (a > 0.f) ? a : 0.2f * a;
    float ex = expf(a - m);
    den += ex;
    float2 hv = *(const float2*)(h + (size_t)s * HID + 2 * lane);
    acc0 += ex * hv.x;
    acc1 += ex * hv.y;
  }
  {
    float ex = expf(aself - m);
    den += ex;
    float2 hv = *(const float2*)(h + (size_t)i * HID + 2 * lane);
    acc0 += ex * hv.x;
    acc1 += ex * hv.y;
  }
  float inv = 1.f / den;
  float o0 = acc0 * inv + bias[2 * lane];
  float o1 = acc1 * inv + bias[2 * lane + 1];
  if (act) {
    o0 = (o0 > 0.f) ? o0 : 0.01f * o0;
    o1 = (o1 > 0.f) ? o1 : 0.01f * o1;
  }
  out[(size_t)i * HID + 2 * lane] = o0;
  out[(size_t)i * HID + 2 * lane + 1] = o1;
}

// ---------------- virtual-node path ----------------

__global__ void k_vnreduce(const float* __restrict__ out, float* __restrict__ vnsum) {
  int d = threadIdx.x;  // 128 threads
  float acc = 0.f;
  for (int i = blockIdx.x; i < NN; i += gridDim.x)
    acc += out[(size_t)i * HID + d];
  atomicAdd(&vnsum[d], acc);
}

__global__ void k_mlp(const float* __restrict__ vnsum, const float* __restrict__ vn_w,
                      const float* __restrict__ w1, const float* __restrict__ b1,
                      const float* __restrict__ w2, const float* __restrict__ b2,
                      const float* __restrict__ w3, const float* __restrict__ b3,
                      const float* __restrict__ w4, const float* __restrict__ b4,
                      float* __restrict__ outv) {
  __shared__ float xb[HID], yb[HID];
  int t = threadIdx.x;
  xb[t] = vnsum[t] + vn_w[t];
  __syncthreads();
  const float* Ws[4] = {w1, w2, w3, w4};
  const float* Bs[4] = {b1, b2, b3, b4};
  float* cur = xb;
  float* nxt = yb;
  for (int l = 0; l < 4; ++l) {
    const float* W = Ws[l];
    const float* B = Bs[l];
    float acc = B[t];
    for (int d = 0; d < HID; ++d) acc += cur[d] * W[d * HID + t];
    nxt[t] = fmaxf(acc, 0.f);
    __syncthreads();
    float* tmp = cur; cur = nxt; nxt = tmp;
  }
  outv[t] = cur[t];
}

// ---------------- launch ----------------

extern "C" void kernel_launch(void* const* d_in, const int* in_sizes, int n_in,
                              void* d_out, int out_size, void* d_ws, size_t ws_size,
                              hipStream_t stream) {
  const float* x = (const float*)d_in[0];
  const int* ei = (const int*)d_in[1];
  const float* edge_attr = (const float*)d_in[2];
  const float *W[3], *as_[3], *ad_[3], *We[3], *ae[3], *bb[3];
  for (int l = 0; l < 3; ++l) {
    W[l]   = (const float*)d_in[3 + l * 6 + 0];
    as_[l] = (const float*)d_in[3 + l * 6 + 1];
    ad_[l] = (const float*)d_in[3 + l * 6 + 2];
    We[l]  = (const float*)d_in[3 + l * 6 + 3];
    ae[l]  = (const float*)d_in[3 + l * 6 + 4];
    bb[l]  = (const float*)d_in[3 + l * 6 + 5];
  }
  const float* vn_w = (const float*)d_in[21];
  const float* m1w1 = (const float*)d_in[22];
  const float* m1b1 = (const float*)d_in[23];
  const float* m1w2 = (const float*)d_in[24];
  const float* m1b2 = (const float*)d_in[25];
  const float* m2w1 = (const float*)d_in[26];
  const float* m2b1 = (const float*)d_in[27];
  const float* m2w2 = (const float*)d_in[28];
  const float* m2b2 = (const float*)d_in[29];
  const float* Wout = (const float*)d_in[30];
  const float* bout = (const float*)d_in[31];

  char* ws = (char*)d_ws;
  size_t o = 0;
  auto alloc = [&](size_t bytes) {
    o = (o + 255) & ~(size_t)255;
    void* p = ws + o;
    o += bytes;
    return p;
  };
  float* hbuf   = (float*)alloc((size_t)NN * HID * 4);
  float* outbuf = (float*)alloc((size_t)NN * HID * 4);
  float* lattr  = (float*)alloc((size_t)NN * ED * 4);
  float* esc    = (float*)alloc((size_t)3 * EB * 4);
  float* hs     = (float*)alloc((size_t)NN * 4);
  float* hd     = (float*)alloc((size_t)NN * 4);
  float* vnsum  = (float*)alloc(HID * 4);
  float* weae   = (float*)alloc(3 * ED * 4);
  int* cnt      = (int*)alloc((size_t)NN * 4);
  int* off      = (int*)alloc((size_t)(NN + 1) * 4);
  int* cursor   = (int*)alloc((size_t)NN * 4);
  int* eid      = (int*)alloc((size_t)EE * 4);

  const int* srcv = ei;
  const int* dstv = ei + EE;

  k_zero<<<(NN + 255) / 256, 256, 0, stream>>>(cnt, vnsum);
  k_count<<<(EE + 255) / 256, 256, 0, stream>>>(dstv, cnt);
  k_scan<<<1, 1024, 0, stream>>>(cnt, off, cursor);
  k_scatter<<<(EE + 255) / 256, 256, 0, stream>>>(dstv, cursor, eid);
  k_loopattr<<<(NN + 3) / 4, 256, 0, stream>>>(edge_attr, off, eid, lattr);
  k_weae<<<1, 256, 0, stream>>>(We[0], We[1], We[2], ae[0], ae[1], ae[2], weae);
  k_esc<<<(EB + 3) / 4, 256, 0, stream>>>(edge_attr, lattr, weae, esc);

  const float* in_ptr = x;
  for (int l = 0; l < 3; ++l) {
    k_gemm128<<<(NN + 31) / 32, 256, 0, stream>>>(in_ptr, W[l], nullptr, hbuf, 0);
    k_hsd<<<(NN + 3) / 4, 256, 0, stream>>>(hbuf, as_[l], ad_[l], hs, hd);
    k_aggregate<<<(NN + 3) / 4, 256, 0, stream>>>(
        hbuf, hs, hd, esc + (size_t)l * EB, srcv, off, eid, bb[l], outbuf,
        (l > 0) ? 1 : 0);
    in_ptr = outbuf;
  }

  float* node_out = (float*)d_out;
  k_gemm128<<<(NN + 31) / 32, 256, 0, stream>>>(outbuf, Wout, bout, node_out, 1);
  k_vnreduce<<<256, 128, 0, stream>>>(outbuf, vnsum);
  k_mlp<<<1, 128, 0, stream>>>(vnsum, vn_w, m1w1, m1b1, m1w2, m1b2, m2w1, m2b1,
                               m2w2, m2b2, node_out + (size_t)NN * HID);
}

// Round 2
// 744.815 us; speedup vs baseline: 1.1560x; 1.1560x over previous
//
#include <hip/hip_runtime.h>

#define NN 50000
#define EE 400000
#define EB 450000   // EE + NN (edges incl. self-loops)
#define HID 128
#define ED 64
#define SCAN_G 196  // ceil(50000/256)

static __device__ __forceinline__ float wave_reduce_sum(float v) {
#pragma unroll
  for (int o = 32; o > 0; o >>= 1) v += __shfl_xor(v, o, 64);
  return v;
}

// exclusive prefix of v across 256 threads; s must hold >=256 ints.
// After return, s[255] holds the block total.
static __device__ __forceinline__ int block_excl_scan_256(int v, int* s) {
  int tid = threadIdx.x;
  s[tid] = v;
  __syncthreads();
  for (int d = 1; d < 256; d <<= 1) {
    int t = (tid >= d) ? s[tid - d] : 0;
    __syncthreads();
    s[tid] += t;
    __syncthreads();
  }
  return s[tid] - v;
}

// ---------------- setup kernels ----------------

__global__ void k_zero(int* __restrict__ cnt, float* __restrict__ vnsum) {
  int t = blockIdx.x * blockDim.x + threadIdx.x;
  if (t < NN) cnt[t] = 0;
  if (t < HID) vnsum[t] = 0.f;
}

__global__ void k_count(const int* __restrict__ dst, int* __restrict__ cnt) {
  int e = blockIdx.x * blockDim.x + threadIdx.x;
  if (e < EE) atomicAdd(&cnt[dst[e]], 1);
}

// phase 1: per-block sums
__global__ __launch_bounds__(256) void k_scan1(const int* __restrict__ cnt,
                                               int* __restrict__ bsum) {
  __shared__ int s[256];
  int idx = blockIdx.x * 256 + threadIdx.x;
  int v = (idx < NN) ? cnt[idx] : 0;
  s[threadIdx.x] = v;
  __syncthreads();
  for (int d = 128; d > 0; d >>= 1) {
    if (threadIdx.x < d) s[threadIdx.x] += s[threadIdx.x + d];
    __syncthreads();
  }
  if (threadIdx.x == 0) bsum[blockIdx.x] = s[0];
}

// phase 2: scan block sums (SCAN_G <= 256), write off[NN] = total
__global__ __launch_bounds__(256) void k_scan2(const int* __restrict__ bsum,
                                               int* __restrict__ bexc,
                                               int* __restrict__ off) {
  __shared__ int s[256];
  int t = threadIdx.x;
  int v = (t < SCAN_G) ? bsum[t] : 0;
  int exc = block_excl_scan_256(v, s);
  if (t < SCAN_G) bexc[t] = exc;
  if (t == 255) off[NN] = s[255];
}

// phase 3: per-block exclusive scan + block offset
__global__ __launch_bounds__(256) void k_scan3(const int* __restrict__ cnt,
                                               const int* __restrict__ bexc,
                                               int* __restrict__ off,
                                               int* __restrict__ cursor) {
  __shared__ int s[256];
  int idx = blockIdx.x * 256 + threadIdx.x;
  int v = (idx < NN) ? cnt[idx] : 0;
  int exc = block_excl_scan_256(v, s) + bexc[blockIdx.x];
  if (idx < NN) {
    off[idx] = exc;
    cursor[idx] = exc;
  }
}

__global__ void k_scatter(const int* __restrict__ dst, int* __restrict__ cursor,
                          int* __restrict__ eid) {
  int e = blockIdx.x * blockDim.x + threadIdx.x;
  if (e < EE) {
    int p = atomicAdd(&cursor[dst[e]], 1);
    eid[p] = e;
  }
}

// self-loop edge_attr = mean of incoming edge_attr; wave per node, lane = dim
__global__ __launch_bounds__(256) void k_loopattr(
    const float* __restrict__ edge_attr, const int* __restrict__ off,
    const int* __restrict__ eid, float* __restrict__ lattr) {
  int i = blockIdx.x * 4 + (threadIdx.x >> 6);
  int lane = threadIdx.x & 63;
  if (i >= NN) return;
  int s0 = off[i], s1 = off[i + 1];
  float acc = 0.f;
  for (int p = s0; p < s1; ++p) {
    int e = eid[p];
    acc += edge_attr[(size_t)e * ED + lane];
  }
  int deg = s1 - s0;
  lattr[(size_t)i * ED + lane] = acc / (float)(deg > 1 ? deg : 1);
}

// we_ae[l] = We_l @ ae_l  (64-vector per layer)
__global__ void k_weae(const float* __restrict__ We0, const float* __restrict__ We1,
                       const float* __restrict__ We2, const float* __restrict__ ae0,
                       const float* __restrict__ ae1, const float* __restrict__ ae2,
                       float* __restrict__ weae) {
  int t = threadIdx.x;
  if (t >= 192) return;
  int l = t >> 6, j = t & 63;
  const float* We = (l == 0) ? We0 : (l == 1) ? We1 : We2;
  const float* ae = (l == 0) ? ae0 : (l == 1) ? ae1 : ae2;
  float acc = 0.f;
  for (int k = 0; k < HID; ++k) acc += We[j * HID + k] * ae[k];
  weae[l * ED + j] = acc;
}

// per-edge (incl self-loop rows) scalar: esc[l][e] = ea_e . weae[l]
__global__ __launch_bounds__(256) void k_esc(
    const float* __restrict__ edge_attr, const float* __restrict__ lattr,
    const float* __restrict__ weae, float* __restrict__ esc) {
  int item = blockIdx.x * 4 + (threadIdx.x >> 6);
  int lane = threadIdx.x & 63;
  if (item >= EB) return;
  const float* base = (item < EE) ? (edge_attr + (size_t)item * ED)
                                  : (lattr + (size_t)(item - EE) * ED);
  float v = base[lane];
#pragma unroll
  for (int l = 0; l < 3; ++l) {
    float pv = wave_reduce_sum(v * weae[l * ED + lane]);
    if (lane == 0) esc[(size_t)l * EB + item] = pv;
  }
}

// ---------------- per-layer kernels ----------------

// O[NN x 128] = X[NN x 128] @ W[128 x 128] (+ bias). 32 rows per block.
__global__ __launch_bounds__(256) void k_gemm128(
    const float* __restrict__ X, const float* __restrict__ W,
    const float* __restrict__ bias, float* __restrict__ O, int use_bias) {
  __shared__ float sX[32][HID];
  __shared__ float sW[64][HID];
  int tid = threadIdx.x;
  int row0 = blockIdx.x * 32;
  {
    const float4* xs = (const float4*)(X + (size_t)row0 * HID);
    float4* xd = (float4*)(&sX[0][0]);
#pragma unroll
    for (int v = 0; v < 4; ++v) {
      int idx = tid + v * 256;       // 0..1023, 32 float4 per row
      int grow = row0 + (idx >> 5);
      xd[idx] = (grow < NN) ? xs[idx] : make_float4(0.f, 0.f, 0.f, 0.f);
    }
  }
  int colg = (tid & 31) * 4;
  int rowg = (tid >> 5) * 4;
  float acc[4][4] = {{0.f}};
  for (int kc = 0; kc < 2; ++kc) {
    __syncthreads();
    {
      const float4* wsp = (const float4*)(W + (size_t)kc * 64 * HID);
      float4* wd = (float4*)(&sW[0][0]);
#pragma unroll
      for (int v = 0; v < 8; ++v) wd[tid + v * 256] = wsp[tid + v * 256];
    }
    __syncthreads();
#pragma unroll 8
    for (int k = 0; k < 64; ++k) {
      float4 wv = *(const float4*)(&sW[k][colg]);
#pragma unroll
      for (int r = 0; r < 4; ++r) {
        float xv = sX[rowg + r][kc * 64 + k];
        acc[r][0] += xv * wv.x;
        acc[r][1] += xv * wv.y;
        acc[r][2] += xv * wv.z;
        acc[r][3] += xv * wv.w;
      }
    }
  }
#pragma unroll
  for (int r = 0; r < 4; ++r) {
    int grow = row0 + rowg + r;
    if (grow < NN) {
      float4 o;
      o.x = acc[r][0]; o.y = acc[r][1]; o.z = acc[r][2]; o.w = acc[r][3];
      if (use_bias) {
        o.x += bias[colg + 0];
        o.y += bias[colg + 1];
        o.z += bias[colg + 2];
        o.w += bias[colg + 3];
      }
      *(float4*)(O + (size_t)grow * HID + colg) = o;
    }
  }
}

// hs[i] = h[i].a_s ; hd[i] = h[i].a_d   (wave per node)
__global__ __launch_bounds__(256) void k_hsd(
    const float* __restrict__ h, const float* __restrict__ as_,
    const float* __restrict__ ad_, float* __restrict__ hs,
    float* __restrict__ hd) {
  int i = blockIdx.x * 4 + (threadIdx.x >> 6);
  int lane = threadIdx.x & 63;
  if (i >= NN) return;
  float v0 = h[(size_t)i * HID + lane];
  float v1 = h[(size_t)i * HID + 64 + lane];
  float s = wave_reduce_sum(v0 * as_[lane] + v1 * as_[64 + lane]);
  float d = wave_reduce_sum(v0 * ad_[lane] + v1 * ad_[64 + lane]);
  if (lane == 0) {
    hs[i] = s;
    hd[i] = d;
  }
}

// wave per dst node: softmax over incoming edges (+self loop), aggregate h[src]
__global__ __launch_bounds__(256) void k_aggregate(
    const float* __restrict__ h, const float* __restrict__ hs,
    const float* __restrict__ hd, const float* __restrict__ escl,
    const int* __restrict__ src, const int* __restrict__ off,
    const int* __restrict__ eid, const float* __restrict__ bias,
    float* __restrict__ out, int act) {
  int i = blockIdx.x * 4 + (threadIdx.x >> 6);
  int lane = threadIdx.x & 63;
  if (i >= NN) return;
  int s0 = off[i], s1 = off[i + 1];
  float hdi = hd[i];
  // pass 1: max alpha
  float m = -1e30f;
  for (int p = s0; p < s1; ++p) {
    int e = eid[p];
    int s = src[e];
    float a = hs[s] + hdi + escl[e];
    a = (a > 0.f) ? a : 0.2f * a;
    m = fmaxf(m, a);
  }
  float aself = hs[i] + hdi + escl[EE + i];
  aself = (aself > 0.f) ? aself : 0.2f * aself;
  m = fmaxf(m, aself);
  // pass 2: exp-sum and weighted aggregation
  float den = 0.f, acc0 = 0.f, acc1 = 0.f;
  for (int p = s0; p < s1; ++p) {
    int e = eid[p];
    int s = src[e];
    float a = hs[s] + hdi + escl[e];
    a = (a > 0.f) ? a : 0.2f * a;
    float ex = expf(a - m);
    den += ex;
    float2 hv = *(const float2*)(h + (size_t)s * HID + 2 * lane);
    acc0 += ex * hv.x;
    acc1 += ex * hv.y;
  }
  {
    float ex = expf(aself - m);
    den += ex;
    float2 hv = *(const float2*)(h + (size_t)i * HID + 2 * lane);
    acc0 += ex * hv.x;
    acc1 += ex * hv.y;
  }
  float inv = 1.f / den;
  float o0 = acc0 * inv + bias[2 * lane];
  float o1 = acc1 * inv + bias[2 * lane + 1];
  if (act) {
    o0 = (o0 > 0.f) ? o0 : 0.01f * o0;
    o1 = (o1 > 0.f) ? o1 : 0.01f * o1;
  }
  out[(size_t)i * HID + 2 * lane] = o0;
  out[(size_t)i * HID + 2 * lane + 1] = o1;
}

// ---------------- virtual-node path ----------------

__global__ void k_vnreduce(const float* __restrict__ out, float* __restrict__ vnsum) {
  int d = threadIdx.x;  // 128 threads
  float acc = 0.f;
  for (int i = blockIdx.x; i < NN; i += gridDim.x)
    acc += out[(size_t)i * HID + d];
  atomicAdd(&vnsum[d], acc);
}

__global__ void k_mlp(const float* __restrict__ vnsum, const float* __restrict__ vn_w,
                      const float* __restrict__ w1, const float* __restrict__ b1,
                      const float* __restrict__ w2, const float* __restrict__ b2,
                      const float* __restrict__ w3, const float* __restrict__ b3,
                      const float* __restrict__ w4, const float* __restrict__ b4,
                      float* __restrict__ outv) {
  __shared__ float xb[HID], yb[HID];
  int t = threadIdx.x;
  xb[t] = vnsum[t] + vn_w[t];
  __syncthreads();
  const float* Ws[4] = {w1, w2, w3, w4};
  const float* Bs[4] = {b1, b2, b3, b4};
  float* cur = xb;
  float* nxt = yb;
  for (int l = 0; l < 4; ++l) {
    const float* W = Ws[l];
    const float* B = Bs[l];
    float acc = B[t];
    for (int d = 0; d < HID; ++d) acc += cur[d] * W[d * HID + t];
    nxt[t] = fmaxf(acc, 0.f);
    __syncthreads();
    float* tmp = cur; cur = nxt; nxt = tmp;
  }
  outv[t] = cur[t];
}

// ---------------- launch ----------------

extern "C" void kernel_launch(void* const* d_in, const int* in_sizes, int n_in,
                              void* d_out, int out_size, void* d_ws, size_t ws_size,
                              hipStream_t stream) {
  const float* x = (const float*)d_in[0];
  const int* ei = (const int*)d_in[1];
  const float* edge_attr = (const float*)d_in[2];
  const float *W[3], *as_[3], *ad_[3], *We[3], *ae[3], *bb[3];
  for (int l = 0; l < 3; ++l) {
    W[l]   = (const float*)d_in[3 + l * 6 + 0];
    as_[l] = (const float*)d_in[3 + l * 6 + 1];
    ad_[l] = (const float*)d_in[3 + l * 6 + 2];
    We[l]  = (const float*)d_in[3 + l * 6 + 3];
    ae[l]  = (const float*)d_in[3 + l * 6 + 4];
    bb[l]  = (const float*)d_in[3 + l * 6 + 5];
  }
  const float* vn_w = (const float*)d_in[21];
  const float* m1w1 = (const float*)d_in[22];
  const float* m1b1 = (const float*)d_in[23];
  const float* m1w2 = (const float*)d_in[24];
  const float* m1b2 = (const float*)d_in[25];
  const float* m2w1 = (const float*)d_in[26];
  const float* m2b1 = (const float*)d_in[27];
  const float* m2w2 = (const float*)d_in[28];
  const float* m2b2 = (const float*)d_in[29];
  const float* Wout = (const float*)d_in[30];
  const float* bout = (const float*)d_in[31];

  char* ws = (char*)d_ws;
  size_t o = 0;
  auto alloc = [&](size_t bytes) {
    o = (o + 255) & ~(size_t)255;
    void* p = ws + o;
    o += bytes;
    return p;
  };
  float* hbuf   = (float*)alloc((size_t)NN * HID * 4);
  float* outbuf = (float*)alloc((size_t)NN * HID * 4);
  float* lattr  = (float*)alloc((size_t)NN * ED * 4);
  float* esc    = (float*)alloc((size_t)3 * EB * 4);
  float* hs     = (float*)alloc((size_t)NN * 4);
  float* hd     = (float*)alloc((size_t)NN * 4);
  float* vnsum  = (float*)alloc(HID * 4);
  float* weae   = (float*)alloc(3 * ED * 4);
  int* cnt      = (int*)alloc((size_t)NN * 4);
  int* off      = (int*)alloc((size_t)(NN + 1) * 4);
  int* cursor   = (int*)alloc((size_t)NN * 4);
  int* eid      = (int*)alloc((size_t)EE * 4);
  int* bsum     = (int*)alloc((size_t)SCAN_G * 4);
  int* bexc     = (int*)alloc((size_t)SCAN_G * 4);

  const int* srcv = ei;
  const int* dstv = ei + EE;

  k_zero<<<(NN + 255) / 256, 256, 0, stream>>>(cnt, vnsum);
  k_count<<<(EE + 255) / 256, 256, 0, stream>>>(dstv, cnt);
  k_scan1<<<SCAN_G, 256, 0, stream>>>(cnt, bsum);
  k_scan2<<<1, 256, 0, stream>>>(bsum, bexc, off);
  k_scan3<<<SCAN_G, 256, 0, stream>>>(cnt, bexc, off, cursor);
  k_scatter<<<(EE + 255) / 256, 256, 0, stream>>>(dstv, cursor, eid);
  k_loopattr<<<(NN + 3) / 4, 256, 0, stream>>>(edge_attr, off, eid, lattr);
  k_weae<<<1, 256, 0, stream>>>(We[0], We[1], We[2], ae[0], ae[1], ae[2], weae);
  k_esc<<<(EB + 3) / 4, 256, 0, stream>>>(edge_attr, lattr, weae, esc);

  const float* in_ptr = x;
  for (int l = 0; l < 3; ++l) {
    k_gemm128<<<(NN + 31) / 32, 256, 0, stream>>>(in_ptr, W[l], nullptr, hbuf, 0);
    k_hsd<<<(NN + 3) / 4, 256, 0, stream>>>(hbuf, as_[l], ad_[l], hs, hd);
    k_aggregate<<<(NN + 3) / 4, 256, 0, stream>>>(
        hbuf, hs, hd, esc + (size_t)l * EB, srcv, off, eid, bb[l], outbuf,
        (l > 0) ? 1 : 0);
    in_ptr = outbuf;
  }

  float* node_out = (float*)d_out;
  k_gemm128<<<(NN + 31) / 32, 256, 0, stream>>>(outbuf, Wout, bout, node_out, 1);
  k_vnreduce<<<256, 128, 0, stream>>>(outbuf, vnsum);
  k_mlp<<<1, 128, 0, stream>>>(vnsum, vn_w, m1w1, m1b1, m1w2, m1b2, m2w1, m2b1,
                               m2w2, m2b2, node_out + (size_t)NN * HID);
}

// Round 3
// 705.939 us; speedup vs baseline: 1.2196x; 1.0551x over previous
//
#include <hip/hip_runtime.h>

#define NN 50000
#define EE 400000
#define EB 450000   // EE + NN (edges incl. self-loops)
#define HID 128
#define ED 64
#define SCAN_G 196  // ceil(50000/256)

static __device__ __forceinline__ float wave_reduce_sum(float v) {
#pragma unroll
  for (int o = 32; o > 0; o >>= 1) v += __shfl_xor(v, o, 64);
  return v;
}

// monotone float<->uint key for atomicMax on floats (incl. negatives)
static __device__ __forceinline__ unsigned f2key(float f) {
  unsigned b = __float_as_uint(f);
  return (b & 0x80000000u) ? ~b : (b | 0x80000000u);
}
static __device__ __forceinline__ float key2f(unsigned k) {
  unsigned b = (k & 0x80000000u) ? (k & 0x7FFFFFFFu) : ~k;
  return __uint_as_float(b);
}

// exclusive prefix of v across 256 threads; s must hold >=256 ints.
// After return, s[255] holds the block total.
static __device__ __forceinline__ int block_excl_scan_256(int v, int* s) {
  int tid = threadIdx.x;
  s[tid] = v;
  __syncthreads();
  for (int d = 1; d < 256; d <<= 1) {
    int t = (tid >= d) ? s[tid - d] : 0;
    __syncthreads();
    s[tid] += t;
    __syncthreads();
  }
  return s[tid] - v;
}

// ---------------- setup kernels ----------------

__global__ void k_zero(int* __restrict__ cnt, float* __restrict__ vnsum) {
  int t = blockIdx.x * blockDim.x + threadIdx.x;
  if (t < NN) cnt[t] = 0;
  if (t < HID) vnsum[t] = 0.f;
}

__global__ void k_count(const int* __restrict__ dst, int* __restrict__ cnt) {
  int e = blockIdx.x * blockDim.x + threadIdx.x;
  if (e < EE) atomicAdd(&cnt[dst[e]], 1);
}

// phase 1: per-block sums
__global__ __launch_bounds__(256) void k_scan1(const int* __restrict__ cnt,
                                               int* __restrict__ bsum) {
  __shared__ int s[256];
  int idx = blockIdx.x * 256 + threadIdx.x;
  int v = (idx < NN) ? cnt[idx] : 0;
  s[threadIdx.x] = v;
  __syncthreads();
  for (int d = 128; d > 0; d >>= 1) {
    if (threadIdx.x < d) s[threadIdx.x] += s[threadIdx.x + d];
    __syncthreads();
  }
  if (threadIdx.x == 0) bsum[blockIdx.x] = s[0];
}

// phase 2: scan block sums (SCAN_G <= 256), write off[NN] = total
__global__ __launch_bounds__(256) void k_scan2(const int* __restrict__ bsum,
                                               int* __restrict__ bexc,
                                               int* __restrict__ off) {
  __shared__ int s[256];
  int t = threadIdx.x;
  int v = (t < SCAN_G) ? bsum[t] : 0;
  int exc = block_excl_scan_256(v, s);
  if (t < SCAN_G) bexc[t] = exc;
  if (t == 255) off[NN] = s[255];
}

// phase 3: per-block exclusive scan + block offset
__global__ __launch_bounds__(256) void k_scan3(const int* __restrict__ cnt,
                                               const int* __restrict__ bexc,
                                               int* __restrict__ off,
                                               int* __restrict__ cursor) {
  __shared__ int s[256];
  int idx = blockIdx.x * 256 + threadIdx.x;
  int v = (idx < NN) ? cnt[idx] : 0;
  int exc = block_excl_scan_256(v, s) + bexc[blockIdx.x];
  if (idx < NN) {
    off[idx] = exc;
    cursor[idx] = exc;
  }
}

__global__ void k_scatter(const int* __restrict__ dst, int* __restrict__ cursor,
                          int* __restrict__ eid) {
  int e = blockIdx.x * blockDim.x + threadIdx.x;
  if (e < EE) {
    int p = atomicAdd(&cursor[dst[e]], 1);
    eid[p] = e;
  }
}

// self-loop edge_attr = mean of incoming edge_attr; wave per node, lane = dim
__global__ __launch_bounds__(256) void k_loopattr(
    const float* __restrict__ edge_attr, const int* __restrict__ off,
    const int* __restrict__ eid, float* __restrict__ lattr) {
  int i = blockIdx.x * 4 + (threadIdx.x >> 6);
  int lane = threadIdx.x & 63;
  if (i >= NN) return;
  int s0 = off[i], s1 = off[i + 1];
  float acc = 0.f;
  for (int p = s0; p < s1; ++p) {
    int e = eid[p];
    acc += edge_attr[(size_t)e * ED + lane];
  }
  int deg = s1 - s0;
  lattr[(size_t)i * ED + lane] = acc / (float)(deg > 1 ? deg : 1);
}

// we_ae[l] = We_l @ ae_l  (64-vector per layer)
__global__ void k_weae(const float* __restrict__ We0, const float* __restrict__ We1,
                       const float* __restrict__ We2, const float* __restrict__ ae0,
                       const float* __restrict__ ae1, const float* __restrict__ ae2,
                       float* __restrict__ weae) {
  int t = threadIdx.x;
  if (t >= 192) return;
  int l = t >> 6, j = t & 63;
  const float* We = (l == 0) ? We0 : (l == 1) ? We1 : We2;
  const float* ae = (l == 0) ? ae0 : (l == 1) ? ae1 : ae2;
  float acc = 0.f;
  for (int k = 0; k < HID; ++k) acc += We[j * HID + k] * ae[k];
  weae[l * ED + j] = acc;
}

// per-edge (incl self-loop rows) scalar: esc[l][e] = ea_e . weae[l]
__global__ __launch_bounds__(256) void k_esc(
    const float* __restrict__ edge_attr, const float* __restrict__ lattr,
    const float* __restrict__ weae, float* __restrict__ esc) {
  int item = blockIdx.x * 4 + (threadIdx.x >> 6);
  int lane = threadIdx.x & 63;
  if (item >= EB) return;
  const float* base = (item < EE) ? (edge_attr + (size_t)item * ED)
                                  : (lattr + (size_t)(item - EE) * ED);
  float v = base[lane];
#pragma unroll
  for (int l = 0; l < 3; ++l) {
    float pv = wave_reduce_sum(v * weae[l * ED + lane]);
    if (lane == 0) esc[(size_t)l * EB + item] = pv;
  }
}

// ---------------- per-layer kernels ----------------

// O[NN x 128] = X[NN x 128] @ W[128 x 128] (+ bias). 32 rows per block.
__global__ __launch_bounds__(256) void k_gemm128(
    const float* __restrict__ X, const float* __restrict__ W,
    const float* __restrict__ bias, float* __restrict__ O, int use_bias) {
  __shared__ float sX[32][HID];
  __shared__ float sW[64][HID];
  int tid = threadIdx.x;
  int row0 = blockIdx.x * 32;
  {
    const float4* xs = (const float4*)(X + (size_t)row0 * HID);
    float4* xd = (float4*)(&sX[0][0]);
#pragma unroll
    for (int v = 0; v < 4; ++v) {
      int idx = tid + v * 256;       // 0..1023, 32 float4 per row
      int grow = row0 + (idx >> 5);
      xd[idx] = (grow < NN) ? xs[idx] : make_float4(0.f, 0.f, 0.f, 0.f);
    }
  }
  int colg = (tid & 31) * 4;
  int rowg = (tid >> 5) * 4;
  float acc[4][4] = {{0.f}};
  for (int kc = 0; kc < 2; ++kc) {
    __syncthreads();
    {
      const float4* wsp = (const float4*)(W + (size_t)kc * 64 * HID);
      float4* wd = (float4*)(&sW[0][0]);
#pragma unroll
      for (int v = 0; v < 8; ++v) wd[tid + v * 256] = wsp[tid + v * 256];
    }
    __syncthreads();
#pragma unroll 8
    for (int k = 0; k < 64; ++k) {
      float4 wv = *(const float4*)(&sW[k][colg]);
#pragma unroll
      for (int r = 0; r < 4; ++r) {
        float xv = sX[rowg + r][kc * 64 + k];
        acc[r][0] += xv * wv.x;
        acc[r][1] += xv * wv.y;
        acc[r][2] += xv * wv.z;
        acc[r][3] += xv * wv.w;
      }
    }
  }
#pragma unroll
  for (int r = 0; r < 4; ++r) {
    int grow = row0 + rowg + r;
    if (grow < NN) {
      float4 o;
      o.x = acc[r][0]; o.y = acc[r][1]; o.z = acc[r][2]; o.w = acc[r][3];
      if (use_bias) {
        o.x += bias[colg + 0];
        o.y += bias[colg + 1];
        o.z += bias[colg + 2];
        o.w += bias[colg + 3];
      }
      *(float4*)(O + (size_t)grow * HID + colg) = o;
    }
  }
}

// hs[i] = h[i].a_s ; hd[i] = h[i].a_d ; mkey[i] = 0   (wave per node)
__global__ __launch_bounds__(256) void k_hsd(
    const float* __restrict__ h, const float* __restrict__ as_,
    const float* __restrict__ ad_, float* __restrict__ hs,
    float* __restrict__ hd, unsigned* __restrict__ mkey) {
  int i = blockIdx.x * 4 + (threadIdx.x >> 6);
  int lane = threadIdx.x & 63;
  if (i >= NN) return;
  float v0 = h[(size_t)i * HID + lane];
  float v1 = h[(size_t)i * HID + 64 + lane];
  float s = wave_reduce_sum(v0 * as_[lane] + v1 * as_[64 + lane]);
  float d = wave_reduce_sum(v0 * ad_[lane] + v1 * ad_[64 + lane]);
  if (lane == 0) {
    hs[i] = s;
    hd[i] = d;
    mkey[i] = 0u;
  }
}

// edge-parallel: a[e] = leaky(hs[src]+hd[dst]+esc[e]); atomicMax key per dst.
// items [EE, EB) are self-loops of node i = e - EE.
__global__ __launch_bounds__(256) void k_alpha(
    const float* __restrict__ hs, const float* __restrict__ hd,
    const float* __restrict__ escl, const int* __restrict__ src,
    const int* __restrict__ dst, float* __restrict__ a,
    unsigned* __restrict__ mkey) {
  int e = blockIdx.x * blockDim.x + threadIdx.x;
  if (e >= EB) return;
  int s, d;
  if (e < EE) {
    s = src[e];
    d = dst[e];
  } else {
    s = d = e - EE;
  }
  float v = hs[s] + hd[d] + escl[e];
  v = (v > 0.f) ? v : 0.2f * v;
  a[e] = v;
  atomicMax(&mkey[d], f2key(v));
}

// wave per dst node: single pass — w=exp(a[e]-m), den += w, acc += w*h[src]
__global__ __launch_bounds__(256) void k_aggregate2(
    const float* __restrict__ h, const float* __restrict__ a,
    const unsigned* __restrict__ mkey, const int* __restrict__ src,
    const int* __restrict__ off, const int* __restrict__ eid,
    const float* __restrict__ bias, float* __restrict__ out, int act) {
  int i = blockIdx.x * 4 + (threadIdx.x >> 6);
  int lane = threadIdx.x & 63;
  if (i >= NN) return;
  int s0 = off[i], s1 = off[i + 1];
  float m = key2f(mkey[i]);
  float den = 0.f, acc0 = 0.f, acc1 = 0.f;
  for (int p = s0; p < s1; ++p) {
    int e = eid[p];
    int s = src[e];
    float w = __expf(a[e] - m);
    den += w;
    float2 hv = *(const float2*)(h + (size_t)s * HID + 2 * lane);
    acc0 += w * hv.x;
    acc1 += w * hv.y;
  }
  {  // self-loop
    float w = __expf(a[EE + i] - m);
    den += w;
    float2 hv = *(const float2*)(h + (size_t)i * HID + 2 * lane);
    acc0 += w * hv.x;
    acc1 += w * hv.y;
  }
  float inv = 1.f / den;
  float o0 = acc0 * inv + bias[2 * lane];
  float o1 = acc1 * inv + bias[2 * lane + 1];
  if (act) {
    o0 = (o0 > 0.f) ? o0 : 0.01f * o0;
    o1 = (o1 > 0.f) ? o1 : 0.01f * o1;
  }
  out[(size_t)i * HID + 2 * lane] = o0;
  out[(size_t)i * HID + 2 * lane + 1] = o1;
}

// ---------------- virtual-node path ----------------

__global__ void k_vnreduce(const float* __restrict__ out, float* __restrict__ vnsum) {
  int d = threadIdx.x;  // 128 threads
  float acc = 0.f;
  for (int i = blockIdx.x; i < NN; i += gridDim.x)
    acc += out[(size_t)i * HID + d];
  atomicAdd(&vnsum[d], acc);
}

__global__ void k_mlp(const float* __restrict__ vnsum, const float* __restrict__ vn_w,
                      const float* __restrict__ w1, const float* __restrict__ b1,
                      const float* __restrict__ w2, const float* __restrict__ b2,
                      const float* __restrict__ w3, const float* __restrict__ b3,
                      const float* __restrict__ w4, const float* __restrict__ b4,
                      float* __restrict__ outv) {
  __shared__ float xb[HID], yb[HID];
  int t = threadIdx.x;
  xb[t] = vnsum[t] + vn_w[t];
  __syncthreads();
  const float* Ws[4] = {w1, w2, w3, w4};
  const float* Bs[4] = {b1, b2, b3, b4};
  float* cur = xb;
  float* nxt = yb;
  for (int l = 0; l < 4; ++l) {
    const float* W = Ws[l];
    const float* B = Bs[l];
    float acc = B[t];
    for (int d = 0; d < HID; ++d) acc += cur[d] * W[d * HID + t];
    nxt[t] = fmaxf(acc, 0.f);
    __syncthreads();
    float* tmp = cur; cur = nxt; nxt = tmp;
  }
  outv[t] = cur[t];
}

// ---------------- launch ----------------

extern "C" void kernel_launch(void* const* d_in, const int* in_sizes, int n_in,
                              void* d_out, int out_size, void* d_ws, size_t ws_size,
                              hipStream_t stream) {
  const float* x = (const float*)d_in[0];
  const int* ei = (const int*)d_in[1];
  const float* edge_attr = (const float*)d_in[2];
  const float *W[3], *as_[3], *ad_[3], *We[3], *ae[3], *bb[3];
  for (int l = 0; l < 3; ++l) {
    W[l]   = (const float*)d_in[3 + l * 6 + 0];
    as_[l] = (const float*)d_in[3 + l * 6 + 1];
    ad_[l] = (const float*)d_in[3 + l * 6 + 2];
    We[l]  = (const float*)d_in[3 + l * 6 + 3];
    ae[l]  = (const float*)d_in[3 + l * 6 + 4];
    bb[l]  = (const float*)d_in[3 + l * 6 + 5];
  }
  const float* vn_w = (const float*)d_in[21];
  const float* m1w1 = (const float*)d_in[22];
  const float* m1b1 = (const float*)d_in[23];
  const float* m1w2 = (const float*)d_in[24];
  const float* m1b2 = (const float*)d_in[25];
  const float* m2w1 = (const float*)d_in[26];
  const float* m2b1 = (const float*)d_in[27];
  const float* m2w2 = (const float*)d_in[28];
  const float* m2b2 = (const float*)d_in[29];
  const float* Wout = (const float*)d_in[30];
  const float* bout = (const float*)d_in[31];

  char* ws = (char*)d_ws;
  size_t o = 0;
  auto alloc = [&](size_t bytes) {
    o = (o + 255) & ~(size_t)255;
    void* p = ws + o;
    o += bytes;
    return p;
  };
  float* hbuf   = (float*)alloc((size_t)NN * HID * 4);
  float* outbuf = (float*)alloc((size_t)NN * HID * 4);
  float* lattr  = (float*)alloc((size_t)NN * ED * 4);
  float* esc    = (float*)alloc((size_t)3 * EB * 4);
  float* abuf   = (float*)alloc((size_t)EB * 4);
  float* hs     = (float*)alloc((size_t)NN * 4);
  float* hd     = (float*)alloc((size_t)NN * 4);
  unsigned* mkey = (unsigned*)alloc((size_t)NN * 4);
  float* vnsum  = (float*)alloc(HID * 4);
  float* weae   = (float*)alloc(3 * ED * 4);
  int* cnt      = (int*)alloc((size_t)NN * 4);
  int* off      = (int*)alloc((size_t)(NN + 1) * 4);
  int* cursor   = (int*)alloc((size_t)NN * 4);
  int* eid      = (int*)alloc((size_t)EE * 4);
  int* bsum     = (int*)alloc((size_t)SCAN_G * 4);
  int* bexc     = (int*)alloc((size_t)SCAN_G * 4);

  const int* srcv = ei;
  const int* dstv = ei + EE;

  k_zero<<<(NN + 255) / 256, 256, 0, stream>>>(cnt, vnsum);
  k_count<<<(EE + 255) / 256, 256, 0, stream>>>(dstv, cnt);
  k_scan1<<<SCAN_G, 256, 0, stream>>>(cnt, bsum);
  k_scan2<<<1, 256, 0, stream>>>(bsum, bexc, off);
  k_scan3<<<SCAN_G, 256, 0, stream>>>(cnt, bexc, off, cursor);
  k_scatter<<<(EE + 255) / 256, 256, 0, stream>>>(dstv, cursor, eid);
  k_loopattr<<<(NN + 3) / 4, 256, 0, stream>>>(edge_attr, off, eid, lattr);
  k_weae<<<1, 256, 0, stream>>>(We[0], We[1], We[2], ae[0], ae[1], ae[2], weae);
  k_esc<<<(EB + 3) / 4, 256, 0, stream>>>(edge_attr, lattr, weae, esc);

  const float* in_ptr = x;
  for (int l = 0; l < 3; ++l) {
    k_gemm128<<<(NN + 31) / 32, 256, 0, stream>>>(in_ptr, W[l], nullptr, hbuf, 0);
    k_hsd<<<(NN + 3) / 4, 256, 0, stream>>>(hbuf, as_[l], ad_[l], hs, hd, mkey);
    k_alpha<<<(EB + 255) / 256, 256, 0, stream>>>(
        hs, hd, esc + (size_t)l * EB, srcv, dstv, abuf, mkey);
    k_aggregate2<<<(NN + 3) / 4, 256, 0, stream>>>(
        hbuf, abuf, mkey, srcv, off, eid, bb[l], outbuf, (l > 0) ? 1 : 0);
    in_ptr = outbuf;
  }

  float* node_out = (float*)d_out;
  k_gemm128<<<(NN + 31) / 32, 256, 0, stream>>>(outbuf, Wout, bout, node_out, 1);
  k_vnreduce<<<256, 128, 0, stream>>>(outbuf, vnsum);
  k_mlp<<<1, 128, 0, stream>>>(vnsum, vn_w, m1w1, m1b1, m1w2, m1b2, m2w1, m2b1,
                               m2w2, m2b2, node_out + (size_t)NN * HID);
}

// Round 4
// 630.288 us; speedup vs baseline: 1.3660x; 1.1200x over previous
//
#include <hip/hip_runtime.h>

#define NN 50000
#define EE 400000
#define EB 450000   // EE + NN (edges incl. self-loops)
#define HID 128
#define ED 64
#define SCAN_G 196  // ceil(50000/256)

static __device__ __forceinline__ float wave_reduce_sum(float v) {
#pragma unroll
  for (int o = 32; o > 0; o >>= 1) v += __shfl_xor(v, o, 64);
  return v;
}

// monotone float<->uint key for atomicMax on floats (incl. negatives)
static __device__ __forceinline__ unsigned f2key(float f) {
  unsigned b = __float_as_uint(f);
  return (b & 0x80000000u) ? ~b : (b | 0x80000000u);
}
static __device__ __forceinline__ float key2f(unsigned k) {
  unsigned b = (k & 0x80000000u) ? (k & 0x7FFFFFFFu) : ~k;
  return __uint_as_float(b);
}

// exclusive prefix of v across 256 threads; s must hold >=256 ints.
// After return, s[255] holds the block total.
static __device__ __forceinline__ int block_excl_scan_256(int v, int* s) {
  int tid = threadIdx.x;
  s[tid] = v;
  __syncthreads();
  for (int d = 1; d < 256; d <<= 1) {
    int t = (tid >= d) ? s[tid - d] : 0;
    __syncthreads();
    s[tid] += t;
    __syncthreads();
  }
  return s[tid] - v;
}

// ---------------- setup kernels ----------------

__global__ void k_zero(int* __restrict__ cnt, float* __restrict__ vnsum) {
  int t = blockIdx.x * blockDim.x + threadIdx.x;
  if (t < NN) cnt[t] = 0;
  if (t < HID) vnsum[t] = 0.f;
}

__global__ void k_count(const int* __restrict__ dst, int* __restrict__ cnt) {
  int e = blockIdx.x * blockDim.x + threadIdx.x;
  if (e < EE) atomicAdd(&cnt[dst[e]], 1);
}

// phase 1: per-block sums
__global__ __launch_bounds__(256) void k_scan1(const int* __restrict__ cnt,
                                               int* __restrict__ bsum) {
  __shared__ int s[256];
  int idx = blockIdx.x * 256 + threadIdx.x;
  int v = (idx < NN) ? cnt[idx] : 0;
  s[threadIdx.x] = v;
  __syncthreads();
  for (int d = 128; d > 0; d >>= 1) {
    if (threadIdx.x < d) s[threadIdx.x] += s[threadIdx.x + d];
    __syncthreads();
  }
  if (threadIdx.x == 0) bsum[blockIdx.x] = s[0];
}

// phase 2: scan block sums (SCAN_G <= 256), write off[NN] = total
__global__ __launch_bounds__(256) void k_scan2(const int* __restrict__ bsum,
                                               int* __restrict__ bexc,
                                               int* __restrict__ off) {
  __shared__ int s[256];
  int t = threadIdx.x;
  int v = (t < SCAN_G) ? bsum[t] : 0;
  int exc = block_excl_scan_256(v, s);
  if (t < SCAN_G) bexc[t] = exc;
  if (t == 255) off[NN] = s[255];
}

// phase 3: per-block exclusive scan + block offset
__global__ __launch_bounds__(256) void k_scan3(const int* __restrict__ cnt,
                                               const int* __restrict__ bexc,
                                               int* __restrict__ off,
                                               int* __restrict__ cursor) {
  __shared__ int s[256];
  int idx = blockIdx.x * 256 + threadIdx.x;
  int v = (idx < NN) ? cnt[idx] : 0;
  int exc = block_excl_scan_256(v, s) + bexc[blockIdx.x];
  if (idx < NN) {
    off[idx] = exc;
    cursor[idx] = exc;
  }
}

__global__ void k_scatter(const int* __restrict__ dst, int* __restrict__ cursor,
                          int* __restrict__ eid) {
  int e = blockIdx.x * blockDim.x + threadIdx.x;
  if (e < EE) {
    int p = atomicAdd(&cursor[dst[e]], 1);
    eid[p] = e;
  }
}

// self-loop edge_attr = mean of incoming edge_attr; wave per node, lane = dim
__global__ __launch_bounds__(256) void k_loopattr(
    const float* __restrict__ edge_attr, const int* __restrict__ off,
    const int* __restrict__ eid, float* __restrict__ lattr) {
  int i = blockIdx.x * 4 + (threadIdx.x >> 6);
  int lane = threadIdx.x & 63;
  if (i >= NN) return;
  int s0 = off[i], s1 = off[i + 1];
  float acc = 0.f;
  for (int p = s0; p < s1; ++p) {
    int e = eid[p];
    acc += edge_attr[(size_t)e * ED + lane];
  }
  int deg = s1 - s0;
  lattr[(size_t)i * ED + lane] = acc / (float)(deg > 1 ? deg : 1);
}

// we_ae[l] = We_l @ ae_l  (64-vector per layer)
__global__ void k_weae(const float* __restrict__ We0, const float* __restrict__ We1,
                       const float* __restrict__ We2, const float* __restrict__ ae0,
                       const float* __restrict__ ae1, const float* __restrict__ ae2,
                       float* __restrict__ weae) {
  int t = threadIdx.x;
  if (t >= 192) return;
  int l = t >> 6, j = t & 63;
  const float* We = (l == 0) ? We0 : (l == 1) ? We1 : We2;
  const float* ae = (l == 0) ? ae0 : (l == 1) ? ae1 : ae2;
  float acc = 0.f;
  for (int k = 0; k < HID; ++k) acc += We[j * HID + k] * ae[k];
  weae[l * ED + j] = acc;
}

// per-edge (incl self-loop rows) scalar: esc[l][e] = ea_e . weae[l]
// thread per item, 16x float4 row load, weae staged in LDS (broadcast reads)
__global__ __launch_bounds__(256) void k_esc(
    const float* __restrict__ edge_attr, const float* __restrict__ lattr,
    const float* __restrict__ weae, float* __restrict__ esc) {
  __shared__ float4 sw[3][16];
  int tid = threadIdx.x;
  if (tid < 48) ((float4*)sw)[tid] = ((const float4*)weae)[tid];
  __syncthreads();
  int item = blockIdx.x * 256 + tid;
  if (item >= EB) return;
  const float4* row = (item < EE)
                          ? (const float4*)(edge_attr + (size_t)item * ED)
                          : (const float4*)(lattr + (size_t)(item - EE) * ED);
  float a0 = 0.f, a1 = 0.f, a2 = 0.f;
#pragma unroll
  for (int c = 0; c < 16; ++c) {
    float4 v = row[c];
    float4 w0 = sw[0][c], w1 = sw[1][c], w2 = sw[2][c];
    a0 += v.x * w0.x + v.y * w0.y + v.z * w0.z + v.w * w0.w;
    a1 += v.x * w1.x + v.y * w1.y + v.z * w1.z + v.w * w1.w;
    a2 += v.x * w2.x + v.y * w2.y + v.z * w2.z + v.w * w2.w;
  }
  esc[item] = a0;
  esc[(size_t)EB + item] = a1;
  esc[(size_t)2 * EB + item] = a2;
}

// ---------------- per-layer kernels ----------------

// O[NN x 128] = X[NN x 128] @ W[128 x 128] (+ bias). 32 rows per block.
__global__ __launch_bounds__(256) void k_gemm128(
    const float* __restrict__ X, const float* __restrict__ W,
    const float* __restrict__ bias, float* __restrict__ O, int use_bias) {
  __shared__ float sX[32][HID];
  __shared__ float sW[64][HID];
  int tid = threadIdx.x;
  int row0 = blockIdx.x * 32;
  {
    const float4* xs = (const float4*)(X + (size_t)row0 * HID);
    float4* xd = (float4*)(&sX[0][0]);
#pragma unroll
    for (int v = 0; v < 4; ++v) {
      int idx = tid + v * 256;       // 0..1023, 32 float4 per row
      int grow = row0 + (idx >> 5);
      xd[idx] = (grow < NN) ? xs[idx] : make_float4(0.f, 0.f, 0.f, 0.f);
    }
  }
  int colg = (tid & 31) * 4;
  int rowg = (tid >> 5) * 4;
  float acc[4][4] = {{0.f}};
  for (int kc = 0; kc < 2; ++kc) {
    __syncthreads();
    {
      const float4* wsp = (const float4*)(W + (size_t)kc * 64 * HID);
      float4* wd = (float4*)(&sW[0][0]);
#pragma unroll
      for (int v = 0; v < 8; ++v) wd[tid + v * 256] = wsp[tid + v * 256];
    }
    __syncthreads();
#pragma unroll 8
    for (int k = 0; k < 64; ++k) {
      float4 wv = *(const float4*)(&sW[k][colg]);
#pragma unroll
      for (int r = 0; r < 4; ++r) {
        float xv = sX[rowg + r][kc * 64 + k];
        acc[r][0] += xv * wv.x;
        acc[r][1] += xv * wv.y;
        acc[r][2] += xv * wv.z;
        acc[r][3] += xv * wv.w;
      }
    }
  }
#pragma unroll
  for (int r = 0; r < 4; ++r) {
    int grow = row0 + rowg + r;
    if (grow < NN) {
      float4 o;
      o.x = acc[r][0]; o.y = acc[r][1]; o.z = acc[r][2]; o.w = acc[r][3];
      if (use_bias) {
        o.x += bias[colg + 0];
        o.y += bias[colg + 1];
        o.z += bias[colg + 2];
        o.w += bias[colg + 3];
      }
      *(float4*)(O + (size_t)grow * HID + colg) = o;
    }
  }
}

// hs[i] = h[i].a_s ; hd[i] = h[i].a_d ; mkey[i] = 0   (wave per node)
__global__ __launch_bounds__(256) void k_hsd(
    const float* __restrict__ h, const float* __restrict__ as_,
    const float* __restrict__ ad_, float* __restrict__ hs,
    float* __restrict__ hd, unsigned* __restrict__ mkey) {
  int i = blockIdx.x * 4 + (threadIdx.x >> 6);
  int lane = threadIdx.x & 63;
  if (i >= NN) return;
  float v0 = h[(size_t)i * HID + lane];
  float v1 = h[(size_t)i * HID + 64 + lane];
  float s = wave_reduce_sum(v0 * as_[lane] + v1 * as_[64 + lane]);
  float d = wave_reduce_sum(v0 * ad_[lane] + v1 * ad_[64 + lane]);
  if (lane == 0) {
    hs[i] = s;
    hd[i] = d;
    mkey[i] = 0u;
  }
}

// edge-parallel: a[e] = leaky(hs[src]+hd[dst]+esc[e]); atomicMax key per dst.
// items [EE, EB) are self-loops of node i = e - EE.
__global__ __launch_bounds__(256) void k_alpha(
    const float* __restrict__ hs, const float* __restrict__ hd,
    const float* __restrict__ escl, const int* __restrict__ src,
    const int* __restrict__ dst, float* __restrict__ a,
    unsigned* __restrict__ mkey) {
  int e = blockIdx.x * blockDim.x + threadIdx.x;
  if (e >= EB) return;
  int s, d;
  if (e < EE) {
    s = src[e];
    d = dst[e];
  } else {
    s = d = e - EE;
  }
  float v = hs[s] + hd[d] + escl[e];
  v = (v > 0.f) ? v : 0.2f * v;
  a[e] = v;
  atomicMax(&mkey[d], f2key(v));
}

// wave per dst node: single pass — w=exp(a[e]-m), den += w, acc += w*h[src]
__global__ __launch_bounds__(256) void k_aggregate2(
    const float* __restrict__ h, const float* __restrict__ a,
    const unsigned* __restrict__ mkey, const int* __restrict__ src,
    const int* __restrict__ off, const int* __restrict__ eid,
    const float* __restrict__ bias, float* __restrict__ out, int act) {
  int i = blockIdx.x * 4 + (threadIdx.x >> 6);
  int lane = threadIdx.x & 63;
  if (i >= NN) return;
  int s0 = off[i], s1 = off[i + 1];
  float m = key2f(mkey[i]);
  float den = 0.f, acc0 = 0.f, acc1 = 0.f;
  for (int p = s0; p < s1; ++p) {
    int e = eid[p];
    int s = src[e];
    float w = __expf(a[e] - m);
    den += w;
    float2 hv = *(const float2*)(h + (size_t)s * HID + 2 * lane);
    acc0 += w * hv.x;
    acc1 += w * hv.y;
  }
  {  // self-loop
    float w = __expf(a[EE + i] - m);
    den += w;
    float2 hv = *(const float2*)(h + (size_t)i * HID + 2 * lane);
    acc0 += w * hv.x;
    acc1 += w * hv.y;
  }
  float inv = 1.f / den;
  float o0 = acc0 * inv + bias[2 * lane];
  float o1 = acc1 * inv + bias[2 * lane + 1];
  if (act) {
    o0 = (o0 > 0.f) ? o0 : 0.01f * o0;
    o1 = (o1 > 0.f) ? o1 : 0.01f * o1;
  }
  out[(size_t)i * HID + 2 * lane] = o0;
  out[(size_t)i * HID + 2 * lane + 1] = o1;
}

// ---------------- virtual-node path ----------------

__global__ void k_vnreduce(const float* __restrict__ out, float* __restrict__ vnsum) {
  int d = threadIdx.x;  // 128 threads
  float acc = 0.f;
  for (int i = blockIdx.x; i < NN; i += gridDim.x)
    acc += out[(size_t)i * HID + d];
  atomicAdd(&vnsum[d], acc);
}

__global__ void k_mlp(const float* __restrict__ vnsum, const float* __restrict__ vn_w,
                      const float* __restrict__ w1, const float* __restrict__ b1,
                      const float* __restrict__ w2, const float* __restrict__ b2,
                      const float* __restrict__ w3, const float* __restrict__ b3,
                      const float* __restrict__ w4, const float* __restrict__ b4,
                      float* __restrict__ outv) {
  __shared__ float xb[HID], yb[HID];
  int t = threadIdx.x;
  xb[t] = vnsum[t] + vn_w[t];
  __syncthreads();
  const float* Ws[4] = {w1, w2, w3, w4};
  const float* Bs[4] = {b1, b2, b3, b4};
  float* cur = xb;
  float* nxt = yb;
  for (int l = 0; l < 4; ++l) {
    const float* W = Ws[l];
    const float* B = Bs[l];
    float acc = B[t];
    for (int d = 0; d < HID; ++d) acc += cur[d] * W[d * HID + t];
    nxt[t] = fmaxf(acc, 0.f);
    __syncthreads();
    float* tmp = cur; cur = nxt; nxt = tmp;
  }
  outv[t] = cur[t];
}

// ---------------- launch ----------------

extern "C" void kernel_launch(void* const* d_in, const int* in_sizes, int n_in,
                              void* d_out, int out_size, void* d_ws, size_t ws_size,
                              hipStream_t stream) {
  const float* x = (const float*)d_in[0];
  const int* ei = (const int*)d_in[1];
  const float* edge_attr = (const float*)d_in[2];
  const float *W[3], *as_[3], *ad_[3], *We[3], *ae[3], *bb[3];
  for (int l = 0; l < 3; ++l) {
    W[l]   = (const float*)d_in[3 + l * 6 + 0];
    as_[l] = (const float*)d_in[3 + l * 6 + 1];
    ad_[l] = (const float*)d_in[3 + l * 6 + 2];
    We[l]  = (const float*)d_in[3 + l * 6 + 3];
    ae[l]  = (const float*)d_in[3 + l * 6 + 4];
    bb[l]  = (const float*)d_in[3 + l * 6 + 5];
  }
  const float* vn_w = (const float*)d_in[21];
  const float* m1w1 = (const float*)d_in[22];
  const float* m1b1 = (const float*)d_in[23];
  const float* m1w2 = (const float*)d_in[24];
  const float* m1b2 = (const float*)d_in[25];
  const float* m2w1 = (const float*)d_in[26];
  const float* m2b1 = (const float*)d_in[27];
  const float* m2w2 = (const float*)d_in[28];
  const float* m2b2 = (const float*)d_in[29];
  const float* Wout = (const float*)d_in[30];
  const float* bout = (const float*)d_in[31];

  char* ws = (char*)d_ws;
  size_t o = 0;
  auto alloc = [&](size_t bytes) {
    o = (o + 255) & ~(size_t)255;
    void* p = ws + o;
    o += bytes;
    return p;
  };
  float* hbuf   = (float*)alloc((size_t)NN * HID * 4);
  float* outbuf = (float*)alloc((size_t)NN * HID * 4);
  float* lattr  = (float*)alloc((size_t)NN * ED * 4);
  float* esc    = (float*)alloc((size_t)3 * EB * 4);
  float* abuf   = (float*)alloc((size_t)EB * 4);
  float* hs     = (float*)alloc((size_t)NN * 4);
  float* hd     = (float*)alloc((size_t)NN * 4);
  unsigned* mkey = (unsigned*)alloc((size_t)NN * 4);
  float* vnsum  = (float*)alloc(HID * 4);
  float* weae   = (float*)alloc(3 * ED * 4);
  int* cnt      = (int*)alloc((size_t)NN * 4);
  int* off      = (int*)alloc((size_t)(NN + 1) * 4);
  int* cursor   = (int*)alloc((size_t)NN * 4);
  int* eid      = (int*)alloc((size_t)EE * 4);
  int* bsum     = (int*)alloc((size_t)SCAN_G * 4);
  int* bexc     = (int*)alloc((size_t)SCAN_G * 4);

  const int* srcv = ei;
  const int* dstv = ei + EE;

  k_zero<<<(NN + 255) / 256, 256, 0, stream>>>(cnt, vnsum);
  k_count<<<(EE + 255) / 256, 256, 0, stream>>>(dstv, cnt);
  k_scan1<<<SCAN_G, 256, 0, stream>>>(cnt, bsum);
  k_scan2<<<1, 256, 0, stream>>>(bsum, bexc, off);
  k_scan3<<<SCAN_G, 256, 0, stream>>>(cnt, bexc, off, cursor);
  k_scatter<<<(EE + 255) / 256, 256, 0, stream>>>(dstv, cursor, eid);
  k_loopattr<<<(NN + 3) / 4, 256, 0, stream>>>(edge_attr, off, eid, lattr);
  k_weae<<<1, 256, 0, stream>>>(We[0], We[1], We[2], ae[0], ae[1], ae[2], weae);
  k_esc<<<(EB + 255) / 256, 256, 0, stream>>>(edge_attr, lattr, weae, esc);

  const float* in_ptr = x;
  for (int l = 0; l < 3; ++l) {
    k_gemm128<<<(NN + 31) / 32, 256, 0, stream>>>(in_ptr, W[l], nullptr, hbuf, 0);
    k_hsd<<<(NN + 3) / 4, 256, 0, stream>>>(hbuf, as_[l], ad_[l], hs, hd, mkey);
    k_alpha<<<(EB + 255) / 256, 256, 0, stream>>>(
        hs, hd, esc + (size_t)l * EB, srcv, dstv, abuf, mkey);
    k_aggregate2<<<(NN + 3) / 4, 256, 0, stream>>>(
        hbuf, abuf, mkey, srcv, off, eid, bb[l], outbuf, (l > 0) ? 1 : 0);
    in_ptr = outbuf;
  }

  float* node_out = (float*)d_out;
  k_gemm128<<<(NN + 31) / 32, 256, 0, stream>>>(outbuf, Wout, bout, node_out, 1);
  k_vnreduce<<<256, 128, 0, stream>>>(outbuf, vnsum);
  k_mlp<<<1, 128, 0, stream>>>(vnsum, vn_w, m1w1, m1b1, m1w2, m1b2, m2w1, m2b1,
                               m2w2, m2b2, node_out + (size_t)NN * HID);
}

// Round 5
// 595.568 us; speedup vs baseline: 1.4456x; 1.0583x over previous
//
#include <hip/hip_runtime.h>

#define NN 50000
#define EE 400000
#define EB 450000   // EE + NN (edges incl. self-loops)
#define HID 128
#define ED 64
#define SCAN_G 196  // ceil(50000/256)

static __device__ __forceinline__ float wave_reduce_sum(float v) {
#pragma unroll
  for (int o = 32; o > 0; o >>= 1) v += __shfl_xor(v, o, 64);
  return v;
}

// monotone float<->uint key for atomicMax on floats (incl. negatives)
static __device__ __forceinline__ unsigned f2key(float f) {
  unsigned b = __float_as_uint(f);
  return (b & 0x80000000u) ? ~b : (b | 0x80000000u);
}
static __device__ __forceinline__ float key2f(unsigned k) {
  unsigned b = (k & 0x80000000u) ? (k & 0x7FFFFFFFu) : ~k;
  return __uint_as_float(b);
}

// exclusive prefix of v across 256 threads; s must hold >=256 ints.
// After return, s[255] holds the block total.
static __device__ __forceinline__ int block_excl_scan_256(int v, int* s) {
  int tid = threadIdx.x;
  s[tid] = v;
  __syncthreads();
  for (int d = 1; d < 256; d <<= 1) {
    int t = (tid >= d) ? s[tid - d] : 0;
    __syncthreads();
    s[tid] += t;
    __syncthreads();
  }
  return s[tid] - v;
}

// ---------------- setup kernels ----------------

__global__ void k_zero(int* __restrict__ cnt, float* __restrict__ vnsum) {
  int t = blockIdx.x * blockDim.x + threadIdx.x;
  if (t < NN) cnt[t] = 0;
  if (t < HID) vnsum[t] = 0.f;
}

__global__ void k_count(const int* __restrict__ dst, int* __restrict__ cnt) {
  int e = blockIdx.x * blockDim.x + threadIdx.x;
  if (e < EE) atomicAdd(&cnt[dst[e]], 1);
}

// phase 1: per-block sums
__global__ __launch_bounds__(256) void k_scan1(const int* __restrict__ cnt,
                                               int* __restrict__ bsum) {
  __shared__ int s[256];
  int idx = blockIdx.x * 256 + threadIdx.x;
  int v = (idx < NN) ? cnt[idx] : 0;
  s[threadIdx.x] = v;
  __syncthreads();
  for (int d = 128; d > 0; d >>= 1) {
    if (threadIdx.x < d) s[threadIdx.x] += s[threadIdx.x + d];
    __syncthreads();
  }
  if (threadIdx.x == 0) bsum[blockIdx.x] = s[0];
}

// phase 2: scan block sums (SCAN_G <= 256), write off[NN] = total
__global__ __launch_bounds__(256) void k_scan2(const int* __restrict__ bsum,
                                               int* __restrict__ bexc,
                                               int* __restrict__ off) {
  __shared__ int s[256];
  int t = threadIdx.x;
  int v = (t < SCAN_G) ? bsum[t] : 0;
  int exc = block_excl_scan_256(v, s);
  if (t < SCAN_G) bexc[t] = exc;
  if (t == 255) off[NN] = s[255];
}

// phase 3: per-block exclusive scan + block offset
__global__ __launch_bounds__(256) void k_scan3(const int* __restrict__ cnt,
                                               const int* __restrict__ bexc,
                                               int* __restrict__ off,
                                               int* __restrict__ cursor) {
  __shared__ int s[256];
  int idx = blockIdx.x * 256 + threadIdx.x;
  int v = (idx < NN) ? cnt[idx] : 0;
  int exc = block_excl_scan_256(v, s) + bexc[blockIdx.x];
  if (idx < NN) {
    off[idx] = exc;
    cursor[idx] = exc;
  }
}

__global__ void k_scatter(const int* __restrict__ dst, int* __restrict__ cursor,
                          int* __restrict__ eid) {
  int e = blockIdx.x * blockDim.x + threadIdx.x;
  if (e < EE) {
    int p = atomicAdd(&cursor[dst[e]], 1);
    eid[p] = e;
  }
}

// we_ae[l] = We_l @ ae_l  (64-vector per layer)
__global__ void k_weae(const float* __restrict__ We0, const float* __restrict__ We1,
                       const float* __restrict__ We2, const float* __restrict__ ae0,
                       const float* __restrict__ ae1, const float* __restrict__ ae2,
                       float* __restrict__ weae) {
  int t = threadIdx.x;
  if (t >= 192) return;
  int l = t >> 6, j = t & 63;
  const float* We = (l == 0) ? We0 : (l == 1) ? We1 : We2;
  const float* ae = (l == 0) ? ae0 : (l == 1) ? ae1 : ae2;
  float acc = 0.f;
  for (int k = 0; k < HID; ++k) acc += We[j * HID + k] * ae[k];
  weae[l * ED + j] = acc;
}

// per-REAL-edge scalar: esc[l][e] = ea_e . weae[l]
// thread per item, 16x float4 row load, weae staged in LDS (broadcast reads)
__global__ __launch_bounds__(256) void k_esc(
    const float* __restrict__ edge_attr, const float* __restrict__ weae,
    float* __restrict__ esc) {
  __shared__ float4 sw[3][16];
  int tid = threadIdx.x;
  if (tid < 48) ((float4*)sw)[tid] = ((const float4*)weae)[tid];
  __syncthreads();
  int item = blockIdx.x * 256 + tid;
  if (item >= EE) return;
  const float4* row = (const float4*)(edge_attr + (size_t)item * ED);
  float a0 = 0.f, a1 = 0.f, a2 = 0.f;
#pragma unroll
  for (int c = 0; c < 16; ++c) {
    float4 v = row[c];
    float4 w0 = sw[0][c], w1 = sw[1][c], w2 = sw[2][c];
    a0 += v.x * w0.x + v.y * w0.y + v.z * w0.z + v.w * w0.w;
    a1 += v.x * w1.x + v.y * w1.y + v.z * w1.z + v.w * w1.w;
    a2 += v.x * w2.x + v.y * w2.y + v.z * w2.z + v.w * w2.w;
  }
  esc[item] = a0;
  esc[(size_t)EB + item] = a1;
  esc[(size_t)2 * EB + item] = a2;
}

// self-loop esc via linearity: esc[l][EE+i] = (1/max(deg,1)) * sum esc[l][e]
// 16-lane group per node, lane-parallel over CSR edge list.
__global__ __launch_bounds__(256) void k_escself(
    const int* __restrict__ off, const int* __restrict__ eid,
    float* __restrict__ esc) {
  int i = blockIdx.x * 16 + (threadIdx.x >> 4);
  int g = threadIdx.x & 15;
  if (i >= NN) return;
  int s0 = off[i], s1 = off[i + 1];
  float a0 = 0.f, a1 = 0.f, a2 = 0.f;
  for (int p = s0 + g; p < s1; p += 16) {
    int e = eid[p];
    a0 += esc[e];
    a1 += esc[(size_t)EB + e];
    a2 += esc[(size_t)2 * EB + e];
  }
#pragma unroll
  for (int o = 8; o > 0; o >>= 1) {
    a0 += __shfl_xor(a0, o, 64);
    a1 += __shfl_xor(a1, o, 64);
    a2 += __shfl_xor(a2, o, 64);
  }
  if (g == 0) {
    int deg = s1 - s0;
    float inv = 1.f / (float)(deg > 1 ? deg : 1);
    esc[EE + i] = a0 * inv;
    esc[(size_t)EB + EE + i] = a1 * inv;
    esc[(size_t)2 * EB + EE + i] = a2 * inv;
  }
}

// ---------------- per-layer kernels ----------------

// O[NN x 128] = X[NN x 128] @ W[128 x 128] (+ bias). 32 rows per block.
__global__ __launch_bounds__(256) void k_gemm128(
    const float* __restrict__ X, const float* __restrict__ W,
    const float* __restrict__ bias, float* __restrict__ O, int use_bias) {
  __shared__ float sX[32][HID];
  __shared__ float sW[64][HID];
  int tid = threadIdx.x;
  int row0 = blockIdx.x * 32;
  {
    const float4* xs = (const float4*)(X + (size_t)row0 * HID);
    float4* xd = (float4*)(&sX[0][0]);
#pragma unroll
    for (int v = 0; v < 4; ++v) {
      int idx = tid + v * 256;       // 0..1023, 32 float4 per row
      int grow = row0 + (idx >> 5);
      xd[idx] = (grow < NN) ? xs[idx] : make_float4(0.f, 0.f, 0.f, 0.f);
    }
  }
  int colg = (tid & 31) * 4;
  int rowg = (tid >> 5) * 4;
  float acc[4][4] = {{0.f}};
  for (int kc = 0; kc < 2; ++kc) {
    __syncthreads();
    {
      const float4* wsp = (const float4*)(W + (size_t)kc * 64 * HID);
      float4* wd = (float4*)(&sW[0][0]);
#pragma unroll
      for (int v = 0; v < 8; ++v) wd[tid + v * 256] = wsp[tid + v * 256];
    }
    __syncthreads();
#pragma unroll 8
    for (int k = 0; k < 64; ++k) {
      float4 wv = *(const float4*)(&sW[k][colg]);
#pragma unroll
      for (int r = 0; r < 4; ++r) {
        float xv = sX[rowg + r][kc * 64 + k];
        acc[r][0] += xv * wv.x;
        acc[r][1] += xv * wv.y;
        acc[r][2] += xv * wv.z;
        acc[r][3] += xv * wv.w;
      }
    }
  }
#pragma unroll
  for (int r = 0; r < 4; ++r) {
    int grow = row0 + rowg + r;
    if (grow < NN) {
      float4 o;
      o.x = acc[r][0]; o.y = acc[r][1]; o.z = acc[r][2]; o.w = acc[r][3];
      if (use_bias) {
        o.x += bias[colg + 0];
        o.y += bias[colg + 1];
        o.z += bias[colg + 2];
        o.w += bias[colg + 3];
      }
      *(float4*)(O + (size_t)grow * HID + colg) = o;
    }
  }
}

// hs[i] = h[i].a_s ; hd[i] = h[i].a_d ; mkey[i] = 0   (wave per node)
__global__ __launch_bounds__(256) void k_hsd(
    const float* __restrict__ h, const float* __restrict__ as_,
    const float* __restrict__ ad_, float* __restrict__ hs,
    float* __restrict__ hd, unsigned* __restrict__ mkey) {
  int i = blockIdx.x * 4 + (threadIdx.x >> 6);
  int lane = threadIdx.x & 63;
  if (i >= NN) return;
  float v0 = h[(size_t)i * HID + lane];
  float v1 = h[(size_t)i * HID + 64 + lane];
  float s = wave_reduce_sum(v0 * as_[lane] + v1 * as_[64 + lane]);
  float d = wave_reduce_sum(v0 * ad_[lane] + v1 * ad_[64 + lane]);
  if (lane == 0) {
    hs[i] = s;
    hd[i] = d;
    mkey[i] = 0u;
  }
}

// edge-parallel: a[e] = leaky(hs[src]+hd[dst]+esc[e]); atomicMax key per dst.
// items [EE, EB) are self-loops of node i = e - EE.
__global__ __launch_bounds__(256) void k_alpha(
    const float* __restrict__ hs, const float* __restrict__ hd,
    const float* __restrict__ escl, const int* __restrict__ src,
    const int* __restrict__ dst, float* __restrict__ a,
    unsigned* __restrict__ mkey) {
  int e = blockIdx.x * blockDim.x + threadIdx.x;
  if (e >= EB) return;
  int s, d;
  if (e < EE) {
    s = src[e];
    d = dst[e];
  } else {
    s = d = e - EE;
  }
  float v = hs[s] + hd[d] + escl[e];
  v = (v > 0.f) ? v : 0.2f * v;
  a[e] = v;
  atomicMax(&mkey[d], f2key(v));
}

// wave per dst node: single pass — w=exp(a[e]-m), den += w, acc += w*h[src]
__global__ __launch_bounds__(256) void k_aggregate2(
    const float* __restrict__ h, const float* __restrict__ a,
    const unsigned* __restrict__ mkey, const int* __restrict__ src,
    const int* __restrict__ off, const int* __restrict__ eid,
    const float* __restrict__ bias, float* __restrict__ out, int act) {
  int i = blockIdx.x * 4 + (threadIdx.x >> 6);
  int lane = threadIdx.x & 63;
  if (i >= NN) return;
  int s0 = off[i], s1 = off[i + 1];
  float m = key2f(mkey[i]);
  float den = 0.f, acc0 = 0.f, acc1 = 0.f;
  for (int p = s0; p < s1; ++p) {
    int e = eid[p];
    int s = src[e];
    float w = __expf(a[e] - m);
    den += w;
    float2 hv = *(const float2*)(h + (size_t)s * HID + 2 * lane);
    acc0 += w * hv.x;
    acc1 += w * hv.y;
  }
  {  // self-loop
    float w = __expf(a[EE + i] - m);
    den += w;
    float2 hv = *(const float2*)(h + (size_t)i * HID + 2 * lane);
    acc0 += w * hv.x;
    acc1 += w * hv.y;
  }
  float inv = 1.f / den;
  float o0 = acc0 * inv + bias[2 * lane];
  float o1 = acc1 * inv + bias[2 * lane + 1];
  if (act) {
    o0 = (o0 > 0.f) ? o0 : 0.01f * o0;
    o1 = (o1 > 0.f) ? o1 : 0.01f * o1;
  }
  out[(size_t)i * HID + 2 * lane] = o0;
  out[(size_t)i * HID + 2 * lane + 1] = o1;
}

// ---------------- virtual-node path ----------------

__global__ void k_vnreduce(const float* __restrict__ out, float* __restrict__ vnsum) {
  int d = threadIdx.x;  // 128 threads
  float acc = 0.f;
  for (int i = blockIdx.x; i < NN; i += gridDim.x)
    acc += out[(size_t)i * HID + d];
  atomicAdd(&vnsum[d], acc);
}

__global__ void k_mlp(const float* __restrict__ vnsum, const float* __restrict__ vn_w,
                      const float* __restrict__ w1, const float* __restrict__ b1,
                      const float* __restrict__ w2, const float* __restrict__ b2,
                      const float* __restrict__ w3, const float* __restrict__ b3,
                      const float* __restrict__ w4, const float* __restrict__ b4,
                      float* __restrict__ outv) {
  __shared__ float xb[HID], yb[HID];
  int t = threadIdx.x;
  xb[t] = vnsum[t] + vn_w[t];
  __syncthreads();
  const float* Ws[4] = {w1, w2, w3, w4};
  const float* Bs[4] = {b1, b2, b3, b4};
  float* cur = xb;
  float* nxt = yb;
  for (int l = 0; l < 4; ++l) {
    const float* W = Ws[l];
    const float* B = Bs[l];
    float acc = B[t];
    for (int d = 0; d < HID; ++d) acc += cur[d] * W[d * HID + t];
    nxt[t] = fmaxf(acc, 0.f);
    __syncthreads();
    float* tmp = cur; cur = nxt; nxt = tmp;
  }
  outv[t] = cur[t];
}

// ---------------- launch ----------------

extern "C" void kernel_launch(void* const* d_in, const int* in_sizes, int n_in,
                              void* d_out, int out_size, void* d_ws, size_t ws_size,
                              hipStream_t stream) {
  const float* x = (const float*)d_in[0];
  const int* ei = (const int*)d_in[1];
  const float* edge_attr = (const float*)d_in[2];
  const float *W[3], *as_[3], *ad_[3], *We[3], *ae[3], *bb[3];
  for (int l = 0; l < 3; ++l) {
    W[l]   = (const float*)d_in[3 + l * 6 + 0];
    as_[l] = (const float*)d_in[3 + l * 6 + 1];
    ad_[l] = (const float*)d_in[3 + l * 6 + 2];
    We[l]  = (const float*)d_in[3 + l * 6 + 3];
    ae[l]  = (const float*)d_in[3 + l * 6 + 4];
    bb[l]  = (const float*)d_in[3 + l * 6 + 5];
  }
  const float* vn_w = (const float*)d_in[21];
  const float* m1w1 = (const float*)d_in[22];
  const float* m1b1 = (const float*)d_in[23];
  const float* m1w2 = (const float*)d_in[24];
  const float* m1b2 = (const float*)d_in[25];
  const float* m2w1 = (const float*)d_in[26];
  const float* m2b1 = (const float*)d_in[27];
  const float* m2w2 = (const float*)d_in[28];
  const float* m2b2 = (const float*)d_in[29];
  const float* Wout = (const float*)d_in[30];
  const float* bout = (const float*)d_in[31];

  char* ws = (char*)d_ws;
  size_t o = 0;
  auto alloc = [&](size_t bytes) {
    o = (o + 255) & ~(size_t)255;
    void* p = ws + o;
    o += bytes;
    return p;
  };
  float* hbuf   = (float*)alloc((size_t)NN * HID * 4);
  float* outbuf = (float*)alloc((size_t)NN * HID * 4);
  float* esc    = (float*)alloc((size_t)3 * EB * 4);
  float* abuf   = (float*)alloc((size_t)EB * 4);
  float* hs     = (float*)alloc((size_t)NN * 4);
  float* hd     = (float*)alloc((size_t)NN * 4);
  unsigned* mkey = (unsigned*)alloc((size_t)NN * 4);
  float* vnsum  = (float*)alloc(HID * 4);
  float* weae   = (float*)alloc(3 * ED * 4);
  int* cnt      = (int*)alloc((size_t)NN * 4);
  int* off      = (int*)alloc((size_t)(NN + 1) * 4);
  int* cursor   = (int*)alloc((size_t)NN * 4);
  int* eid      = (int*)alloc((size_t)EE * 4);
  int* bsum     = (int*)alloc((size_t)SCAN_G * 4);
  int* bexc     = (int*)alloc((size_t)SCAN_G * 4);

  const int* srcv = ei;
  const int* dstv = ei + EE;

  k_zero<<<(NN + 255) / 256, 256, 0, stream>>>(cnt, vnsum);
  k_count<<<(EE + 255) / 256, 256, 0, stream>>>(dstv, cnt);
  k_scan1<<<SCAN_G, 256, 0, stream>>>(cnt, bsum);
  k_scan2<<<1, 256, 0, stream>>>(bsum, bexc, off);
  k_scan3<<<SCAN_G, 256, 0, stream>>>(cnt, bexc, off, cursor);
  k_scatter<<<(EE + 255) / 256, 256, 0, stream>>>(dstv, cursor, eid);
  k_weae<<<1, 256, 0, stream>>>(We[0], We[1], We[2], ae[0], ae[1], ae[2], weae);
  k_esc<<<(EE + 255) / 256, 256, 0, stream>>>(edge_attr, weae, esc);
  k_escself<<<(NN + 15) / 16, 256, 0, stream>>>(off, eid, esc);

  const float* in_ptr = x;
  for (int l = 0; l < 3; ++l) {
    k_gemm128<<<(NN + 31) / 32, 256, 0, stream>>>(in_ptr, W[l], nullptr, hbuf, 0);
    k_hsd<<<(NN + 3) / 4, 256, 0, stream>>>(hbuf, as_[l], ad_[l], hs, hd, mkey);
    k_alpha<<<(EB + 255) / 256, 256, 0, stream>>>(
        hs, hd, esc + (size_t)l * EB, srcv, dstv, abuf, mkey);
    k_aggregate2<<<(NN + 3) / 4, 256, 0, stream>>>(
        hbuf, abuf, mkey, srcv, off, eid, bb[l], outbuf, (l > 0) ? 1 : 0);
    in_ptr = outbuf;
  }

  float* node_out = (float*)d_out;
  k_gemm128<<<(NN + 31) / 32, 256, 0, stream>>>(outbuf, Wout, bout, node_out, 1);
  k_vnreduce<<<256, 128, 0, stream>>>(outbuf, vnsum);
  k_mlp<<<1, 128, 0, stream>>>(vnsum, vn_w, m1w1, m1b1, m1w2, m1b2, m2w1, m2b1,
                               m2w2, m2b2, node_out + (size_t)NN * HID);
}

// Round 6
// 497.517 us; speedup vs baseline: 1.7306x; 1.1971x over previous
//
#include <hip/hip_runtime.h>

#define NN 50000
#define EE 400000
#define EB 450000   // EE + NN (edges incl. self-loops)
#define HID 128
#define ED 64
#define SCAN_G 196  // ceil(50000/256)

static __device__ __forceinline__ float wave_reduce_sum(float v) {
#pragma unroll
  for (int o = 32; o > 0; o >>= 1) v += __shfl_xor(v, o, 64);
  return v;
}

// monotone float<->uint key for atomicMax on floats (incl. negatives)
static __device__ __forceinline__ unsigned f2key(float f) {
  unsigned b = __float_as_uint(f);
  return (b & 0x80000000u) ? ~b : (b | 0x80000000u);
}
static __device__ __forceinline__ float key2f(unsigned k) {
  unsigned b = (k & 0x80000000u) ? (k & 0x7FFFFFFFu) : ~k;
  return __uint_as_float(b);
}

// exclusive prefix of v across 256 threads; s must hold >=256 ints.
// After return, s[255] holds the block total.
static __device__ __forceinline__ int block_excl_scan_256(int v, int* s) {
  int tid = threadIdx.x;
  s[tid] = v;
  __syncthreads();
  for (int d = 1; d < 256; d <<= 1) {
    int t = (tid >= d) ? s[tid - d] : 0;
    __syncthreads();
    s[tid] += t;
    __syncthreads();
  }
  return s[tid] - v;
}

// ---------------- setup kernels ----------------

__global__ void k_zero(int* __restrict__ cnt, float* __restrict__ vnsum) {
  int t = blockIdx.x * blockDim.x + threadIdx.x;
  if (t < NN) cnt[t] = 0;
  if (t < HID) vnsum[t] = 0.f;
}

__global__ void k_count(const int* __restrict__ dst, int* __restrict__ cnt) {
  int e = blockIdx.x * blockDim.x + threadIdx.x;
  if (e < EE) atomicAdd(&cnt[dst[e]], 1);
}

// phase 1: per-block sums
__global__ __launch_bounds__(256) void k_scan1(const int* __restrict__ cnt,
                                               int* __restrict__ bsum) {
  __shared__ int s[256];
  int idx = blockIdx.x * 256 + threadIdx.x;
  int v = (idx < NN) ? cnt[idx] : 0;
  s[threadIdx.x] = v;
  __syncthreads();
  for (int d = 128; d > 0; d >>= 1) {
    if (threadIdx.x < d) s[threadIdx.x] += s[threadIdx.x + d];
    __syncthreads();
  }
  if (threadIdx.x == 0) bsum[blockIdx.x] = s[0];
}

// phase 2: scan block sums (SCAN_G <= 256), write off[NN] = total
__global__ __launch_bounds__(256) void k_scan2(const int* __restrict__ bsum,
                                               int* __restrict__ bexc,
                                               int* __restrict__ off) {
  __shared__ int s[256];
  int t = threadIdx.x;
  int v = (t < SCAN_G) ? bsum[t] : 0;
  int exc = block_excl_scan_256(v, s);
  if (t < SCAN_G) bexc[t] = exc;
  if (t == 255) off[NN] = s[255];
}

// phase 3: per-block exclusive scan + block offset
__global__ __launch_bounds__(256) void k_scan3(const int* __restrict__ cnt,
                                               const int* __restrict__ bexc,
                                               int* __restrict__ off,
                                               int* __restrict__ cursor) {
  __shared__ int s[256];
  int idx = blockIdx.x * 256 + threadIdx.x;
  int v = (idx < NN) ? cnt[idx] : 0;
  int exc = block_excl_scan_256(v, s) + bexc[blockIdx.x];
  if (idx < NN) {
    off[idx] = exc;
    cursor[idx] = exc;
  }
}

// scatter: CSR edge list + src-in-CSR-order + edge->CSR-position map
__global__ void k_scatter(const int* __restrict__ src, const int* __restrict__ dst,
                          int* __restrict__ cursor, int* __restrict__ eid,
                          int* __restrict__ sperm, int* __restrict__ epos) {
  int e = blockIdx.x * blockDim.x + threadIdx.x;
  if (e < EE) {
    int p = atomicAdd(&cursor[dst[e]], 1);
    eid[p] = e;
    sperm[p] = src[e];
    epos[e] = p;
  }
}

// we_ae[l] = We_l @ ae_l  (64-vector per layer)
__global__ void k_weae(const float* __restrict__ We0, const float* __restrict__ We1,
                       const float* __restrict__ We2, const float* __restrict__ ae0,
                       const float* __restrict__ ae1, const float* __restrict__ ae2,
                       float* __restrict__ weae) {
  int t = threadIdx.x;
  if (t >= 192) return;
  int l = t >> 6, j = t & 63;
  const float* We = (l == 0) ? We0 : (l == 1) ? We1 : We2;
  const float* ae = (l == 0) ? ae0 : (l == 1) ? ae1 : ae2;
  float acc = 0.f;
  for (int k = 0; k < HID; ++k) acc += We[j * HID + k] * ae[k];
  weae[l * ED + j] = acc;
}

// per-REAL-edge scalar: esc[l][e] = ea_e . weae[l]
// thread per item, 16x float4 row load, weae staged in LDS (broadcast reads)
__global__ __launch_bounds__(256) void k_esc(
    const float* __restrict__ edge_attr, const float* __restrict__ weae,
    float* __restrict__ esc) {
  __shared__ float4 sw[3][16];
  int tid = threadIdx.x;
  if (tid < 48) ((float4*)sw)[tid] = ((const float4*)weae)[tid];
  __syncthreads();
  int item = blockIdx.x * 256 + tid;
  if (item >= EE) return;
  const float4* row = (const float4*)(edge_attr + (size_t)item * ED);
  float a0 = 0.f, a1 = 0.f, a2 = 0.f;
#pragma unroll
  for (int c = 0; c < 16; ++c) {
    float4 v = row[c];
    float4 w0 = sw[0][c], w1 = sw[1][c], w2 = sw[2][c];
    a0 += v.x * w0.x + v.y * w0.y + v.z * w0.z + v.w * w0.w;
    a1 += v.x * w1.x + v.y * w1.y + v.z * w1.z + v.w * w1.w;
    a2 += v.x * w2.x + v.y * w2.y + v.z * w2.z + v.w * w2.w;
  }
  esc[item] = a0;
  esc[(size_t)EB + item] = a1;
  esc[(size_t)2 * EB + item] = a2;
}

// self-loop esc via linearity: esc[l][EE+i] = (1/max(deg,1)) * sum esc[l][e]
// 16-lane group per node, lane-parallel over CSR edge list.
__global__ __launch_bounds__(256) void k_escself(
    const int* __restrict__ off, const int* __restrict__ eid,
    float* __restrict__ esc) {
  int i = blockIdx.x * 16 + (threadIdx.x >> 4);
  int g = threadIdx.x & 15;
  if (i >= NN) return;
  int s0 = off[i], s1 = off[i + 1];
  float a0 = 0.f, a1 = 0.f, a2 = 0.f;
  for (int p = s0 + g; p < s1; p += 16) {
    int e = eid[p];
    a0 += esc[e];
    a1 += esc[(size_t)EB + e];
    a2 += esc[(size_t)2 * EB + e];
  }
#pragma unroll
  for (int o = 8; o > 0; o >>= 1) {
    a0 += __shfl_xor(a0, o, 64);
    a1 += __shfl_xor(a1, o, 64);
    a2 += __shfl_xor(a2, o, 64);
  }
  if (g == 0) {
    int deg = s1 - s0;
    float inv = 1.f / (float)(deg > 1 ? deg : 1);
    esc[EE + i] = a0 * inv;
    esc[(size_t)EB + EE + i] = a1 * inv;
    esc[(size_t)2 * EB + EE + i] = a2 * inv;
  }
}

// ---------------- per-layer kernels ----------------

// O[NN x 128] = X[NN x 128] @ W[128 x 128] (+ bias). 32 rows per block.
__global__ __launch_bounds__(256) void k_gemm128(
    const float* __restrict__ X, const float* __restrict__ W,
    const float* __restrict__ bias, float* __restrict__ O, int use_bias) {
  __shared__ float sX[32][HID];
  __shared__ float sW[64][HID];
  int tid = threadIdx.x;
  int row0 = blockIdx.x * 32;
  {
    const float4* xs = (const float4*)(X + (size_t)row0 * HID);
    float4* xd = (float4*)(&sX[0][0]);
#pragma unroll
    for (int v = 0; v < 4; ++v) {
      int idx = tid + v * 256;       // 0..1023, 32 float4 per row
      int grow = row0 + (idx >> 5);
      xd[idx] = (grow < NN) ? xs[idx] : make_float4(0.f, 0.f, 0.f, 0.f);
    }
  }
  int colg = (tid & 31) * 4;
  int rowg = (tid >> 5) * 4;
  float acc[4][4] = {{0.f}};
  for (int kc = 0; kc < 2; ++kc) {
    __syncthreads();
    {
      const float4* wsp = (const float4*)(W + (size_t)kc * 64 * HID);
      float4* wd = (float4*)(&sW[0][0]);
#pragma unroll
      for (int v = 0; v < 8; ++v) wd[tid + v * 256] = wsp[tid + v * 256];
    }
    __syncthreads();
#pragma unroll 8
    for (int k = 0; k < 64; ++k) {
      float4 wv = *(const float4*)(&sW[k][colg]);
#pragma unroll
      for (int r = 0; r < 4; ++r) {
        float xv = sX[rowg + r][kc * 64 + k];
        acc[r][0] += xv * wv.x;
        acc[r][1] += xv * wv.y;
        acc[r][2] += xv * wv.z;
        acc[r][3] += xv * wv.w;
      }
    }
  }
#pragma unroll
  for (int r = 0; r < 4; ++r) {
    int grow = row0 + rowg + r;
    if (grow < NN) {
      float4 o;
      o.x = acc[r][0]; o.y = acc[r][1]; o.z = acc[r][2]; o.w = acc[r][3];
      if (use_bias) {
        o.x += bias[colg + 0];
        o.y += bias[colg + 1];
        o.z += bias[colg + 2];
        o.w += bias[colg + 3];
      }
      *(float4*)(O + (size_t)grow * HID + colg) = o;
    }
  }
}

// hs[i] = h[i].a_s ; hd[i] = h[i].a_d ; mkey[i] = 0   (wave per node)
__global__ __launch_bounds__(256) void k_hsd(
    const float* __restrict__ h, const float* __restrict__ as_,
    const float* __restrict__ ad_, float* __restrict__ hs,
    float* __restrict__ hd, unsigned* __restrict__ mkey) {
  int i = blockIdx.x * 4 + (threadIdx.x >> 6);
  int lane = threadIdx.x & 63;
  if (i >= NN) return;
  float v0 = h[(size_t)i * HID + lane];
  float v1 = h[(size_t)i * HID + 64 + lane];
  float s = wave_reduce_sum(v0 * as_[lane] + v1 * as_[64 + lane]);
  float d = wave_reduce_sum(v0 * ad_[lane] + v1 * ad_[64 + lane]);
  if (lane == 0) {
    hs[i] = s;
    hd[i] = d;
    mkey[i] = 0u;
  }
}

// edge-parallel: alpha = leaky(hs[src]+hd[dst]+esc[e]); atomicMax key per dst.
// Real edges write alpha into CSR slot epos[e]; self-loops into [EE, EB).
__global__ __launch_bounds__(256) void k_alpha(
    const float* __restrict__ hs, const float* __restrict__ hd,
    const float* __restrict__ escl, const int* __restrict__ src,
    const int* __restrict__ dst, const int* __restrict__ epos,
    float* __restrict__ acsr, unsigned* __restrict__ mkey) {
  int e = blockIdx.x * blockDim.x + threadIdx.x;
  if (e >= EB) return;
  int s, d, idx;
  if (e < EE) {
    s = src[e];
    d = dst[e];
    idx = epos[e];
  } else {
    s = d = e - EE;
    idx = e;
  }
  float v = hs[s] + hd[d] + escl[e];
  v = (v > 0.f) ? v : 0.2f * v;
  acsr[idx] = v;
  atomicMax(&mkey[d], f2key(v));
}

// wave per dst node, 4 edge-groups x 16 dim-lanes:
// group g handles edge t0+g; lane j covers dims [8j, 8j+8).
__global__ __launch_bounds__(256) void k_aggregate3(
    const float* __restrict__ h, const float* __restrict__ acsr,
    const unsigned* __restrict__ mkey, const int* __restrict__ sperm,
    const int* __restrict__ off, const float* __restrict__ bias,
    float* __restrict__ out, int act) {
  int i = blockIdx.x * 4 + (threadIdx.x >> 6);
  int lane = threadIdx.x & 63;
  if (i >= NN) return;
  int g = lane >> 4;
  int j = lane & 15;
  int s0 = off[i];
  int deg = off[i + 1] - s0;
  int nt = deg + 1;  // + self-loop
  float m = key2f(mkey[i]);
  float den = 0.f;
  float4 acc0 = make_float4(0.f, 0.f, 0.f, 0.f);
  float4 acc1 = make_float4(0.f, 0.f, 0.f, 0.f);
  for (int t0 = 0; t0 < nt; t0 += 4) {
    int t = t0 + g;
    if (t < nt) {
      int s;
      float av;
      if (t < deg) {
        s = sperm[s0 + t];
        av = acsr[s0 + t];
      } else {
        s = i;
        av = acsr[EE + i];
      }
      float w = __expf(av - m);
      den += w;
      const float4* hp = (const float4*)(h + (size_t)s * HID + j * 8);
      float4 v0 = hp[0], v1 = hp[1];
      acc0.x += w * v0.x; acc0.y += w * v0.y; acc0.z += w * v0.z; acc0.w += w * v0.w;
      acc1.x += w * v1.x; acc1.y += w * v1.y; acc1.z += w * v1.z; acc1.w += w * v1.w;
    }
  }
  // reduce across the 4 groups (lanes j, j+16, j+32, j+48)
#pragma unroll
  for (int o = 16; o <= 32; o <<= 1) {
    acc0.x += __shfl_xor(acc0.x, o, 64);
    acc0.y += __shfl_xor(acc0.y, o, 64);
    acc0.z += __shfl_xor(acc0.z, o, 64);
    acc0.w += __shfl_xor(acc0.w, o, 64);
    acc1.x += __shfl_xor(acc1.x, o, 64);
    acc1.y += __shfl_xor(acc1.y, o, 64);
    acc1.z += __shfl_xor(acc1.z, o, 64);
    acc1.w += __shfl_xor(acc1.w, o, 64);
    den += __shfl_xor(den, o, 64);
  }
  if (g == 0) {
    float inv = 1.f / den;
    const float4* bp = (const float4*)(bias + j * 8);
    float4 b0 = bp[0], b1 = bp[1];
    float4 o0, o1;
    o0.x = acc0.x * inv + b0.x; o0.y = acc0.y * inv + b0.y;
    o0.z = acc0.z * inv + b0.z; o0.w = acc0.w * inv + b0.w;
    o1.x = acc1.x * inv + b1.x; o1.y = acc1.y * inv + b1.y;
    o1.z = acc1.z * inv + b1.z; o1.w = acc1.w * inv + b1.w;
    if (act) {
      o0.x = (o0.x > 0.f) ? o0.x : 0.01f * o0.x;
      o0.y = (o0.y > 0.f) ? o0.y : 0.01f * o0.y;
      o0.z = (o0.z > 0.f) ? o0.z : 0.01f * o0.z;
      o0.w = (o0.w > 0.f) ? o0.w : 0.01f * o0.w;
      o1.x = (o1.x > 0.f) ? o1.x : 0.01f * o1.x;
      o1.y = (o1.y > 0.f) ? o1.y : 0.01f * o1.y;
      o1.z = (o1.z > 0.f) ? o1.z : 0.01f * o1.z;
      o1.w = (o1.w > 0.f) ? o1.w : 0.01f * o1.w;
    }
    float4* op = (float4*)(out + (size_t)i * HID + j * 8);
    op[0] = o0;
    op[1] = o1;
  }
}

// ---------------- virtual-node path ----------------

__global__ void k_vnreduce(const float* __restrict__ out, float* __restrict__ vnsum) {
  int d = threadIdx.x;  // 128 threads
  float acc = 0.f;
  for (int i = blockIdx.x; i < NN; i += gridDim.x)
    acc += out[(size_t)i * HID + d];
  atomicAdd(&vnsum[d], acc);
}

__global__ void k_mlp(const float* __restrict__ vnsum, const float* __restrict__ vn_w,
                      const float* __restrict__ w1, const float* __restrict__ b1,
                      const float* __restrict__ w2, const float* __restrict__ b2,
                      const float* __restrict__ w3, const float* __restrict__ b3,
                      const float* __restrict__ w4, const float* __restrict__ b4,
                      float* __restrict__ outv) {
  __shared__ float xb[HID], yb[HID];
  int t = threadIdx.x;
  xb[t] = vnsum[t] + vn_w[t];
  __syncthreads();
  const float* Ws[4] = {w1, w2, w3, w4};
  const float* Bs[4] = {b1, b2, b3, b4};
  float* cur = xb;
  float* nxt = yb;
  for (int l = 0; l < 4; ++l) {
    const float* W = Ws[l];
    const float* B = Bs[l];
    float acc = B[t];
    for (int d = 0; d < HID; ++d) acc += cur[d] * W[d * HID + t];
    nxt[t] = fmaxf(acc, 0.f);
    __syncthreads();
    float* tmp = cur; cur = nxt; nxt = tmp;
  }
  outv[t] = cur[t];
}

// ---------------- launch ----------------

extern "C" void kernel_launch(void* const* d_in, const int* in_sizes, int n_in,
                              void* d_out, int out_size, void* d_ws, size_t ws_size,
                              hipStream_t stream) {
  const float* x = (const float*)d_in[0];
  const int* ei = (const int*)d_in[1];
  const float* edge_attr = (const float*)d_in[2];
  const float *W[3], *as_[3], *ad_[3], *We[3], *ae[3], *bb[3];
  for (int l = 0; l < 3; ++l) {
    W[l]   = (const float*)d_in[3 + l * 6 + 0];
    as_[l] = (const float*)d_in[3 + l * 6 + 1];
    ad_[l] = (const float*)d_in[3 + l * 6 + 2];
    We[l]  = (const float*)d_in[3 + l * 6 + 3];
    ae[l]  = (const float*)d_in[3 + l * 6 + 4];
    bb[l]  = (const float*)d_in[3 + l * 6 + 5];
  }
  const float* vn_w = (const float*)d_in[21];
  const float* m1w1 = (const float*)d_in[22];
  const float* m1b1 = (const float*)d_in[23];
  const float* m1w2 = (const float*)d_in[24];
  const float* m1b2 = (const float*)d_in[25];
  const float* m2w1 = (const float*)d_in[26];
  const float* m2b1 = (const float*)d_in[27];
  const float* m2w2 = (const float*)d_in[28];
  const float* m2b2 = (const float*)d_in[29];
  const float* Wout = (const float*)d_in[30];
  const float* bout = (const float*)d_in[31];

  char* ws = (char*)d_ws;
  size_t o = 0;
  auto alloc = [&](size_t bytes) {
    o = (o + 255) & ~(size_t)255;
    void* p = ws + o;
    o += bytes;
    return p;
  };
  float* hbuf   = (float*)alloc((size_t)NN * HID * 4);
  float* outbuf = (float*)alloc((size_t)NN * HID * 4);
  float* esc    = (float*)alloc((size_t)3 * EB * 4);
  float* acsr   = (float*)alloc((size_t)EB * 4);
  float* hs     = (float*)alloc((size_t)NN * 4);
  float* hd     = (float*)alloc((size_t)NN * 4);
  unsigned* mkey = (unsigned*)alloc((size_t)NN * 4);
  float* vnsum  = (float*)alloc(HID * 4);
  float* weae   = (float*)alloc(3 * ED * 4);
  int* cnt      = (int*)alloc((size_t)NN * 4);
  int* off      = (int*)alloc((size_t)(NN + 1) * 4);
  int* cursor   = (int*)alloc((size_t)NN * 4);
  int* eid      = (int*)alloc((size_t)EE * 4);
  int* sperm    = (int*)alloc((size_t)EE * 4);
  int* epos     = (int*)alloc((size_t)EE * 4);
  int* bsum     = (int*)alloc((size_t)SCAN_G * 4);
  int* bexc     = (int*)alloc((size_t)SCAN_G * 4);

  const int* srcv = ei;
  const int* dstv = ei + EE;

  k_zero<<<(NN + 255) / 256, 256, 0, stream>>>(cnt, vnsum);
  k_count<<<(EE + 255) / 256, 256, 0, stream>>>(dstv, cnt);
  k_scan1<<<SCAN_G, 256, 0, stream>>>(cnt, bsum);
  k_scan2<<<1, 256, 0, stream>>>(bsum, bexc, off);
  k_scan3<<<SCAN_G, 256, 0, stream>>>(cnt, bexc, off, cursor);
  k_scatter<<<(EE + 255) / 256, 256, 0, stream>>>(srcv, dstv, cursor, eid, sperm,
                                                  epos);
  k_weae<<<1, 256, 0, stream>>>(We[0], We[1], We[2], ae[0], ae[1], ae[2], weae);
  k_esc<<<(EE + 255) / 256, 256, 0, stream>>>(edge_attr, weae, esc);
  k_escself<<<(NN + 15) / 16, 256, 0, stream>>>(off, eid, esc);

  const float* in_ptr = x;
  for (int l = 0; l < 3; ++l) {
    k_gemm128<<<(NN + 31) / 32, 256, 0, stream>>>(in_ptr, W[l], nullptr, hbuf, 0);
    k_hsd<<<(NN + 3) / 4, 256, 0, stream>>>(hbuf, as_[l], ad_[l], hs, hd, mkey);
    k_alpha<<<(EB + 255) / 256, 256, 0, stream>>>(
        hs, hd, esc + (size_t)l * EB, srcv, dstv, epos, acsr, mkey);
    k_aggregate3<<<(NN + 3) / 4, 256, 0, stream>>>(
        hbuf, acsr, mkey, sperm, off, bb[l], outbuf, (l > 0) ? 1 : 0);
    in_ptr = outbuf;
  }

  float* node_out = (float*)d_out;
  k_gemm128<<<(NN + 31) / 32, 256, 0, stream>>>(outbuf, Wout, bout, node_out, 1);
  k_vnreduce<<<256, 128, 0, stream>>>(outbuf, vnsum);
  k_mlp<<<1, 128, 0, stream>>>(vnsum, vn_w, m1w1, m1b1, m1w2, m1b2, m2w1, m2b1,
                               m2w2, m2b2, node_out + (size_t)NN * HID);
}

// Round 7
// 405.091 us; speedup vs baseline: 2.1254x; 1.2282x over previous
//
#include <hip/hip_runtime.h>

#define NN 50000
#define EE 400000
#define HID 128
#define ED 64
#define SCAN_G 196  // ceil(50000/256)

typedef __attribute__((ext_vector_type(8))) unsigned short ushort8_t;

// bf16 pack/unpack (RNE; values are finite)
static __device__ __forceinline__ unsigned short f2bf(float f) {
  unsigned u = __float_as_uint(f);
  unsigned r = (u + 0x7FFFu + ((u >> 16) & 1u)) >> 16;
  return (unsigned short)r;
}
static __device__ __forceinline__ float bf2f(unsigned short b) {
  return __uint_as_float((unsigned)b << 16);
}

// exclusive prefix of v across 256 threads; s must hold >=256 ints.
// After return, s[255] holds the block total.
static __device__ __forceinline__ int block_excl_scan_256(int v, int* s) {
  int tid = threadIdx.x;
  s[tid] = v;
  __syncthreads();
  for (int d = 1; d < 256; d <<= 1) {
    int t = (tid >= d) ? s[tid - d] : 0;
    __syncthreads();
    s[tid] += t;
    __syncthreads();
  }
  return s[tid] - v;
}

// ---------------- setup kernels ----------------

__global__ void k_zero(int* __restrict__ cnt, float* __restrict__ vnsum) {
  int t = blockIdx.x * blockDim.x + threadIdx.x;
  if (t < NN) cnt[t] = 0;
  if (t < HID) vnsum[t] = 0.f;
}

__global__ void k_count(const int* __restrict__ dst, int* __restrict__ cnt) {
  int e = blockIdx.x * blockDim.x + threadIdx.x;
  if (e < EE) atomicAdd(&cnt[dst[e]], 1);
}

__global__ __launch_bounds__(256) void k_scan1(const int* __restrict__ cnt,
                                               int* __restrict__ bsum) {
  __shared__ int s[256];
  int idx = blockIdx.x * 256 + threadIdx.x;
  int v = (idx < NN) ? cnt[idx] : 0;
  s[threadIdx.x] = v;
  __syncthreads();
  for (int d = 128; d > 0; d >>= 1) {
    if (threadIdx.x < d) s[threadIdx.x] += s[threadIdx.x + d];
    __syncthreads();
  }
  if (threadIdx.x == 0) bsum[blockIdx.x] = s[0];
}

__global__ __launch_bounds__(256) void k_scan2(const int* __restrict__ bsum,
                                               int* __restrict__ bexc,
                                               int* __restrict__ off) {
  __shared__ int s[256];
  int t = threadIdx.x;
  int v = (t < SCAN_G) ? bsum[t] : 0;
  int exc = block_excl_scan_256(v, s);
  if (t < SCAN_G) bexc[t] = exc;
  if (t == 255) off[NN] = s[255];
}

__global__ __launch_bounds__(256) void k_scan3(const int* __restrict__ cnt,
                                               const int* __restrict__ bexc,
                                               int* __restrict__ off,
                                               int* __restrict__ cursor) {
  __shared__ int s[256];
  int idx = blockIdx.x * 256 + threadIdx.x;
  int v = (idx < NN) ? cnt[idx] : 0;
  int exc = block_excl_scan_256(v, s) + bexc[blockIdx.x];
  if (idx < NN) {
    off[idx] = exc;
    cursor[idx] = exc;
  }
}

// scatter: src-in-CSR-order + edge->CSR-position map
__global__ void k_scatter(const int* __restrict__ src, const int* __restrict__ dst,
                          int* __restrict__ cursor, int* __restrict__ sperm,
                          int* __restrict__ epos) {
  int e = blockIdx.x * blockDim.x + threadIdx.x;
  if (e < EE) {
    int p = atomicAdd(&cursor[dst[e]], 1);
    sperm[p] = src[e];
    epos[e] = p;
  }
}

// we_ae[l] = We_l @ ae_l  (64-vector per layer)
__global__ void k_weae(const float* __restrict__ We0, const float* __restrict__ We1,
                       const float* __restrict__ We2, const float* __restrict__ ae0,
                       const float* __restrict__ ae1, const float* __restrict__ ae2,
                       float* __restrict__ weae) {
  int t = threadIdx.x;
  if (t >= 192) return;
  int l = t >> 6, j = t & 63;
  const float* We = (l == 0) ? We0 : (l == 1) ? We1 : We2;
  const float* ae = (l == 0) ? ae0 : (l == 1) ? ae1 : ae2;
  float acc = 0.f;
  for (int k = 0; k < HID; ++k) acc += We[j * HID + k] * ae[k];
  weae[l * ED + j] = acc;
}

// per-REAL-edge scalar -> CSR slot: esc_csr[l*EE + epos[e]] = ea_e . weae[l]
__global__ __launch_bounds__(256) void k_esc(
    const float* __restrict__ edge_attr, const float* __restrict__ weae,
    const int* __restrict__ epos, float* __restrict__ esc_csr) {
  __shared__ float4 sw[3][16];
  int tid = threadIdx.x;
  if (tid < 48) ((float4*)sw)[tid] = ((const float4*)weae)[tid];
  __syncthreads();
  int item = blockIdx.x * 256 + tid;
  if (item >= EE) return;
  const float4* row = (const float4*)(edge_attr + (size_t)item * ED);
  float a0 = 0.f, a1 = 0.f, a2 = 0.f;
#pragma unroll
  for (int c = 0; c < 16; ++c) {
    float4 v = row[c];
    float4 w0 = sw[0][c], w1 = sw[1][c], w2 = sw[2][c];
    a0 += v.x * w0.x + v.y * w0.y + v.z * w0.z + v.w * w0.w;
    a1 += v.x * w1.x + v.y * w1.y + v.z * w1.z + v.w * w1.w;
    a2 += v.x * w2.x + v.y * w2.y + v.z * w2.z + v.w * w2.w;
  }
  int p = epos[item];
  esc_csr[p] = a0;
  esc_csr[(size_t)EE + p] = a1;
  esc_csr[(size_t)2 * EE + p] = a2;
}

// self-loop esc via linearity: escself[l*NN+i] = avg over CSR range (CSR-direct)
__global__ __launch_bounds__(256) void k_escself(
    const int* __restrict__ off, const float* __restrict__ esc_csr,
    float* __restrict__ escself) {
  int i = blockIdx.x * 16 + (threadIdx.x >> 4);
  int g = threadIdx.x & 15;
  if (i >= NN) return;
  int s0 = off[i], s1 = off[i + 1];
  float a0 = 0.f, a1 = 0.f, a2 = 0.f;
  for (int p = s0 + g; p < s1; p += 16) {
    a0 += esc_csr[p];
    a1 += esc_csr[(size_t)EE + p];
    a2 += esc_csr[(size_t)2 * EE + p];
  }
#pragma unroll
  for (int o = 8; o > 0; o >>= 1) {
    a0 += __shfl_xor(a0, o, 64);
    a1 += __shfl_xor(a1, o, 64);
    a2 += __shfl_xor(a2, o, 64);
  }
  if (g == 0) {
    int deg = s1 - s0;
    float inv = 1.f / (float)(deg > 1 ? deg : 1);
    escself[i] = a0 * inv;
    escself[(size_t)NN + i] = a1 * inv;
    escself[(size_t)2 * NN + i] = a2 * inv;
  }
}

// ---------------- per-layer kernels ----------------

// Fused: hb[NNx128](bf16) = X @ W ; hs[i]=h[i].a_s ; hd[i]=h[i].a_d
__global__ __launch_bounds__(256) void k_gemmA(
    const float* __restrict__ X, const float* __restrict__ W,
    const float* __restrict__ as_, const float* __restrict__ ad_,
    unsigned short* __restrict__ hb, float* __restrict__ hs,
    float* __restrict__ hd) {
  __shared__ float sX[32][HID];
  __shared__ float sW[64][HID];
  int tid = threadIdx.x;
  int row0 = blockIdx.x * 32;
  {
    const float4* xs = (const float4*)(X + (size_t)row0 * HID);
    float4* xd = (float4*)(&sX[0][0]);
#pragma unroll
    for (int v = 0; v < 4; ++v) {
      int idx = tid + v * 256;
      int grow = row0 + (idx >> 5);
      xd[idx] = (grow < NN) ? xs[idx] : make_float4(0.f, 0.f, 0.f, 0.f);
    }
  }
  int colg = (tid & 31) * 4;
  int rowg = (tid >> 5) * 4;
  float acc[4][4] = {{0.f}};
  for (int kc = 0; kc < 2; ++kc) {
    __syncthreads();
    {
      const float4* wsp = (const float4*)(W + (size_t)kc * 64 * HID);
      float4* wd = (float4*)(&sW[0][0]);
#pragma unroll
      for (int v = 0; v < 8; ++v) wd[tid + v * 256] = wsp[tid + v * 256];
    }
    __syncthreads();
#pragma unroll 8
    for (int k = 0; k < 64; ++k) {
      float4 wv = *(const float4*)(&sW[k][colg]);
#pragma unroll
      for (int r = 0; r < 4; ++r) {
        float xv = sX[rowg + r][kc * 64 + k];
        acc[r][0] += xv * wv.x;
        acc[r][1] += xv * wv.y;
        acc[r][2] += xv * wv.z;
        acc[r][3] += xv * wv.w;
      }
    }
  }
  // bf16 output tile
#pragma unroll
  for (int r = 0; r < 4; ++r) {
    int grow = row0 + rowg + r;
    if (grow < NN) {
      ushort4 b;
      b.x = f2bf(acc[r][0]);
      b.y = f2bf(acc[r][1]);
      b.z = f2bf(acc[r][2]);
      b.w = f2bf(acc[r][3]);
      *(ushort4*)(hb + (size_t)grow * HID + colg) = b;
    }
  }
  // hs/hd epilogue: partial dots then reduce over the 32 column-threads
  float asv0 = as_[colg], asv1 = as_[colg + 1], asv2 = as_[colg + 2],
        asv3 = as_[colg + 3];
  float adv0 = ad_[colg], adv1 = ad_[colg + 1], adv2 = ad_[colg + 2],
        adv3 = ad_[colg + 3];
#pragma unroll
  for (int r = 0; r < 4; ++r) {
    float ps = acc[r][0] * asv0 + acc[r][1] * asv1 + acc[r][2] * asv2 +
               acc[r][3] * asv3;
    float pd = acc[r][0] * adv0 + acc[r][1] * adv1 + acc[r][2] * adv2 +
               acc[r][3] * adv3;
#pragma unroll
    for (int o = 1; o < 32; o <<= 1) {
      ps += __shfl_xor(ps, o, 64);
      pd += __shfl_xor(pd, o, 64);
    }
    if ((tid & 31) == 0) {
      int grow = row0 + rowg + r;
      if (grow < NN) {
        hs[grow] = ps;
        hd[grow] = pd;
      }
    }
  }
}

// wave per dst node, 4 edge-groups x 16 dim-lanes; softmax without max-sub.
__global__ __launch_bounds__(256) void k_aggregate4(
    const unsigned short* __restrict__ hb, const float* __restrict__ hs,
    const float* __restrict__ hd, const float* __restrict__ escl,
    const float* __restrict__ esl, const int* __restrict__ sperm,
    const int* __restrict__ off, const float* __restrict__ bias,
    float* __restrict__ out, int act) {
  int i = blockIdx.x * 4 + (threadIdx.x >> 6);
  int lane = threadIdx.x & 63;
  if (i >= NN) return;
  int g = lane >> 4;
  int j = lane & 15;
  int s0 = off[i];
  int deg = off[i + 1] - s0;
  int nt = deg + 1;  // + self-loop
  float hdi = hd[i];
  float den = 0.f;
  float4 acc0 = make_float4(0.f, 0.f, 0.f, 0.f);
  float4 acc1 = make_float4(0.f, 0.f, 0.f, 0.f);
  for (int t0 = 0; t0 < nt; t0 += 4) {
    int t = t0 + g;
    if (t < nt) {
      int s;
      float av;
      if (t < deg) {
        s = sperm[s0 + t];
        av = hs[s] + hdi + escl[s0 + t];
      } else {
        s = i;
        av = hs[i] + hdi + esl[i];
      }
      av = (av > 0.f) ? av : 0.2f * av;
      float w = __expf(av);
      den += w;
      ushort8_t hv = *(const ushort8_t*)(hb + (size_t)s * HID + j * 8);
      acc0.x += w * bf2f(hv[0]);
      acc0.y += w * bf2f(hv[1]);
      acc0.z += w * bf2f(hv[2]);
      acc0.w += w * bf2f(hv[3]);
      acc1.x += w * bf2f(hv[4]);
      acc1.y += w * bf2f(hv[5]);
      acc1.z += w * bf2f(hv[6]);
      acc1.w += w * bf2f(hv[7]);
    }
  }
  // reduce across the 4 groups (lanes j, j+16, j+32, j+48)
#pragma unroll
  for (int o = 16; o <= 32; o <<= 1) {
    acc0.x += __shfl_xor(acc0.x, o, 64);
    acc0.y += __shfl_xor(acc0.y, o, 64);
    acc0.z += __shfl_xor(acc0.z, o, 64);
    acc0.w += __shfl_xor(acc0.w, o, 64);
    acc1.x += __shfl_xor(acc1.x, o, 64);
    acc1.y += __shfl_xor(acc1.y, o, 64);
    acc1.z += __shfl_xor(acc1.z, o, 64);
    acc1.w += __shfl_xor(acc1.w, o, 64);
    den += __shfl_xor(den, o, 64);
  }
  if (g == 0) {
    float inv = 1.f / den;
    const float4* bp = (const float4*)(bias + j * 8);
    float4 b0 = bp[0], b1 = bp[1];
    float4 o0, o1;
    o0.x = acc0.x * inv + b0.x; o0.y = acc0.y * inv + b0.y;
    o0.z = acc0.z * inv + b0.z; o0.w = acc0.w * inv + b0.w;
    o1.x = acc1.x * inv + b1.x; o1.y = acc1.y * inv + b1.y;
    o1.z = acc1.z * inv + b1.z; o1.w = acc1.w * inv + b1.w;
    if (act) {
      o0.x = (o0.x > 0.f) ? o0.x : 0.01f * o0.x;
      o0.y = (o0.y > 0.f) ? o0.y : 0.01f * o0.y;
      o0.z = (o0.z > 0.f) ? o0.z : 0.01f * o0.z;
      o0.w = (o0.w > 0.f) ? o0.w : 0.01f * o0.w;
      o1.x = (o1.x > 0.f) ? o1.x : 0.01f * o1.x;
      o1.y = (o1.y > 0.f) ? o1.y : 0.01f * o1.y;
      o1.z = (o1.z > 0.f) ? o1.z : 0.01f * o1.z;
      o1.w = (o1.w > 0.f) ? o1.w : 0.01f * o1.w;
    }
    float4* op = (float4*)(out + (size_t)i * HID + j * 8);
    op[0] = o0;
    op[1] = o1;
  }
}

// final node GEMM (fp32, with bias) — unchanged structure
__global__ __launch_bounds__(256) void k_gemm128(
    const float* __restrict__ X, const float* __restrict__ W,
    const float* __restrict__ bias, float* __restrict__ O) {
  __shared__ float sX[32][HID];
  __shared__ float sW[64][HID];
  int tid = threadIdx.x;
  int row0 = blockIdx.x * 32;
  {
    const float4* xs = (const float4*)(X + (size_t)row0 * HID);
    float4* xd = (float4*)(&sX[0][0]);
#pragma unroll
    for (int v = 0; v < 4; ++v) {
      int idx = tid + v * 256;
      int grow = row0 + (idx >> 5);
      xd[idx] = (grow < NN) ? xs[idx] : make_float4(0.f, 0.f, 0.f, 0.f);
    }
  }
  int colg = (tid & 31) * 4;
  int rowg = (tid >> 5) * 4;
  float acc[4][4] = {{0.f}};
  for (int kc = 0; kc < 2; ++kc) {
    __syncthreads();
    {
      const float4* wsp = (const float4*)(W + (size_t)kc * 64 * HID);
      float4* wd = (float4*)(&sW[0][0]);
#pragma unroll
      for (int v = 0; v < 8; ++v) wd[tid + v * 256] = wsp[tid + v * 256];
    }
    __syncthreads();
#pragma unroll 8
    for (int k = 0; k < 64; ++k) {
      float4 wv = *(const float4*)(&sW[k][colg]);
#pragma unroll
      for (int r = 0; r < 4; ++r) {
        float xv = sX[rowg + r][kc * 64 + k];
        acc[r][0] += xv * wv.x;
        acc[r][1] += xv * wv.y;
        acc[r][2] += xv * wv.z;
        acc[r][3] += xv * wv.w;
      }
    }
  }
#pragma unroll
  for (int r = 0; r < 4; ++r) {
    int grow = row0 + rowg + r;
    if (grow < NN) {
      float4 o;
      o.x = acc[r][0] + bias[colg + 0];
      o.y = acc[r][1] + bias[colg + 1];
      o.z = acc[r][2] + bias[colg + 2];
      o.w = acc[r][3] + bias[colg + 3];
      *(float4*)(O + (size_t)grow * HID + colg) = o;
    }
  }
}

// ---------------- virtual-node path ----------------

__global__ void k_vnreduce(const float* __restrict__ out, float* __restrict__ vnsum) {
  int d = threadIdx.x;  // 128 threads
  float acc = 0.f;
  for (int i = blockIdx.x; i < NN; i += gridDim.x)
    acc += out[(size_t)i * HID + d];
  atomicAdd(&vnsum[d], acc);
}

__global__ void k_mlp(const float* __restrict__ vnsum, const float* __restrict__ vn_w,
                      const float* __restrict__ w1, const float* __restrict__ b1,
                      const float* __restrict__ w2, const float* __restrict__ b2,
                      const float* __restrict__ w3, const float* __restrict__ b3,
                      const float* __restrict__ w4, const float* __restrict__ b4,
                      float* __restrict__ outv) {
  __shared__ float xb[HID], yb[HID];
  int t = threadIdx.x;
  xb[t] = vnsum[t] + vn_w[t];
  __syncthreads();
  const float* Ws[4] = {w1, w2, w3, w4};
  const float* Bs[4] = {b1, b2, b3, b4};
  float* cur = xb;
  float* nxt = yb;
  for (int l = 0; l < 4; ++l) {
    const float* W = Ws[l];
    const float* B = Bs[l];
    float acc = B[t];
    for (int d = 0; d < HID; ++d) acc += cur[d] * W[d * HID + t];
    nxt[t] = fmaxf(acc, 0.f);
    __syncthreads();
    float* tmp = cur; cur = nxt; nxt = tmp;
  }
  outv[t] = cur[t];
}

// ---------------- launch ----------------

extern "C" void kernel_launch(void* const* d_in, const int* in_sizes, int n_in,
                              void* d_out, int out_size, void* d_ws, size_t ws_size,
                              hipStream_t stream) {
  const float* x = (const float*)d_in[0];
  const int* ei = (const int*)d_in[1];
  const float* edge_attr = (const float*)d_in[2];
  const float *W[3], *as_[3], *ad_[3], *We[3], *ae[3], *bb[3];
  for (int l = 0; l < 3; ++l) {
    W[l]   = (const float*)d_in[3 + l * 6 + 0];
    as_[l] = (const float*)d_in[3 + l * 6 + 1];
    ad_[l] = (const float*)d_in[3 + l * 6 + 2];
    We[l]  = (const float*)d_in[3 + l * 6 + 3];
    ae[l]  = (const float*)d_in[3 + l * 6 + 4];
    bb[l]  = (const float*)d_in[3 + l * 6 + 5];
  }
  const float* vn_w = (const float*)d_in[21];
  const float* m1w1 = (const float*)d_in[22];
  const float* m1b1 = (const float*)d_in[23];
  const float* m1w2 = (const float*)d_in[24];
  const float* m1b2 = (const float*)d_in[25];
  const float* m2w1 = (const float*)d_in[26];
  const float* m2b1 = (const float*)d_in[27];
  const float* m2w2 = (const float*)d_in[28];
  const float* m2b2 = (const float*)d_in[29];
  const float* Wout = (const float*)d_in[30];
  const float* bout = (const float*)d_in[31];

  char* ws = (char*)d_ws;
  size_t o = 0;
  auto alloc = [&](size_t bytes) {
    o = (o + 255) & ~(size_t)255;
    void* p = ws + o;
    o += bytes;
    return p;
  };
  unsigned short* hb = (unsigned short*)alloc((size_t)NN * HID * 2);
  float* outbuf  = (float*)alloc((size_t)NN * HID * 4);
  float* esc_csr = (float*)alloc((size_t)3 * EE * 4);
  float* escself = (float*)alloc((size_t)3 * NN * 4);
  float* hs      = (float*)alloc((size_t)NN * 4);
  float* hd      = (float*)alloc((size_t)NN * 4);
  float* vnsum   = (float*)alloc(HID * 4);
  float* weae    = (float*)alloc(3 * ED * 4);
  int* cnt       = (int*)alloc((size_t)NN * 4);
  int* off       = (int*)alloc((size_t)(NN + 1) * 4);
  int* cursor    = (int*)alloc((size_t)NN * 4);
  int* sperm     = (int*)alloc((size_t)EE * 4);
  int* epos      = (int*)alloc((size_t)EE * 4);
  int* bsum      = (int*)alloc((size_t)SCAN_G * 4);
  int* bexc      = (int*)alloc((size_t)SCAN_G * 4);

  const int* srcv = ei;
  const int* dstv = ei + EE;

  k_zero<<<(NN + 255) / 256, 256, 0, stream>>>(cnt, vnsum);
  k_count<<<(EE + 255) / 256, 256, 0, stream>>>(dstv, cnt);
  k_scan1<<<SCAN_G, 256, 0, stream>>>(cnt, bsum);
  k_scan2<<<1, 256, 0, stream>>>(bsum, bexc, off);
  k_scan3<<<SCAN_G, 256, 0, stream>>>(cnt, bexc, off, cursor);
  k_scatter<<<(EE + 255) / 256, 256, 0, stream>>>(srcv, dstv, cursor, sperm, epos);
  k_weae<<<1, 256, 0, stream>>>(We[0], We[1], We[2], ae[0], ae[1], ae[2], weae);
  k_esc<<<(EE + 255) / 256, 256, 0, stream>>>(edge_attr, weae, epos, esc_csr);
  k_escself<<<(NN + 15) / 16, 256, 0, stream>>>(off, esc_csr, escself);

  const float* in_ptr = x;
  for (int l = 0; l < 3; ++l) {
    k_gemmA<<<(NN + 31) / 32, 256, 0, stream>>>(in_ptr, W[l], as_[l], ad_[l], hb,
                                                hs, hd);
    k_aggregate4<<<(NN + 3) / 4, 256, 0, stream>>>(
        hb, hs, hd, esc_csr + (size_t)l * EE, escself + (size_t)l * NN, sperm,
        off, bb[l], outbuf, (l > 0) ? 1 : 0);
    in_ptr = outbuf;
  }

  float* node_out = (float*)d_out;
  k_gemm128<<<(NN + 31) / 32, 256, 0, stream>>>(outbuf, Wout, bout, node_out);
  k_vnreduce<<<256, 128, 0, stream>>>(outbuf, vnsum);
  k_mlp<<<1, 128, 0, stream>>>(vnsum, vn_w, m1w1, m1b1, m1w2, m1b2, m2w1, m2b1,
                               m2w2, m2b2, node_out + (size_t)NN * HID);
}

// Round 8
// 404.056 us; speedup vs baseline: 2.1308x; 1.0026x over previous
//
#include <hip/hip_runtime.h>

#define NN 50000
#define EE 400000
#define HID 128
#define ED 64
#define SCAN_G 196  // ceil(50000/256)

typedef __attribute__((ext_vector_type(8))) unsigned short ushort8_t;

// bf16 pack/unpack (RNE; values are finite)
static __device__ __forceinline__ unsigned short f2bf(float f) {
  unsigned u = __float_as_uint(f);
  unsigned r = (u + 0x7FFFu + ((u >> 16) & 1u)) >> 16;
  return (unsigned short)r;
}
static __device__ __forceinline__ float bf2f(unsigned short b) {
  return __uint_as_float((unsigned)b << 16);
}

// exclusive prefix of v across 256 threads; s must hold >=256 ints.
// After return, s[255] holds the block total.
static __device__ __forceinline__ int block_excl_scan_256(int v, int* s) {
  int tid = threadIdx.x;
  s[tid] = v;
  __syncthreads();
  for (int d = 1; d < 256; d <<= 1) {
    int t = (tid >= d) ? s[tid - d] : 0;
    __syncthreads();
    s[tid] += t;
    __syncthreads();
  }
  return s[tid] - v;
}

// ---------------- setup kernels ----------------

__global__ void k_zero(int* __restrict__ cnt, float* __restrict__ vnsum) {
  int t = blockIdx.x * blockDim.x + threadIdx.x;
  if (t < NN) cnt[t] = 0;
  if (t < HID) vnsum[t] = 0.f;
}

__global__ void k_count(const int* __restrict__ dst, int* __restrict__ cnt) {
  int e = blockIdx.x * blockDim.x + threadIdx.x;
  if (e < EE) atomicAdd(&cnt[dst[e]], 1);
}

__global__ __launch_bounds__(256) void k_scan1(const int* __restrict__ cnt,
                                               int* __restrict__ bsum) {
  __shared__ int s[256];
  int idx = blockIdx.x * 256 + threadIdx.x;
  int v = (idx < NN) ? cnt[idx] : 0;
  s[threadIdx.x] = v;
  __syncthreads();
  for (int d = 128; d > 0; d >>= 1) {
    if (threadIdx.x < d) s[threadIdx.x] += s[threadIdx.x + d];
    __syncthreads();
  }
  if (threadIdx.x == 0) bsum[blockIdx.x] = s[0];
}

__global__ __launch_bounds__(256) void k_scan2(const int* __restrict__ bsum,
                                               int* __restrict__ bexc,
                                               int* __restrict__ off) {
  __shared__ int s[256];
  int t = threadIdx.x;
  int v = (t < SCAN_G) ? bsum[t] : 0;
  int exc = block_excl_scan_256(v, s);
  if (t < SCAN_G) bexc[t] = exc;
  if (t == 255) off[NN] = s[255];
}

__global__ __launch_bounds__(256) void k_scan3(const int* __restrict__ cnt,
                                               const int* __restrict__ bexc,
                                               int* __restrict__ off,
                                               int* __restrict__ cursor) {
  __shared__ int s[256];
  int idx = blockIdx.x * 256 + threadIdx.x;
  int v = (idx < NN) ? cnt[idx] : 0;
  int exc = block_excl_scan_256(v, s) + bexc[blockIdx.x];
  if (idx < NN) {
    off[idx] = exc;
    cursor[idx] = exc;
  }
}

// scatter: CSR edge id + src-in-CSR-order
__global__ void k_scatter(const int* __restrict__ src, const int* __restrict__ dst,
                          int* __restrict__ cursor, int* __restrict__ sperm,
                          int* __restrict__ eid) {
  int e = blockIdx.x * blockDim.x + threadIdx.x;
  if (e < EE) {
    int p = atomicAdd(&cursor[dst[e]], 1);
    sperm[p] = src[e];
    eid[p] = e;
  }
}

// we_ae[l] = We_l @ ae_l  (64-vector per layer)
__global__ void k_weae(const float* __restrict__ We0, const float* __restrict__ We1,
                       const float* __restrict__ We2, const float* __restrict__ ae0,
                       const float* __restrict__ ae1, const float* __restrict__ ae2,
                       float* __restrict__ weae) {
  int t = threadIdx.x;
  if (t >= 192) return;
  int l = t >> 6, j = t & 63;
  const float* We = (l == 0) ? We0 : (l == 1) ? We1 : We2;
  const float* ae = (l == 0) ? ae0 : (l == 1) ? ae1 : ae2;
  float acc = 0.f;
  for (int k = 0; k < HID; ++k) acc += We[j * HID + k] * ae[k];
  weae[l * ED + j] = acc;
}

// per-REAL-edge scalar in EDGE order (coalesced writes, no scatter):
// esc_eo[l*EE + e] = ea_e . weae[l]
__global__ __launch_bounds__(256) void k_esc_eo(
    const float* __restrict__ edge_attr, const float* __restrict__ weae,
    float* __restrict__ esc_eo) {
  __shared__ float4 sw[3][16];
  int tid = threadIdx.x;
  if (tid < 48) ((float4*)sw)[tid] = ((const float4*)weae)[tid];
  __syncthreads();
  int item = blockIdx.x * 256 + tid;
  if (item >= EE) return;
  const float4* row = (const float4*)(edge_attr + (size_t)item * ED);
  float a0 = 0.f, a1 = 0.f, a2 = 0.f;
#pragma unroll
  for (int c = 0; c < 16; ++c) {
    float4 v = row[c];
    float4 w0 = sw[0][c], w1 = sw[1][c], w2 = sw[2][c];
    a0 += v.x * w0.x + v.y * w0.y + v.z * w0.z + v.w * w0.w;
    a1 += v.x * w1.x + v.y * w1.y + v.z * w1.z + v.w * w1.w;
    a2 += v.x * w2.x + v.y * w2.y + v.z * w2.z + v.w * w2.w;
  }
  esc_eo[item] = a0;
  esc_eo[(size_t)EE + item] = a1;
  esc_eo[(size_t)2 * EE + item] = a2;
}

// permute esc to CSR order (gather, L2-resident table) + self-loop mean.
// 16-lane group per node.
__global__ __launch_bounds__(256) void k_permself(
    const int* __restrict__ off, const int* __restrict__ eid,
    const float* __restrict__ esc_eo, float* __restrict__ esc_csr,
    float* __restrict__ escself) {
  int i = blockIdx.x * 16 + (threadIdx.x >> 4);
  int g = threadIdx.x & 15;
  if (i >= NN) return;
  int s0 = off[i], s1 = off[i + 1];
  float a0 = 0.f, a1 = 0.f, a2 = 0.f;
  for (int p = s0 + g; p < s1; p += 16) {
    int e = eid[p];
    float v0 = esc_eo[e];
    float v1 = esc_eo[(size_t)EE + e];
    float v2 = esc_eo[(size_t)2 * EE + e];
    esc_csr[p] = v0;
    esc_csr[(size_t)EE + p] = v1;
    esc_csr[(size_t)2 * EE + p] = v2;
    a0 += v0;
    a1 += v1;
    a2 += v2;
  }
#pragma unroll
  for (int o = 8; o > 0; o >>= 1) {
    a0 += __shfl_xor(a0, o, 64);
    a1 += __shfl_xor(a1, o, 64);
    a2 += __shfl_xor(a2, o, 64);
  }
  if (g == 0) {
    int deg = s1 - s0;
    float inv = 1.f / (float)(deg > 1 ? deg : 1);
    escself[i] = a0 * inv;
    escself[(size_t)NN + i] = a1 * inv;
    escself[(size_t)2 * NN + i] = a2 * inv;
  }
}

// ---------------- per-layer kernels ----------------

// Fused: hb[NNx128](bf16) = X @ W ; hs[i]=h[i].a_s ; hd[i]=h[i].a_d
__global__ __launch_bounds__(256) void k_gemmA(
    const float* __restrict__ X, const float* __restrict__ W,
    const float* __restrict__ as_, const float* __restrict__ ad_,
    unsigned short* __restrict__ hb, float* __restrict__ hs,
    float* __restrict__ hd) {
  __shared__ float sX[32][HID];
  __shared__ float sW[64][HID];
  int tid = threadIdx.x;
  int row0 = blockIdx.x * 32;
  {
    const float4* xs = (const float4*)(X + (size_t)row0 * HID);
    float4* xd = (float4*)(&sX[0][0]);
#pragma unroll
    for (int v = 0; v < 4; ++v) {
      int idx = tid + v * 256;
      int grow = row0 + (idx >> 5);
      xd[idx] = (grow < NN) ? xs[idx] : make_float4(0.f, 0.f, 0.f, 0.f);
    }
  }
  int colg = (tid & 31) * 4;
  int rowg = (tid >> 5) * 4;
  float acc[4][4] = {{0.f}};
  for (int kc = 0; kc < 2; ++kc) {
    __syncthreads();
    {
      const float4* wsp = (const float4*)(W + (size_t)kc * 64 * HID);
      float4* wd = (float4*)(&sW[0][0]);
#pragma unroll
      for (int v = 0; v < 8; ++v) wd[tid + v * 256] = wsp[tid + v * 256];
    }
    __syncthreads();
#pragma unroll 8
    for (int k = 0; k < 64; ++k) {
      float4 wv = *(const float4*)(&sW[k][colg]);
#pragma unroll
      for (int r = 0; r < 4; ++r) {
        float xv = sX[rowg + r][kc * 64 + k];
        acc[r][0] += xv * wv.x;
        acc[r][1] += xv * wv.y;
        acc[r][2] += xv * wv.z;
        acc[r][3] += xv * wv.w;
      }
    }
  }
  // bf16 output tile
#pragma unroll
  for (int r = 0; r < 4; ++r) {
    int grow = row0 + rowg + r;
    if (grow < NN) {
      ushort4 b;
      b.x = f2bf(acc[r][0]);
      b.y = f2bf(acc[r][1]);
      b.z = f2bf(acc[r][2]);
      b.w = f2bf(acc[r][3]);
      *(ushort4*)(hb + (size_t)grow * HID + colg) = b;
    }
  }
  // hs/hd epilogue: partial dots then reduce over the 32 column-threads
  float asv0 = as_[colg], asv1 = as_[colg + 1], asv2 = as_[colg + 2],
        asv3 = as_[colg + 3];
  float adv0 = ad_[colg], adv1 = ad_[colg + 1], adv2 = ad_[colg + 2],
        adv3 = ad_[colg + 3];
#pragma unroll
  for (int r = 0; r < 4; ++r) {
    float ps = acc[r][0] * asv0 + acc[r][1] * asv1 + acc[r][2] * asv2 +
               acc[r][3] * asv3;
    float pd = acc[r][0] * adv0 + acc[r][1] * adv1 + acc[r][2] * adv2 +
               acc[r][3] * adv3;
#pragma unroll
    for (int o = 1; o < 32; o <<= 1) {
      ps += __shfl_xor(ps, o, 64);
      pd += __shfl_xor(pd, o, 64);
    }
    if ((tid & 31) == 0) {
      int grow = row0 + rowg + r;
      if (grow < NN) {
        hs[grow] = ps;
        hd[grow] = pd;
      }
    }
  }
}

// wave per dst node, 4 edge-groups x 16 dim-lanes; softmax without max-sub.
__global__ __launch_bounds__(256) void k_aggregate4(
    const unsigned short* __restrict__ hb, const float* __restrict__ hs,
    const float* __restrict__ hd, const float* __restrict__ escl,
    const float* __restrict__ esl, const int* __restrict__ sperm,
    const int* __restrict__ off, const float* __restrict__ bias,
    float* __restrict__ out, int act) {
  int i = blockIdx.x * 4 + (threadIdx.x >> 6);
  int lane = threadIdx.x & 63;
  if (i >= NN) return;
  int g = lane >> 4;
  int j = lane & 15;
  int s0 = off[i];
  int deg = off[i + 1] - s0;
  int nt = deg + 1;  // + self-loop
  float hdi = hd[i];
  float den = 0.f;
  float4 acc0 = make_float4(0.f, 0.f, 0.f, 0.f);
  float4 acc1 = make_float4(0.f, 0.f, 0.f, 0.f);
  for (int t0 = 0; t0 < nt; t0 += 4) {
    int t = t0 + g;
    if (t < nt) {
      int s;
      float av;
      if (t < deg) {
        s = sperm[s0 + t];
        av = hs[s] + hdi + escl[s0 + t];
      } else {
        s = i;
        av = hs[i] + hdi + esl[i];
      }
      av = (av > 0.f) ? av : 0.2f * av;
      float w = __expf(av);
      den += w;
      ushort8_t hv = *(const ushort8_t*)(hb + (size_t)s * HID + j * 8);
      acc0.x += w * bf2f(hv[0]);
      acc0.y += w * bf2f(hv[1]);
      acc0.z += w * bf2f(hv[2]);
      acc0.w += w * bf2f(hv[3]);
      acc1.x += w * bf2f(hv[4]);
      acc1.y += w * bf2f(hv[5]);
      acc1.z += w * bf2f(hv[6]);
      acc1.w += w * bf2f(hv[7]);
    }
  }
  // reduce across the 4 groups (lanes j, j+16, j+32, j+48)
#pragma unroll
  for (int o = 16; o <= 32; o <<= 1) {
    acc0.x += __shfl_xor(acc0.x, o, 64);
    acc0.y += __shfl_xor(acc0.y, o, 64);
    acc0.z += __shfl_xor(acc0.z, o, 64);
    acc0.w += __shfl_xor(acc0.w, o, 64);
    acc1.x += __shfl_xor(acc1.x, o, 64);
    acc1.y += __shfl_xor(acc1.y, o, 64);
    acc1.z += __shfl_xor(acc1.z, o, 64);
    acc1.w += __shfl_xor(acc1.w, o, 64);
    den += __shfl_xor(den, o, 64);
  }
  if (g == 0) {
    float inv = 1.f / den;
    const float4* bp = (const float4*)(bias + j * 8);
    float4 b0 = bp[0], b1 = bp[1];
    float4 o0, o1;
    o0.x = acc0.x * inv + b0.x; o0.y = acc0.y * inv + b0.y;
    o0.z = acc0.z * inv + b0.z; o0.w = acc0.w * inv + b0.w;
    o1.x = acc1.x * inv + b1.x; o1.y = acc1.y * inv + b1.y;
    o1.z = acc1.z * inv + b1.z; o1.w = acc1.w * inv + b1.w;
    if (act) {
      o0.x = (o0.x > 0.f) ? o0.x : 0.01f * o0.x;
      o0.y = (o0.y > 0.f) ? o0.y : 0.01f * o0.y;
      o0.z = (o0.z > 0.f) ? o0.z : 0.01f * o0.z;
      o0.w = (o0.w > 0.f) ? o0.w : 0.01f * o0.w;
      o1.x = (o1.x > 0.f) ? o1.x : 0.01f * o1.x;
      o1.y = (o1.y > 0.f) ? o1.y : 0.01f * o1.y;
      o1.z = (o1.z > 0.f) ? o1.z : 0.01f * o1.z;
      o1.w = (o1.w > 0.f) ? o1.w : 0.01f * o1.w;
    }
    float4* op = (float4*)(out + (size_t)i * HID + j * 8);
    op[0] = o0;
    op[1] = o1;
  }
}

// final node GEMM (fp32, with bias) — unchanged structure
__global__ __launch_bounds__(256) void k_gemm128(
    const float* __restrict__ X, const float* __restrict__ W,
    const float* __restrict__ bias, float* __restrict__ O) {
  __shared__ float sX[32][HID];
  __shared__ float sW[64][HID];
  int tid = threadIdx.x;
  int row0 = blockIdx.x * 32;
  {
    const float4* xs = (const float4*)(X + (size_t)row0 * HID);
    float4* xd = (float4*)(&sX[0][0]);
#pragma unroll
    for (int v = 0; v < 4; ++v) {
      int idx = tid + v * 256;
      int grow = row0 + (idx >> 5);
      xd[idx] = (grow < NN) ? xs[idx] : make_float4(0.f, 0.f, 0.f, 0.f);
    }
  }
  int colg = (tid & 31) * 4;
  int rowg = (tid >> 5) * 4;
  float acc[4][4] = {{0.f}};
  for (int kc = 0; kc < 2; ++kc) {
    __syncthreads();
    {
      const float4* wsp = (const float4*)(W + (size_t)kc * 64 * HID);
      float4* wd = (float4*)(&sW[0][0]);
#pragma unroll
      for (int v = 0; v < 8; ++v) wd[tid + v * 256] = wsp[tid + v * 256];
    }
    __syncthreads();
#pragma unroll 8
    for (int k = 0; k < 64; ++k) {
      float4 wv = *(const float4*)(&sW[k][colg]);
#pragma unroll
      for (int r = 0; r < 4; ++r) {
        float xv = sX[rowg + r][kc * 64 + k];
        acc[r][0] += xv * wv.x;
        acc[r][1] += xv * wv.y;
        acc[r][2] += xv * wv.z;
        acc[r][3] += xv * wv.w;
      }
    }
  }
#pragma unroll
  for (int r = 0; r < 4; ++r) {
    int grow = row0 + rowg + r;
    if (grow < NN) {
      float4 o;
      o.x = acc[r][0] + bias[colg + 0];
      o.y = acc[r][1] + bias[colg + 1];
      o.z = acc[r][2] + bias[colg + 2];
      o.w = acc[r][3] + bias[colg + 3];
      *(float4*)(O + (size_t)grow * HID + colg) = o;
    }
  }
}

// ---------------- virtual-node path ----------------

__global__ void k_vnreduce(const float* __restrict__ out, float* __restrict__ vnsum) {
  int d = threadIdx.x;  // 128 threads
  float acc = 0.f;
  for (int i = blockIdx.x; i < NN; i += gridDim.x)
    acc += out[(size_t)i * HID + d];
  atomicAdd(&vnsum[d], acc);
}

__global__ void k_mlp(const float* __restrict__ vnsum, const float* __restrict__ vn_w,
                      const float* __restrict__ w1, const float* __restrict__ b1,
                      const float* __restrict__ w2, const float* __restrict__ b2,
                      const float* __restrict__ w3, const float* __restrict__ b3,
                      const float* __restrict__ w4, const float* __restrict__ b4,
                      float* __restrict__ outv) {
  __shared__ float xb[HID], yb[HID];
  int t = threadIdx.x;
  xb[t] = vnsum[t] + vn_w[t];
  __syncthreads();
  const float* Ws[4] = {w1, w2, w3, w4};
  const float* Bs[4] = {b1, b2, b3, b4};
  float* cur = xb;
  float* nxt = yb;
  for (int l = 0; l < 4; ++l) {
    const float* W = Ws[l];
    const float* B = Bs[l];
    float acc = B[t];
    for (int d = 0; d < HID; ++d) acc += cur[d] * W[d * HID + t];
    nxt[t] = fmaxf(acc, 0.f);
    __syncthreads();
    float* tmp = cur; cur = nxt; nxt = tmp;
  }
  outv[t] = cur[t];
}

// ---------------- launch ----------------

extern "C" void kernel_launch(void* const* d_in, const int* in_sizes, int n_in,
                              void* d_out, int out_size, void* d_ws, size_t ws_size,
                              hipStream_t stream) {
  const float* x = (const float*)d_in[0];
  const int* ei = (const int*)d_in[1];
  const float* edge_attr = (const float*)d_in[2];
  const float *W[3], *as_[3], *ad_[3], *We[3], *ae[3], *bb[3];
  for (int l = 0; l < 3; ++l) {
    W[l]   = (const float*)d_in[3 + l * 6 + 0];
    as_[l] = (const float*)d_in[3 + l * 6 + 1];
    ad_[l] = (const float*)d_in[3 + l * 6 + 2];
    We[l]  = (const float*)d_in[3 + l * 6 + 3];
    ae[l]  = (const float*)d_in[3 + l * 6 + 4];
    bb[l]  = (const float*)d_in[3 + l * 6 + 5];
  }
  const float* vn_w = (const float*)d_in[21];
  const float* m1w1 = (const float*)d_in[22];
  const float* m1b1 = (const float*)d_in[23];
  const float* m1w2 = (const float*)d_in[24];
  const float* m1b2 = (const float*)d_in[25];
  const float* m2w1 = (const float*)d_in[26];
  const float* m2b1 = (const float*)d_in[27];
  const float* m2w2 = (const float*)d_in[28];
  const float* m2b2 = (const float*)d_in[29];
  const float* Wout = (const float*)d_in[30];
  const float* bout = (const float*)d_in[31];

  char* ws = (char*)d_ws;
  size_t o = 0;
  auto alloc = [&](size_t bytes) {
    o = (o + 255) & ~(size_t)255;
    void* p = ws + o;
    o += bytes;
    return p;
  };
  unsigned short* hb = (unsigned short*)alloc((size_t)NN * HID * 2);
  float* outbuf  = (float*)alloc((size_t)NN * HID * 4);
  float* esc_eo  = (float*)alloc((size_t)3 * EE * 4);
  float* esc_csr = (float*)alloc((size_t)3 * EE * 4);
  float* escself = (float*)alloc((size_t)3 * NN * 4);
  float* hs      = (float*)alloc((size_t)NN * 4);
  float* hd      = (float*)alloc((size_t)NN * 4);
  float* vnsum   = (float*)alloc(HID * 4);
  float* weae    = (float*)alloc(3 * ED * 4);
  int* cnt       = (int*)alloc((size_t)NN * 4);
  int* off       = (int*)alloc((size_t)(NN + 1) * 4);
  int* cursor    = (int*)alloc((size_t)NN * 4);
  int* sperm     = (int*)alloc((size_t)EE * 4);
  int* eid       = (int*)alloc((size_t)EE * 4);
  int* bsum      = (int*)alloc((size_t)SCAN_G * 4);
  int* bexc      = (int*)alloc((size_t)SCAN_G * 4);

  const int* srcv = ei;
  const int* dstv = ei + EE;

  k_zero<<<(NN + 255) / 256, 256, 0, stream>>>(cnt, vnsum);
  k_count<<<(EE + 255) / 256, 256, 0, stream>>>(dstv, cnt);
  k_scan1<<<SCAN_G, 256, 0, stream>>>(cnt, bsum);
  k_scan2<<<1, 256, 0, stream>>>(bsum, bexc, off);
  k_scan3<<<SCAN_G, 256, 0, stream>>>(cnt, bexc, off, cursor);
  k_scatter<<<(EE + 255) / 256, 256, 0, stream>>>(srcv, dstv, cursor, sperm, eid);
  k_weae<<<1, 256, 0, stream>>>(We[0], We[1], We[2], ae[0], ae[1], ae[2], weae);
  k_esc_eo<<<(EE + 255) / 256, 256, 0, stream>>>(edge_attr, weae, esc_eo);
  k_permself<<<(NN + 15) / 16, 256, 0, stream>>>(off, eid, esc_eo, esc_csr,
                                                 escself);

  const float* in_ptr = x;
  for (int l = 0; l < 3; ++l) {
    k_gemmA<<<(NN + 31) / 32, 256, 0, stream>>>(in_ptr, W[l], as_[l], ad_[l], hb,
                                                hs, hd);
    k_aggregate4<<<(NN + 3) / 4, 256, 0, stream>>>(
        hb, hs, hd, esc_csr + (size_t)l * EE, escself + (size_t)l * NN, sperm,
        off, bb[l], outbuf, (l > 0) ? 1 : 0);
    in_ptr = outbuf;
  }

  float* node_out = (float*)d_out;
  k_gemm128<<<(NN + 31) / 32, 256, 0, stream>>>(outbuf, Wout, bout, node_out);
  k_vnreduce<<<256, 128, 0, stream>>>(outbuf, vnsum);
  k_mlp<<<1, 128, 0, stream>>>(vnsum, vn_w, m1w1, m1b1, m1w2, m1b2, m2w1, m2b1,
                               m2w2, m2b2, node_out + (size_t)NN * HID);
}

// Round 9
// 393.333 us; speedup vs baseline: 2.1889x; 1.0273x over previous
//
#include <hip/hip_runtime.h>

#define NN 50000
#define EE 400000
#define HID 128
#define ED 64
#define SCAN_G 196  // ceil(50000/256)

typedef __attribute__((ext_vector_type(8))) unsigned short ushort8_t;

// bf16 pack/unpack (RNE; values are finite)
static __device__ __forceinline__ unsigned short f2bf(float f) {
  unsigned u = __float_as_uint(f);
  unsigned r = (u + 0x7FFFu + ((u >> 16) & 1u)) >> 16;
  return (unsigned short)r;
}
static __device__ __forceinline__ float bf2f(unsigned short b) {
  return __uint_as_float((unsigned)b << 16);
}

// exclusive prefix of v across 256 threads; s must hold >=256 ints.
// After return, s[255] holds the block total.
static __device__ __forceinline__ int block_excl_scan_256(int v, int* s) {
  int tid = threadIdx.x;
  s[tid] = v;
  __syncthreads();
  for (int d = 1; d < 256; d <<= 1) {
    int t = (tid >= d) ? s[tid - d] : 0;
    __syncthreads();
    s[tid] += t;
    __syncthreads();
  }
  return s[tid] - v;
}

// ---------------- setup kernels ----------------

__global__ void k_zero(int* __restrict__ cnt, float* __restrict__ vnsum) {
  int t = blockIdx.x * blockDim.x + threadIdx.x;
  if (t < NN) cnt[t] = 0;
  if (t < HID) vnsum[t] = 0.f;
}

__global__ void k_count(const int* __restrict__ dst, int* __restrict__ cnt) {
  int e = blockIdx.x * blockDim.x + threadIdx.x;
  if (e < EE) atomicAdd(&cnt[dst[e]], 1);
}

__global__ __launch_bounds__(256) void k_scan1(const int* __restrict__ cnt,
                                               int* __restrict__ bsum) {
  __shared__ int s[256];
  int idx = blockIdx.x * 256 + threadIdx.x;
  int v = (idx < NN) ? cnt[idx] : 0;
  s[threadIdx.x] = v;
  __syncthreads();
  for (int d = 128; d > 0; d >>= 1) {
    if (threadIdx.x < d) s[threadIdx.x] += s[threadIdx.x + d];
    __syncthreads();
  }
  if (threadIdx.x == 0) bsum[blockIdx.x] = s[0];
}

__global__ __launch_bounds__(256) void k_scan2(const int* __restrict__ bsum,
                                               int* __restrict__ bexc,
                                               int* __restrict__ off) {
  __shared__ int s[256];
  int t = threadIdx.x;
  int v = (t < SCAN_G) ? bsum[t] : 0;
  int exc = block_excl_scan_256(v, s);
  if (t < SCAN_G) bexc[t] = exc;
  if (t == 255) off[NN] = s[255];
}

__global__ __launch_bounds__(256) void k_scan3(const int* __restrict__ cnt,
                                               const int* __restrict__ bexc,
                                               int* __restrict__ off,
                                               int* __restrict__ cursor) {
  __shared__ int s[256];
  int idx = blockIdx.x * 256 + threadIdx.x;
  int v = (idx < NN) ? cnt[idx] : 0;
  int exc = block_excl_scan_256(v, s) + bexc[blockIdx.x];
  if (idx < NN) {
    off[idx] = exc;
    cursor[idx] = exc;
  }
}

// scatter: CSR edge id + src-in-CSR-order
__global__ void k_scatter(const int* __restrict__ src, const int* __restrict__ dst,
                          int* __restrict__ cursor, int* __restrict__ sperm,
                          int* __restrict__ eid) {
  int e = blockIdx.x * blockDim.x + threadIdx.x;
  if (e < EE) {
    int p = atomicAdd(&cursor[dst[e]], 1);
    sperm[p] = src[e];
    eid[p] = e;
  }
}

// we_ae[l] = We_l @ ae_l  (64-vector per layer)
__global__ void k_weae(const float* __restrict__ We0, const float* __restrict__ We1,
                       const float* __restrict__ We2, const float* __restrict__ ae0,
                       const float* __restrict__ ae1, const float* __restrict__ ae2,
                       float* __restrict__ weae) {
  int t = threadIdx.x;
  if (t >= 192) return;
  int l = t >> 6, j = t & 63;
  const float* We = (l == 0) ? We0 : (l == 1) ? We1 : We2;
  const float* ae = (l == 0) ? ae0 : (l == 1) ? ae1 : ae2;
  float acc = 0.f;
  for (int k = 0; k < HID; ++k) acc += We[j * HID + k] * ae[k];
  weae[l * ED + j] = acc;
}

// per-REAL-edge scalars in EDGE order, packed float4 {e0,e1,e2,0}.
// 16 lanes per row -> one fully coalesced 256B row read per 16-lane group.
__global__ __launch_bounds__(256) void k_esc_eo(
    const float* __restrict__ edge_attr, const float* __restrict__ weae,
    float4* __restrict__ esc4) {
  __shared__ float4 sw[3][16];
  int tid = threadIdx.x;
  if (tid < 48) ((float4*)sw)[tid] = ((const float4*)weae)[tid];
  __syncthreads();
  int c = tid & 15;   // float4 column within row
  int r0 = tid >> 4;  // row sub-index 0..15
  float4 w0 = sw[0][c], w1 = sw[1][c], w2 = sw[2][c];
#pragma unroll
  for (int pass = 0; pass < 4; ++pass) {
    int row = blockIdx.x * 64 + pass * 16 + r0;
    if (row < EE) {
      float4 v = ((const float4*)edge_attr)[(size_t)row * 16 + c];
      float a0 = v.x * w0.x + v.y * w0.y + v.z * w0.z + v.w * w0.w;
      float a1 = v.x * w1.x + v.y * w1.y + v.z * w1.z + v.w * w1.w;
      float a2 = v.x * w2.x + v.y * w2.y + v.z * w2.z + v.w * w2.w;
#pragma unroll
      for (int o = 1; o < 16; o <<= 1) {
        a0 += __shfl_xor(a0, o, 64);
        a1 += __shfl_xor(a1, o, 64);
        a2 += __shfl_xor(a2, o, 64);
      }
      if (c == 0) esc4[row] = make_float4(a0, a1, a2, 0.f);
    }
  }
}

// permute esc to CSR planes (single float4 gather per edge, L2-resident)
// + self-loop mean. 16-lane group per node.
__global__ __launch_bounds__(256) void k_permself(
    const int* __restrict__ off, const int* __restrict__ eid,
    const float4* __restrict__ esc4, float* __restrict__ esc_csr,
    float* __restrict__ escself) {
  int i = blockIdx.x * 16 + (threadIdx.x >> 4);
  int g = threadIdx.x & 15;
  if (i >= NN) return;
  int s0 = off[i], s1 = off[i + 1];
  float a0 = 0.f, a1 = 0.f, a2 = 0.f;
  for (int p = s0 + g; p < s1; p += 16) {
    float4 v = esc4[eid[p]];
    esc_csr[p] = v.x;
    esc_csr[(size_t)EE + p] = v.y;
    esc_csr[(size_t)2 * EE + p] = v.z;
    a0 += v.x;
    a1 += v.y;
    a2 += v.z;
  }
#pragma unroll
  for (int o = 8; o > 0; o >>= 1) {
    a0 += __shfl_xor(a0, o, 64);
    a1 += __shfl_xor(a1, o, 64);
    a2 += __shfl_xor(a2, o, 64);
  }
  if (g == 0) {
    int deg = s1 - s0;
    float inv = 1.f / (float)(deg > 1 ? deg : 1);
    escself[i] = a0 * inv;
    escself[(size_t)NN + i] = a1 * inv;
    escself[(size_t)2 * NN + i] = a2 * inv;
  }
}

// ---------------- per-layer kernels ----------------

// Fused: hb[NNx128](bf16) = X @ W ; hs[i]=h[i].a_s ; hd[i]=h[i].a_d
__global__ __launch_bounds__(256) void k_gemmA(
    const float* __restrict__ X, const float* __restrict__ W,
    const float* __restrict__ as_, const float* __restrict__ ad_,
    unsigned short* __restrict__ hb, float* __restrict__ hs,
    float* __restrict__ hd) {
  __shared__ float sX[32][HID];
  __shared__ float sW[64][HID];
  int tid = threadIdx.x;
  int row0 = blockIdx.x * 32;
  {
    const float4* xs = (const float4*)(X + (size_t)row0 * HID);
    float4* xd = (float4*)(&sX[0][0]);
#pragma unroll
    for (int v = 0; v < 4; ++v) {
      int idx = tid + v * 256;
      int grow = row0 + (idx >> 5);
      xd[idx] = (grow < NN) ? xs[idx] : make_float4(0.f, 0.f, 0.f, 0.f);
    }
  }
  int colg = (tid & 31) * 4;
  int rowg = (tid >> 5) * 4;
  float acc[4][4] = {{0.f}};
  for (int kc = 0; kc < 2; ++kc) {
    __syncthreads();
    {
      const float4* wsp = (const float4*)(W + (size_t)kc * 64 * HID);
      float4* wd = (float4*)(&sW[0][0]);
#pragma unroll
      for (int v = 0; v < 8; ++v) wd[tid + v * 256] = wsp[tid + v * 256];
    }
    __syncthreads();
#pragma unroll 4
    for (int k4 = 0; k4 < 64; k4 += 4) {
      float4 wv0 = *(const float4*)(&sW[k4 + 0][colg]);
      float4 wv1 = *(const float4*)(&sW[k4 + 1][colg]);
      float4 wv2 = *(const float4*)(&sW[k4 + 2][colg]);
      float4 wv3 = *(const float4*)(&sW[k4 + 3][colg]);
#pragma unroll
      for (int r = 0; r < 4; ++r) {
        float4 xv = *(const float4*)(&sX[rowg + r][kc * 64 + k4]);
        acc[r][0] += xv.x * wv0.x + xv.y * wv1.x + xv.z * wv2.x + xv.w * wv3.x;
        acc[r][1] += xv.x * wv0.y + xv.y * wv1.y + xv.z * wv2.y + xv.w * wv3.y;
        acc[r][2] += xv.x * wv0.z + xv.y * wv1.z + xv.z * wv2.z + xv.w * wv3.z;
        acc[r][3] += xv.x * wv0.w + xv.y * wv1.w + xv.z * wv2.w + xv.w * wv3.w;
      }
    }
  }
  // bf16 output tile
#pragma unroll
  for (int r = 0; r < 4; ++r) {
    int grow = row0 + rowg + r;
    if (grow < NN) {
      ushort4 b;
      b.x = f2bf(acc[r][0]);
      b.y = f2bf(acc[r][1]);
      b.z = f2bf(acc[r][2]);
      b.w = f2bf(acc[r][3]);
      *(ushort4*)(hb + (size_t)grow * HID + colg) = b;
    }
  }
  // hs/hd epilogue: partial dots then reduce over the 32 column-threads
  float asv0 = as_[colg], asv1 = as_[colg + 1], asv2 = as_[colg + 2],
        asv3 = as_[colg + 3];
  float adv0 = ad_[colg], adv1 = ad_[colg + 1], adv2 = ad_[colg + 2],
        adv3 = ad_[colg + 3];
#pragma unroll
  for (int r = 0; r < 4; ++r) {
    float ps = acc[r][0] * asv0 + acc[r][1] * asv1 + acc[r][2] * asv2 +
               acc[r][3] * asv3;
    float pd = acc[r][0] * adv0 + acc[r][1] * adv1 + acc[r][2] * adv2 +
               acc[r][3] * adv3;
#pragma unroll
    for (int o = 1; o < 32; o <<= 1) {
      ps += __shfl_xor(ps, o, 64);
      pd += __shfl_xor(pd, o, 64);
    }
    if ((tid & 31) == 0) {
      int grow = row0 + rowg + r;
      if (grow < NN) {
        hs[grow] = ps;
        hd[grow] = pd;
      }
    }
  }
}

// wave per dst node, 4 edge-groups x 16 dim-lanes; softmax without max-sub.
__global__ __launch_bounds__(256) void k_aggregate4(
    const unsigned short* __restrict__ hb, const float* __restrict__ hs,
    const float* __restrict__ hd, const float* __restrict__ escl,
    const float* __restrict__ esl, const int* __restrict__ sperm,
    const int* __restrict__ off, const float* __restrict__ bias,
    float* __restrict__ out, int act) {
  int i = blockIdx.x * 4 + (threadIdx.x >> 6);
  int lane = threadIdx.x & 63;
  if (i >= NN) return;
  int g = lane >> 4;
  int j = lane & 15;
  int s0 = off[i];
  int deg = off[i + 1] - s0;
  int nt = deg + 1;  // + self-loop
  float hdi = hd[i];
  float den = 0.f;
  float4 acc0 = make_float4(0.f, 0.f, 0.f, 0.f);
  float4 acc1 = make_float4(0.f, 0.f, 0.f, 0.f);
  for (int t0 = 0; t0 < nt; t0 += 4) {
    int t = t0 + g;
    if (t < nt) {
      int s;
      float av;
      if (t < deg) {
        s = sperm[s0 + t];
        av = hs[s] + hdi + escl[s0 + t];
      } else {
        s = i;
        av = hs[i] + hdi + esl[i];
      }
      av = (av > 0.f) ? av : 0.2f * av;
      float w = __expf(av);
      den += w;
      ushort8_t hv = *(const ushort8_t*)(hb + (size_t)s * HID + j * 8);
      acc0.x += w * bf2f(hv[0]);
      acc0.y += w * bf2f(hv[1]);
      acc0.z += w * bf2f(hv[2]);
      acc0.w += w * bf2f(hv[3]);
      acc1.x += w * bf2f(hv[4]);
      acc1.y += w * bf2f(hv[5]);
      acc1.z += w * bf2f(hv[6]);
      acc1.w += w * bf2f(hv[7]);
    }
  }
  // reduce across the 4 groups (lanes j, j+16, j+32, j+48)
#pragma unroll
  for (int o = 16; o <= 32; o <<= 1) {
    acc0.x += __shfl_xor(acc0.x, o, 64);
    acc0.y += __shfl_xor(acc0.y, o, 64);
    acc0.z += __shfl_xor(acc0.z, o, 64);
    acc0.w += __shfl_xor(acc0.w, o, 64);
    acc1.x += __shfl_xor(acc1.x, o, 64);
    acc1.y += __shfl_xor(acc1.y, o, 64);
    acc1.z += __shfl_xor(acc1.z, o, 64);
    acc1.w += __shfl_xor(acc1.w, o, 64);
    den += __shfl_xor(den, o, 64);
  }
  if (g == 0) {
    float inv = 1.f / den;
    const float4* bp = (const float4*)(bias + j * 8);
    float4 b0 = bp[0], b1 = bp[1];
    float4 o0, o1;
    o0.x = acc0.x * inv + b0.x; o0.y = acc0.y * inv + b0.y;
    o0.z = acc0.z * inv + b0.z; o0.w = acc0.w * inv + b0.w;
    o1.x = acc1.x * inv + b1.x; o1.y = acc1.y * inv + b1.y;
    o1.z = acc1.z * inv + b1.z; o1.w = acc1.w * inv + b1.w;
    if (act) {
      o0.x = (o0.x > 0.f) ? o0.x : 0.01f * o0.x;
      o0.y = (o0.y > 0.f) ? o0.y : 0.01f * o0.y;
      o0.z = (o0.z > 0.f) ? o0.z : 0.01f * o0.z;
      o0.w = (o0.w > 0.f) ? o0.w : 0.01f * o0.w;
      o1.x = (o1.x > 0.f) ? o1.x : 0.01f * o1.x;
      o1.y = (o1.y > 0.f) ? o1.y : 0.01f * o1.y;
      o1.z = (o1.z > 0.f) ? o1.z : 0.01f * o1.z;
      o1.w = (o1.w > 0.f) ? o1.w : 0.01f * o1.w;
    }
    float4* op = (float4*)(out + (size_t)i * HID + j * 8);
    op[0] = o0;
    op[1] = o1;
  }
}

// final node GEMM (fp32, with bias) + fused vn column-sum of the INPUT tile
__global__ __launch_bounds__(256) void k_gemm128(
    const float* __restrict__ X, const float* __restrict__ W,
    const float* __restrict__ bias, float* __restrict__ O,
    float* __restrict__ vnsum) {
  __shared__ float sX[32][HID];
  __shared__ float sW[64][HID];
  int tid = threadIdx.x;
  int row0 = blockIdx.x * 32;
  {
    const float4* xs = (const float4*)(X + (size_t)row0 * HID);
    float4* xd = (float4*)(&sX[0][0]);
#pragma unroll
    for (int v = 0; v < 4; ++v) {
      int idx = tid + v * 256;
      int grow = row0 + (idx >> 5);
      xd[idx] = (grow < NN) ? xs[idx] : make_float4(0.f, 0.f, 0.f, 0.f);
    }
  }
  int colg = (tid & 31) * 4;
  int rowg = (tid >> 5) * 4;
  float acc[4][4] = {{0.f}};
  for (int kc = 0; kc < 2; ++kc) {
    __syncthreads();
    {
      const float4* wsp = (const float4*)(W + (size_t)kc * 64 * HID);
      float4* wd = (float4*)(&sW[0][0]);
#pragma unroll
      for (int v = 0; v < 8; ++v) wd[tid + v * 256] = wsp[tid + v * 256];
    }
    __syncthreads();
#pragma unroll 4
    for (int k4 = 0; k4 < 64; k4 += 4) {
      float4 wv0 = *(const float4*)(&sW[k4 + 0][colg]);
      float4 wv1 = *(const float4*)(&sW[k4 + 1][colg]);
      float4 wv2 = *(const float4*)(&sW[k4 + 2][colg]);
      float4 wv3 = *(const float4*)(&sW[k4 + 3][colg]);
#pragma unroll
      for (int r = 0; r < 4; ++r) {
        float4 xv = *(const float4*)(&sX[rowg + r][kc * 64 + k4]);
        acc[r][0] += xv.x * wv0.x + xv.y * wv1.x + xv.z * wv2.x + xv.w * wv3.x;
        acc[r][1] += xv.x * wv0.y + xv.y * wv1.y + xv.z * wv2.y + xv.w * wv3.y;
        acc[r][2] += xv.x * wv0.z + xv.y * wv1.z + xv.z * wv2.z + xv.w * wv3.z;
        acc[r][3] += xv.x * wv0.w + xv.y * wv1.w + xv.z * wv2.w + xv.w * wv3.w;
      }
    }
  }
#pragma unroll
  for (int r = 0; r < 4; ++r) {
    int grow = row0 + rowg + r;
    if (grow < NN) {
      float4 o;
      o.x = acc[r][0] + bias[colg + 0];
      o.y = acc[r][1] + bias[colg + 1];
      o.z = acc[r][2] + bias[colg + 2];
      o.w = acc[r][3] + bias[colg + 3];
      *(float4*)(O + (size_t)grow * HID + colg) = o;
    }
  }
  // vn partial: column sums of the input tile (padding rows are zero).
  // sX is stable after the first barrier; no extra sync needed.
  if (tid < HID) {
    float s = 0.f;
#pragma unroll
    for (int r = 0; r < 32; ++r) s += sX[r][tid];
    atomicAdd(&vnsum[tid], s);
  }
}

// ---------------- virtual-node path ----------------

__global__ void k_mlp(const float* __restrict__ vnsum, const float* __restrict__ vn_w,
                      const float* __restrict__ w1, const float* __restrict__ b1,
                      const float* __restrict__ w2, const float* __restrict__ b2,
                      const float* __restrict__ w3, const float* __restrict__ b3,
                      const float* __restrict__ w4, const float* __restrict__ b4,
                      float* __restrict__ outv) {
  __shared__ float xb[HID], yb[HID];
  int t = threadIdx.x;
  xb[t] = vnsum[t] + vn_w[t];
  __syncthreads();
  const float* Ws[4] = {w1, w2, w3, w4};
  const float* Bs[4] = {b1, b2, b3, b4};
  float* cur = xb;
  float* nxt = yb;
  for (int l = 0; l < 4; ++l) {
    const float* W = Ws[l];
    const float* B = Bs[l];
    float acc = B[t];
    for (int d = 0; d < HID; ++d) acc += cur[d] * W[d * HID + t];
    nxt[t] = fmaxf(acc, 0.f);
    __syncthreads();
    float* tmp = cur; cur = nxt; nxt = tmp;
  }
  outv[t] = cur[t];
}

// ---------------- launch ----------------

extern "C" void kernel_launch(void* const* d_in, const int* in_sizes, int n_in,
                              void* d_out, int out_size, void* d_ws, size_t ws_size,
                              hipStream_t stream) {
  const float* x = (const float*)d_in[0];
  const int* ei = (const int*)d_in[1];
  const float* edge_attr = (const float*)d_in[2];
  const float *W[3], *as_[3], *ad_[3], *We[3], *ae[3], *bb[3];
  for (int l = 0; l < 3; ++l) {
    W[l]   = (const float*)d_in[3 + l * 6 + 0];
    as_[l] = (const float*)d_in[3 + l * 6 + 1];
    ad_[l] = (const float*)d_in[3 + l * 6 + 2];
    We[l]  = (const float*)d_in[3 + l * 6 + 3];
    ae[l]  = (const float*)d_in[3 + l * 6 + 4];
    bb[l]  = (const float*)d_in[3 + l * 6 + 5];
  }
  const float* vn_w = (const float*)d_in[21];
  const float* m1w1 = (const float*)d_in[22];
  const float* m1b1 = (const float*)d_in[23];
  const float* m1w2 = (const float*)d_in[24];
  const float* m1b2 = (const float*)d_in[25];
  const float* m2w1 = (const float*)d_in[26];
  const float* m2b1 = (const float*)d_in[27];
  const float* m2w2 = (const float*)d_in[28];
  const float* m2b2 = (const float*)d_in[29];
  const float* Wout = (const float*)d_in[30];
  const float* bout = (const float*)d_in[31];

  char* ws = (char*)d_ws;
  size_t o = 0;
  auto alloc = [&](size_t bytes) {
    o = (o + 255) & ~(size_t)255;
    void* p = ws + o;
    o += bytes;
    return p;
  };
  unsigned short* hb = (unsigned short*)alloc((size_t)NN * HID * 2);
  float* outbuf  = (float*)alloc((size_t)NN * HID * 4);
  float4* esc4   = (float4*)alloc((size_t)EE * 16);
  float* esc_csr = (float*)alloc((size_t)3 * EE * 4);
  float* escself = (float*)alloc((size_t)3 * NN * 4);
  float* hs      = (float*)alloc((size_t)NN * 4);
  float* hd      = (float*)alloc((size_t)NN * 4);
  float* vnsum   = (float*)alloc(HID * 4);
  float* weae    = (float*)alloc(3 * ED * 4);
  int* cnt       = (int*)alloc((size_t)NN * 4);
  int* off       = (int*)alloc((size_t)(NN + 1) * 4);
  int* cursor    = (int*)alloc((size_t)NN * 4);
  int* sperm     = (int*)alloc((size_t)EE * 4);
  int* eid       = (int*)alloc((size_t)EE * 4);
  int* bsum      = (int*)alloc((size_t)SCAN_G * 4);
  int* bexc      = (int*)alloc((size_t)SCAN_G * 4);

  const int* srcv = ei;
  const int* dstv = ei + EE;

  k_zero<<<(NN + 255) / 256, 256, 0, stream>>>(cnt, vnsum);
  k_count<<<(EE + 255) / 256, 256, 0, stream>>>(dstv, cnt);
  k_scan1<<<SCAN_G, 256, 0, stream>>>(cnt, bsum);
  k_scan2<<<1, 256, 0, stream>>>(bsum, bexc, off);
  k_scan3<<<SCAN_G, 256, 0, stream>>>(cnt, bexc, off, cursor);
  k_scatter<<<(EE + 255) / 256, 256, 0, stream>>>(srcv, dstv, cursor, sperm, eid);
  k_weae<<<1, 256, 0, stream>>>(We[0], We[1], We[2], ae[0], ae[1], ae[2], weae);
  k_esc_eo<<<(EE + 63) / 64, 256, 0, stream>>>(edge_attr, weae, esc4);
  k_permself<<<(NN + 15) / 16, 256, 0, stream>>>(off, eid, esc4, esc_csr,
                                                 escself);

  const float* in_ptr = x;
  for (int l = 0; l < 3; ++l) {
    k_gemmA<<<(NN + 31) / 32, 256, 0, stream>>>(in_ptr, W[l], as_[l], ad_[l], hb,
                                                hs, hd);
    k_aggregate4<<<(NN + 3) / 4, 256, 0, stream>>>(
        hb, hs, hd, esc_csr + (size_t)l * EE, escself + (size_t)l * NN, sperm,
        off, bb[l], outbuf, (l > 0) ? 1 : 0);
    in_ptr = outbuf;
  }

  float* node_out = (float*)d_out;
  k_gemm128<<<(NN + 31) / 32, 256, 0, stream>>>(outbuf, Wout, bout, node_out,
                                                vnsum);
  k_mlp<<<1, 128, 0, stream>>>(vnsum, vn_w, m1w1, m1b1, m1w2, m1b2, m2w1, m2b1,
                               m2w2, m2b2, node_out + (size_t)NN * HID);
}

// Round 10
// 300.922 us; speedup vs baseline: 2.8611x; 1.3071x over previous
//
#include <hip/hip_runtime.h>

#define NN 50000
#define EE 400000
#define HID 128
#define ED 64
#define SCAN_G 196  // ceil(50000/256)
#define LDP 136     // padded LDS row stride (bf16 elems)

typedef __attribute__((ext_vector_type(8))) unsigned short ushort8_t;
typedef __attribute__((ext_vector_type(8))) short short8_t;
typedef __attribute__((ext_vector_type(4))) float f32x4;

// bf16 pack/unpack (RNE; values are finite)
static __device__ __forceinline__ unsigned short f2bf(float f) {
  unsigned u = __float_as_uint(f);
  unsigned r = (u + 0x7FFFu + ((u >> 16) & 1u)) >> 16;
  return (unsigned short)r;
}
static __device__ __forceinline__ float bf2f(unsigned short b) {
  return __uint_as_float((unsigned)b << 16);
}

// exclusive prefix of v across 256 threads; s must hold >=256 ints.
static __device__ __forceinline__ int block_excl_scan_256(int v, int* s) {
  int tid = threadIdx.x;
  s[tid] = v;
  __syncthreads();
  for (int d = 1; d < 256; d <<= 1) {
    int t = (tid >= d) ? s[tid - d] : 0;
    __syncthreads();
    s[tid] += t;
    __syncthreads();
  }
  return s[tid] - v;
}

// ---------------- setup kernels ----------------

__global__ void k_zero(int* __restrict__ cnt, float* __restrict__ vnsum) {
  int t = blockIdx.x * blockDim.x + threadIdx.x;
  if (t < NN) cnt[t] = 0;
  if (t < HID) vnsum[t] = 0.f;
}

__global__ void k_count(const int* __restrict__ dst, int* __restrict__ cnt) {
  int e = blockIdx.x * blockDim.x + threadIdx.x;
  if (e < EE) atomicAdd(&cnt[dst[e]], 1);
}

__global__ __launch_bounds__(256) void k_scan1(const int* __restrict__ cnt,
                                               int* __restrict__ bsum) {
  __shared__ int s[256];
  int idx = blockIdx.x * 256 + threadIdx.x;
  int v = (idx < NN) ? cnt[idx] : 0;
  s[threadIdx.x] = v;
  __syncthreads();
  for (int d = 128; d > 0; d >>= 1) {
    if (threadIdx.x < d) s[threadIdx.x] += s[threadIdx.x + d];
    __syncthreads();
  }
  if (threadIdx.x == 0) bsum[blockIdx.x] = s[0];
}

__global__ __launch_bounds__(256) void k_scan2(const int* __restrict__ bsum,
                                               int* __restrict__ bexc,
                                               int* __restrict__ off) {
  __shared__ int s[256];
  int t = threadIdx.x;
  int v = (t < SCAN_G) ? bsum[t] : 0;
  int exc = block_excl_scan_256(v, s);
  if (t < SCAN_G) bexc[t] = exc;
  if (t == 255) off[NN] = s[255];
}

__global__ __launch_bounds__(256) void k_scan3(const int* __restrict__ cnt,
                                               const int* __restrict__ bexc,
                                               int* __restrict__ off,
                                               int* __restrict__ cursor) {
  __shared__ int s[256];
  int idx = blockIdx.x * 256 + threadIdx.x;
  int v = (idx < NN) ? cnt[idx] : 0;
  int exc = block_excl_scan_256(v, s) + bexc[blockIdx.x];
  if (idx < NN) {
    off[idx] = exc;
    cursor[idx] = exc;
  }
}

__global__ void k_scatter(const int* __restrict__ src, const int* __restrict__ dst,
                          int* __restrict__ cursor, int* __restrict__ sperm,
                          int* __restrict__ eid) {
  int e = blockIdx.x * blockDim.x + threadIdx.x;
  if (e < EE) {
    int p = atomicAdd(&cursor[dst[e]], 1);
    sperm[p] = src[e];
    eid[p] = e;
  }
}

// we_ae[l] = We_l @ ae_l  (64-vector per layer)
__global__ void k_weae(const float* __restrict__ We0, const float* __restrict__ We1,
                       const float* __restrict__ We2, const float* __restrict__ ae0,
                       const float* __restrict__ ae1, const float* __restrict__ ae2,
                       float* __restrict__ weae) {
  int t = threadIdx.x;
  if (t >= 192) return;
  int l = t >> 6, j = t & 63;
  const float* We = (l == 0) ? We0 : (l == 1) ? We1 : We2;
  const float* ae = (l == 0) ? ae0 : (l == 1) ? ae1 : ae2;
  float acc = 0.f;
  for (int k = 0; k < HID; ++k) acc += We[j * HID + k] * ae[k];
  weae[l * ED + j] = acc;
}

// x (fp32) -> bf16, float4 granularity
__global__ void k_tobf(const float* __restrict__ in,
                       unsigned short* __restrict__ out, int n4) {
  int i = blockIdx.x * blockDim.x + threadIdx.x;
  if (i >= n4) return;
  float4 v = ((const float4*)in)[i];
  ushort4 o;
  o.x = f2bf(v.x); o.y = f2bf(v.y); o.z = f2bf(v.z); o.w = f2bf(v.w);
  ((ushort4*)out)[i] = o;
}

// 4 weight mats [K=128][N=128] fp32 -> bf16 transposed [N][K]
__global__ void k_prepw(const float* __restrict__ W0, const float* __restrict__ W1,
                        const float* __restrict__ W2, const float* __restrict__ Wo,
                        unsigned short* __restrict__ Wt) {
  int idx = blockIdx.x * 256 + threadIdx.x;  // 65536 total
  int m = idx >> 14;
  int rem = idx & 16383;
  int k = rem >> 7;
  int n = rem & 127;  // n fastest -> coalesced reads
  const float* W = (m == 0) ? W0 : (m == 1) ? W1 : (m == 2) ? W2 : Wo;
  Wt[(size_t)m * 16384 + n * 128 + k] = f2bf(W[k * 128 + n]);
}

// per-REAL-edge scalars in EDGE order, packed float4 {e0,e1,e2,0}.
__global__ __launch_bounds__(256) void k_esc_eo(
    const float* __restrict__ edge_attr, const float* __restrict__ weae,
    float4* __restrict__ esc4) {
  __shared__ float4 sw[3][16];
  int tid = threadIdx.x;
  if (tid < 48) ((float4*)sw)[tid] = ((const float4*)weae)[tid];
  __syncthreads();
  int c = tid & 15;
  int r0 = tid >> 4;
  float4 w0 = sw[0][c], w1 = sw[1][c], w2 = sw[2][c];
#pragma unroll
  for (int pass = 0; pass < 4; ++pass) {
    int row = blockIdx.x * 64 + pass * 16 + r0;
    if (row < EE) {
      float4 v = ((const float4*)edge_attr)[(size_t)row * 16 + c];
      float a0 = v.x * w0.x + v.y * w0.y + v.z * w0.z + v.w * w0.w;
      float a1 = v.x * w1.x + v.y * w1.y + v.z * w1.z + v.w * w1.w;
      float a2 = v.x * w2.x + v.y * w2.y + v.z * w2.z + v.w * w2.w;
#pragma unroll
      for (int o = 1; o < 16; o <<= 1) {
        a0 += __shfl_xor(a0, o, 64);
        a1 += __shfl_xor(a1, o, 64);
        a2 += __shfl_xor(a2, o, 64);
      }
      if (c == 0) esc4[row] = make_float4(a0, a1, a2, 0.f);
    }
  }
}

// permute esc to CSR planes + self-loop mean. 16-lane group per node.
__global__ __launch_bounds__(256) void k_permself(
    const int* __restrict__ off, const int* __restrict__ eid,
    const float4* __restrict__ esc4, float* __restrict__ esc_csr,
    float* __restrict__ escself) {
  int i = blockIdx.x * 16 + (threadIdx.x >> 4);
  int g = threadIdx.x & 15;
  if (i >= NN) return;
  int s0 = off[i], s1 = off[i + 1];
  float a0 = 0.f, a1 = 0.f, a2 = 0.f;
  for (int p = s0 + g; p < s1; p += 16) {
    float4 v = esc4[eid[p]];
    esc_csr[p] = v.x;
    esc_csr[(size_t)EE + p] = v.y;
    esc_csr[(size_t)2 * EE + p] = v.z;
    a0 += v.x;
    a1 += v.y;
    a2 += v.z;
  }
#pragma unroll
  for (int o = 8; o > 0; o >>= 1) {
    a0 += __shfl_xor(a0, o, 64);
    a1 += __shfl_xor(a1, o, 64);
    a2 += __shfl_xor(a2, o, 64);
  }
  if (g == 0) {
    int deg = s1 - s0;
    float inv = 1.f / (float)(deg > 1 ? deg : 1);
    escself[i] = a0 * inv;
    escself[(size_t)NN + i] = a1 * inv;
    escself[(size_t)2 * NN + i] = a2 * inv;
  }
}

// ---------------- MFMA GEMM (64 rows x 128 cols per block, 4 waves) --------
// A bf16 [NN][128]; Bt bf16 [128n][128k]. Frag: lane l holds k=(l>>4)*8+e.

// gemmA: hb(bf16) = A@W ; hs/hd fused from fp32 accumulators.
__global__ __launch_bounds__(256) void k_gemmA(
    const unsigned short* __restrict__ A, const unsigned short* __restrict__ Bt,
    const float* __restrict__ as_, const float* __restrict__ ad_,
    unsigned short* __restrict__ hb, float* __restrict__ hs,
    float* __restrict__ hd) {
  __shared__ unsigned short sA[64][LDP];
  __shared__ unsigned short sB[128][LDP];
  int tid = threadIdx.x;
  int row0 = blockIdx.x * 64;
  {
    int r = tid >> 2, sg = (tid & 3) * 32;
    int grow = row0 + r;
    const ushort8_t* src = (const ushort8_t*)(A + (size_t)grow * HID + sg);
    ushort8_t z = {0, 0, 0, 0, 0, 0, 0, 0};
#pragma unroll
    for (int i = 0; i < 4; ++i)
      *(ushort8_t*)&sA[r][sg + i * 8] = (grow < NN) ? src[i] : z;
  }
  {
    int r = tid >> 1, sg = (tid & 1) * 64;
    const ushort8_t* src = (const ushort8_t*)(Bt + r * HID + sg);
#pragma unroll
    for (int i = 0; i < 8; ++i) *(ushort8_t*)&sB[r][sg + i * 8] = src[i];
  }
  __syncthreads();
  int w = tid >> 6, l = tid & 63;
  int lr = l & 15, lg = l >> 4;
  f32x4 acc[8] = {};
  const unsigned short* pa = &sA[w * 16 + lr][lg * 8];
  const unsigned short* pb = &sB[lr][lg * 8];
#pragma unroll
  for (int ks = 0; ks < 4; ++ks) {
    short8_t a = *(const short8_t*)(pa + ks * 32);
#pragma unroll
    for (int ct = 0; ct < 8; ++ct) {
      short8_t b = *(const short8_t*)(pb + ct * 16 * LDP + ks * 32);
      acc[ct] = __builtin_amdgcn_mfma_f32_16x16x32_bf16(a, b, acc[ct], 0, 0, 0);
    }
  }
  int orow = row0 + w * 16 + lg * 4;
  // bf16 h writes
#pragma unroll
  for (int ct = 0; ct < 8; ++ct) {
    int col = ct * 16 + lr;
#pragma unroll
    for (int r = 0; r < 4; ++r) {
      int grow = orow + r;
      if (grow < NN) hb[(size_t)grow * HID + col] = f2bf(acc[ct][r]);
    }
  }
  // hs/hd: per-row dot with a_s/a_d, reduce across 16 lanes
  float asv[8], adv[8];
#pragma unroll
  for (int ct = 0; ct < 8; ++ct) {
    asv[ct] = as_[ct * 16 + lr];
    adv[ct] = ad_[ct * 16 + lr];
  }
#pragma unroll
  for (int r = 0; r < 4; ++r) {
    float ps = 0.f, pd = 0.f;
#pragma unroll
    for (int ct = 0; ct < 8; ++ct) {
      ps += acc[ct][r] * asv[ct];
      pd += acc[ct][r] * adv[ct];
    }
#pragma unroll
    for (int o = 1; o < 16; o <<= 1) {
      ps += __shfl_xor(ps, o, 64);
      pd += __shfl_xor(pd, o, 64);
    }
    int grow = orow + r;
    if (lr == 0 && grow < NN) {
      hs[grow] = ps;
      hd[grow] = pd;
    }
  }
}

// gemmO: node_out(fp32) = A@W + bias ; vnsum += column sums of A tile.
__global__ __launch_bounds__(256) void k_gemmO(
    const unsigned short* __restrict__ A, const unsigned short* __restrict__ Bt,
    const float* __restrict__ bias, float* __restrict__ O,
    float* __restrict__ vnsum) {
  __shared__ unsigned short sA[64][LDP];
  __shared__ unsigned short sB[128][LDP];
  int tid = threadIdx.x;
  int row0 = blockIdx.x * 64;
  {
    int r = tid >> 2, sg = (tid & 3) * 32;
    int grow = row0 + r;
    const ushort8_t* src = (const ushort8_t*)(A + (size_t)grow * HID + sg);
    ushort8_t z = {0, 0, 0, 0, 0, 0, 0, 0};
#pragma unroll
    for (int i = 0; i < 4; ++i)
      *(ushort8_t*)&sA[r][sg + i * 8] = (grow < NN) ? src[i] : z;
  }
  {
    int r = tid >> 1, sg = (tid & 1) * 64;
    const ushort8_t* src = (const ushort8_t*)(Bt + r * HID + sg);
#pragma unroll
    for (int i = 0; i < 8; ++i) *(ushort8_t*)&sB[r][sg + i * 8] = src[i];
  }
  __syncthreads();
  int w = tid >> 6, l = tid & 63;
  int lr = l & 15, lg = l >> 4;
  f32x4 acc[8] = {};
  const unsigned short* pa = &sA[w * 16 + lr][lg * 8];
  const unsigned short* pb = &sB[lr][lg * 8];
#pragma unroll
  for (int ks = 0; ks < 4; ++ks) {
    short8_t a = *(const short8_t*)(pa + ks * 32);
#pragma unroll
    for (int ct = 0; ct < 8; ++ct) {
      short8_t b = *(const short8_t*)(pb + ct * 16 * LDP + ks * 32);
      acc[ct] = __builtin_amdgcn_mfma_f32_16x16x32_bf16(a, b, acc[ct], 0, 0, 0);
    }
  }
  int orow = row0 + w * 16 + lg * 4;
#pragma unroll
  for (int ct = 0; ct < 8; ++ct) {
    int col = ct * 16 + lr;
    float bv = bias[col];
#pragma unroll
    for (int r = 0; r < 4; ++r) {
      int grow = orow + r;
      if (grow < NN) O[(size_t)grow * HID + col] = acc[ct][r] + bv;
    }
  }
  // vn partial: column sums of the (zero-padded) input tile
  if (tid < HID) {
    float s = 0.f;
#pragma unroll
    for (int r = 0; r < 64; ++r) s += bf2f(sA[r][tid]);
    atomicAdd(&vnsum[tid], s);
  }
}

// ---------------- aggregate (bf16 out) ----------------

__global__ __launch_bounds__(256) void k_aggregate4(
    const unsigned short* __restrict__ hb, const float* __restrict__ hs,
    const float* __restrict__ hd, const float* __restrict__ escl,
    const float* __restrict__ esl, const int* __restrict__ sperm,
    const int* __restrict__ off, const float* __restrict__ bias,
    unsigned short* __restrict__ outb, int act) {
  int i = blockIdx.x * 4 + (threadIdx.x >> 6);
  int lane = threadIdx.x & 63;
  if (i >= NN) return;
  int g = lane >> 4;
  int j = lane & 15;
  int s0 = off[i];
  int deg = off[i + 1] - s0;
  int nt = deg + 1;  // + self-loop
  float hdi = hd[i];
  float den = 0.f;
  float4 acc0 = make_float4(0.f, 0.f, 0.f, 0.f);
  float4 acc1 = make_float4(0.f, 0.f, 0.f, 0.f);
  for (int t0 = 0; t0 < nt; t0 += 4) {
    int t = t0 + g;
    if (t < nt) {
      int s;
      float av;
      if (t < deg) {
        s = sperm[s0 + t];
        av = hs[s] + hdi + escl[s0 + t];
      } else {
        s = i;
        av = hs[i] + hdi + esl[i];
      }
      av = (av > 0.f) ? av : 0.2f * av;
      float w = __expf(av);
      den += w;
      ushort8_t hv = *(const ushort8_t*)(hb + (size_t)s * HID + j * 8);
      acc0.x += w * bf2f(hv[0]);
      acc0.y += w * bf2f(hv[1]);
      acc0.z += w * bf2f(hv[2]);
      acc0.w += w * bf2f(hv[3]);
      acc1.x += w * bf2f(hv[4]);
      acc1.y += w * bf2f(hv[5]);
      acc1.z += w * bf2f(hv[6]);
      acc1.w += w * bf2f(hv[7]);
    }
  }
#pragma unroll
  for (int o = 16; o <= 32; o <<= 1) {
    acc0.x += __shfl_xor(acc0.x, o, 64);
    acc0.y += __shfl_xor(acc0.y, o, 64);
    acc0.z += __shfl_xor(acc0.z, o, 64);
    acc0.w += __shfl_xor(acc0.w, o, 64);
    acc1.x += __shfl_xor(acc1.x, o, 64);
    acc1.y += __shfl_xor(acc1.y, o, 64);
    acc1.z += __shfl_xor(acc1.z, o, 64);
    acc1.w += __shfl_xor(acc1.w, o, 64);
    den += __shfl_xor(den, o, 64);
  }
  if (g == 0) {
    float inv = 1.f / den;
    const float4* bp = (const float4*)(bias + j * 8);
    float4 b0 = bp[0], b1 = bp[1];
    float v[8];
    v[0] = acc0.x * inv + b0.x; v[1] = acc0.y * inv + b0.y;
    v[2] = acc0.z * inv + b0.z; v[3] = acc0.w * inv + b0.w;
    v[4] = acc1.x * inv + b1.x; v[5] = acc1.y * inv + b1.y;
    v[6] = acc1.z * inv + b1.z; v[7] = acc1.w * inv + b1.w;
    ushort8_t ob;
#pragma unroll
    for (int q = 0; q < 8; ++q) {
      float t = v[q];
      if (act) t = (t > 0.f) ? t : 0.01f * t;
      ob[q] = f2bf(t);
    }
    *(ushort8_t*)(outb + (size_t)i * HID + j * 8) = ob;
  }
}

// ---------------- virtual-node MLP ----------------

__global__ void k_mlp(const float* __restrict__ vnsum, const float* __restrict__ vn_w,
                      const float* __restrict__ w1, const float* __restrict__ b1,
                      const float* __restrict__ w2, const float* __restrict__ b2,
                      const float* __restrict__ w3, const float* __restrict__ b3,
                      const float* __restrict__ w4, const float* __restrict__ b4,
                      float* __restrict__ outv) {
  __shared__ float xb[HID], yb[HID];
  int t = threadIdx.x;
  xb[t] = vnsum[t] + vn_w[t];
  __syncthreads();
  const float* Ws[4] = {w1, w2, w3, w4};
  const float* Bs[4] = {b1, b2, b3, b4};
  float* cur = xb;
  float* nxt = yb;
  for (int l = 0; l < 4; ++l) {
    const float* W = Ws[l];
    const float* B = Bs[l];
    float acc = B[t];
    for (int d = 0; d < HID; ++d) acc += cur[d] * W[d * HID + t];
    nxt[t] = fmaxf(acc, 0.f);
    __syncthreads();
    float* tmp = cur; cur = nxt; nxt = tmp;
  }
  outv[t] = cur[t];
}

// ---------------- launch ----------------

extern "C" void kernel_launch(void* const* d_in, const int* in_sizes, int n_in,
                              void* d_out, int out_size, void* d_ws, size_t ws_size,
                              hipStream_t stream) {
  const float* x = (const float*)d_in[0];
  const int* ei = (const int*)d_in[1];
  const float* edge_attr = (const float*)d_in[2];
  const float *W[3], *as_[3], *ad_[3], *We[3], *ae[3], *bb[3];
  for (int l = 0; l < 3; ++l) {
    W[l]   = (const float*)d_in[3 + l * 6 + 0];
    as_[l] = (const float*)d_in[3 + l * 6 + 1];
    ad_[l] = (const float*)d_in[3 + l * 6 + 2];
    We[l]  = (const float*)d_in[3 + l * 6 + 3];
    ae[l]  = (const float*)d_in[3 + l * 6 + 4];
    bb[l]  = (const float*)d_in[3 + l * 6 + 5];
  }
  const float* vn_w = (const float*)d_in[21];
  const float* m1w1 = (const float*)d_in[22];
  const float* m1b1 = (const float*)d_in[23];
  const float* m1w2 = (const float*)d_in[24];
  const float* m1b2 = (const float*)d_in[25];
  const float* m2w1 = (const float*)d_in[26];
  const float* m2b1 = (const float*)d_in[27];
  const float* m2w2 = (const float*)d_in[28];
  const float* m2b2 = (const float*)d_in[29];
  const float* Wout = (const float*)d_in[30];
  const float* bout = (const float*)d_in[31];

  char* ws = (char*)d_ws;
  size_t o = 0;
  auto alloc = [&](size_t bytes) {
    o = (o + 255) & ~(size_t)255;
    void* p = ws + o;
    o += bytes;
    return p;
  };
  unsigned short* xb  = (unsigned short*)alloc((size_t)NN * HID * 2);
  unsigned short* hb  = (unsigned short*)alloc((size_t)NN * HID * 2);
  unsigned short* outb = (unsigned short*)alloc((size_t)NN * HID * 2);
  unsigned short* Wtb = (unsigned short*)alloc((size_t)4 * HID * HID * 2);
  float4* esc4   = (float4*)alloc((size_t)EE * 16);
  float* esc_csr = (float*)alloc((size_t)3 * EE * 4);
  float* escself = (float*)alloc((size_t)3 * NN * 4);
  float* hs      = (float*)alloc((size_t)NN * 4);
  float* hd      = (float*)alloc((size_t)NN * 4);
  float* vnsum   = (float*)alloc(HID * 4);
  float* weae    = (float*)alloc(3 * ED * 4);
  int* cnt       = (int*)alloc((size_t)NN * 4);
  int* off       = (int*)alloc((size_t)(NN + 1) * 4);
  int* cursor    = (int*)alloc((size_t)NN * 4);
  int* sperm     = (int*)alloc((size_t)EE * 4);
  int* eid       = (int*)alloc((size_t)EE * 4);
  int* bsum      = (int*)alloc((size_t)SCAN_G * 4);
  int* bexc      = (int*)alloc((size_t)SCAN_G * 4);

  const int* srcv = ei;
  const int* dstv = ei + EE;

  k_zero<<<(NN + 255) / 256, 256, 0, stream>>>(cnt, vnsum);
  k_count<<<(EE + 255) / 256, 256, 0, stream>>>(dstv, cnt);
  k_scan1<<<SCAN_G, 256, 0, stream>>>(cnt, bsum);
  k_scan2<<<1, 256, 0, stream>>>(bsum, bexc, off);
  k_scan3<<<SCAN_G, 256, 0, stream>>>(cnt, bexc, off, cursor);
  k_scatter<<<(EE + 255) / 256, 256, 0, stream>>>(srcv, dstv, cursor, sperm, eid);
  k_weae<<<1, 256, 0, stream>>>(We[0], We[1], We[2], ae[0], ae[1], ae[2], weae);
  k_tobf<<<(NN * HID / 4 + 255) / 256, 256, 0, stream>>>(x, xb, NN * HID / 4);
  k_prepw<<<256, 256, 0, stream>>>(W[0], W[1], W[2], Wout, Wtb);
  k_esc_eo<<<(EE + 63) / 64, 256, 0, stream>>>(edge_attr, weae, esc4);
  k_permself<<<(NN + 15) / 16, 256, 0, stream>>>(off, eid, esc4, esc_csr,
                                                 escself);

  const unsigned short* in_b = xb;
  for (int l = 0; l < 3; ++l) {
    k_gemmA<<<(NN + 63) / 64, 256, 0, stream>>>(
        in_b, Wtb + (size_t)l * HID * HID, as_[l], ad_[l], hb, hs, hd);
    k_aggregate4<<<(NN + 3) / 4, 256, 0, stream>>>(
        hb, hs, hd, esc_csr + (size_t)l * EE, escself + (size_t)l * NN, sperm,
        off, bb[l], outb, (l > 0) ? 1 : 0);
    in_b = outb;
  }

  float* node_out = (float*)d_out;
  k_gemmO<<<(NN + 63) / 64, 256, 0, stream>>>(
      outb, Wtb + (size_t)3 * HID * HID, bout, node_out, vnsum);
  k_mlp<<<1, 128, 0, stream>>>(vnsum, vn_w, m1w1, m1b1, m1w2, m1b2, m2w1, m2b1,
                               m2w2, m2b2, node_out + (size_t)NN * HID);
}

// Round 11
// 287.698 us; speedup vs baseline: 2.9927x; 1.0460x over previous
//
#include <hip/hip_runtime.h>

#define NN 50000
#define EE 400000
#define HID 128
#define ED 64
#define SCAN_G 196  // ceil(50000/256)
#define LDP 136     // padded LDS row stride (bf16 elems)

typedef __attribute__((ext_vector_type(8))) unsigned short ushort8_t;
typedef __attribute__((ext_vector_type(8))) short short8_t;
typedef __attribute__((ext_vector_type(4))) float f32x4;

// bf16 pack/unpack (RNE; values are finite)
static __device__ __forceinline__ unsigned short f2bf(float f) {
  unsigned u = __float_as_uint(f);
  unsigned r = (u + 0x7FFFu + ((u >> 16) & 1u)) >> 16;
  return (unsigned short)r;
}
static __device__ __forceinline__ float bf2f(unsigned short b) {
  return __uint_as_float((unsigned)b << 16);
}

// exclusive prefix of v across 256 threads; s must hold >=256 ints.
static __device__ __forceinline__ int block_excl_scan_256(int v, int* s) {
  int tid = threadIdx.x;
  s[tid] = v;
  __syncthreads();
  for (int d = 1; d < 256; d <<= 1) {
    int t = (tid >= d) ? s[tid - d] : 0;
    __syncthreads();
    s[tid] += t;
    __syncthreads();
  }
  return s[tid] - v;
}

// ---------------- setup kernels ----------------

__global__ void k_zero(int* __restrict__ cnt, float* __restrict__ vnsum) {
  int t = blockIdx.x * blockDim.x + threadIdx.x;
  if (t < NN) cnt[t] = 0;
  if (t < HID) vnsum[t] = 0.f;
}

__global__ void k_count(const int* __restrict__ dst, int* __restrict__ cnt) {
  int e = blockIdx.x * blockDim.x + threadIdx.x;
  if (e < EE) atomicAdd(&cnt[dst[e]], 1);
}

__global__ __launch_bounds__(256) void k_scan1(const int* __restrict__ cnt,
                                               int* __restrict__ bsum) {
  __shared__ int s[256];
  int idx = blockIdx.x * 256 + threadIdx.x;
  int v = (idx < NN) ? cnt[idx] : 0;
  s[threadIdx.x] = v;
  __syncthreads();
  for (int d = 128; d > 0; d >>= 1) {
    if (threadIdx.x < d) s[threadIdx.x] += s[threadIdx.x + d];
    __syncthreads();
  }
  if (threadIdx.x == 0) bsum[blockIdx.x] = s[0];
}

__global__ __launch_bounds__(256) void k_scan2(const int* __restrict__ bsum,
                                               int* __restrict__ bexc,
                                               int* __restrict__ off) {
  __shared__ int s[256];
  int t = threadIdx.x;
  int v = (t < SCAN_G) ? bsum[t] : 0;
  int exc = block_excl_scan_256(v, s);
  if (t < SCAN_G) bexc[t] = exc;
  if (t == 255) off[NN] = s[255];
}

__global__ __launch_bounds__(256) void k_scan3(const int* __restrict__ cnt,
                                               const int* __restrict__ bexc,
                                               int* __restrict__ off,
                                               int* __restrict__ cursor) {
  __shared__ int s[256];
  int idx = blockIdx.x * 256 + threadIdx.x;
  int v = (idx < NN) ? cnt[idx] : 0;
  int exc = block_excl_scan_256(v, s) + bexc[blockIdx.x];
  if (idx < NN) {
    off[idx] = exc;
    cursor[idx] = exc;
  }
}

__global__ void k_scatter(const int* __restrict__ src, const int* __restrict__ dst,
                          int* __restrict__ cursor, int* __restrict__ sperm,
                          int* __restrict__ eid) {
  int e = blockIdx.x * blockDim.x + threadIdx.x;
  if (e < EE) {
    int p = atomicAdd(&cursor[dst[e]], 1);
    sperm[p] = src[e];
    eid[p] = e;
  }
}

// we_ae[l] = We_l @ ae_l  (64-vector per layer)
__global__ void k_weae(const float* __restrict__ We0, const float* __restrict__ We1,
                       const float* __restrict__ We2, const float* __restrict__ ae0,
                       const float* __restrict__ ae1, const float* __restrict__ ae2,
                       float* __restrict__ weae) {
  int t = threadIdx.x;
  if (t >= 192) return;
  int l = t >> 6, j = t & 63;
  const float* We = (l == 0) ? We0 : (l == 1) ? We1 : We2;
  const float* ae = (l == 0) ? ae0 : (l == 1) ? ae1 : ae2;
  float acc = 0.f;
  for (int k = 0; k < HID; ++k) acc += We[j * HID + k] * ae[k];
  weae[l * ED + j] = acc;
}

// x (fp32) -> bf16, float4 granularity
__global__ void k_tobf(const float* __restrict__ in,
                       unsigned short* __restrict__ out, int n4) {
  int i = blockIdx.x * blockDim.x + threadIdx.x;
  if (i >= n4) return;
  float4 v = ((const float4*)in)[i];
  ushort4 o;
  o.x = f2bf(v.x); o.y = f2bf(v.y); o.z = f2bf(v.z); o.w = f2bf(v.w);
  ((ushort4*)out)[i] = o;
}

// 4 weight mats [K=128][N=128] fp32 -> bf16 transposed [N][K]
__global__ void k_prepw(const float* __restrict__ W0, const float* __restrict__ W1,
                        const float* __restrict__ W2, const float* __restrict__ Wo,
                        unsigned short* __restrict__ Wt) {
  int idx = blockIdx.x * 256 + threadIdx.x;  // 65536 total
  int m = idx >> 14;
  int rem = idx & 16383;
  int k = rem >> 7;
  int n = rem & 127;  // n fastest -> coalesced reads
  const float* W = (m == 0) ? W0 : (m == 1) ? W1 : (m == 2) ? W2 : Wo;
  Wt[(size_t)m * 16384 + n * 128 + k] = f2bf(W[k * 128 + n]);
}

// per-REAL-edge scalars in EDGE order, packed float4 {e0,e1,e2,0}.
__global__ __launch_bounds__(256) void k_esc_eo(
    const float* __restrict__ edge_attr, const float* __restrict__ weae,
    float4* __restrict__ esc4) {
  __shared__ float4 sw[3][16];
  int tid = threadIdx.x;
  if (tid < 48) ((float4*)sw)[tid] = ((const float4*)weae)[tid];
  __syncthreads();
  int c = tid & 15;
  int r0 = tid >> 4;
  float4 w0 = sw[0][c], w1 = sw[1][c], w2 = sw[2][c];
#pragma unroll
  for (int pass = 0; pass < 4; ++pass) {
    int row = blockIdx.x * 64 + pass * 16 + r0;
    if (row < EE) {
      float4 v = ((const float4*)edge_attr)[(size_t)row * 16 + c];
      float a0 = v.x * w0.x + v.y * w0.y + v.z * w0.z + v.w * w0.w;
      float a1 = v.x * w1.x + v.y * w1.y + v.z * w1.z + v.w * w1.w;
      float a2 = v.x * w2.x + v.y * w2.y + v.z * w2.z + v.w * w2.w;
#pragma unroll
      for (int o = 1; o < 16; o <<= 1) {
        a0 += __shfl_xor(a0, o, 64);
        a1 += __shfl_xor(a1, o, 64);
        a2 += __shfl_xor(a2, o, 64);
      }
      if (c == 0) esc4[row] = make_float4(a0, a1, a2, 0.f);
    }
  }
}

// permute esc to CSR planes + self-loop mean. 16-lane group per node.
__global__ __launch_bounds__(256) void k_permself(
    const int* __restrict__ off, const int* __restrict__ eid,
    const float4* __restrict__ esc4, float* __restrict__ esc_csr,
    float* __restrict__ escself) {
  int i = blockIdx.x * 16 + (threadIdx.x >> 4);
  int g = threadIdx.x & 15;
  if (i >= NN) return;
  int s0 = off[i], s1 = off[i + 1];
  float a0 = 0.f, a1 = 0.f, a2 = 0.f;
  for (int p = s0 + g; p < s1; p += 16) {
    float4 v = esc4[eid[p]];
    esc_csr[p] = v.x;
    esc_csr[(size_t)EE + p] = v.y;
    esc_csr[(size_t)2 * EE + p] = v.z;
    a0 += v.x;
    a1 += v.y;
    a2 += v.z;
  }
#pragma unroll
  for (int o = 8; o > 0; o >>= 1) {
    a0 += __shfl_xor(a0, o, 64);
    a1 += __shfl_xor(a1, o, 64);
    a2 += __shfl_xor(a2, o, 64);
  }
  if (g == 0) {
    int deg = s1 - s0;
    float inv = 1.f / (float)(deg > 1 ? deg : 1);
    escself[i] = a0 * inv;
    escself[(size_t)NN + i] = a1 * inv;
    escself[(size_t)2 * NN + i] = a2 * inv;
  }
}

// ---------------- MFMA GEMM (64 rows x 128 cols per block, 4 waves) --------

__global__ __launch_bounds__(256) void k_gemmA(
    const unsigned short* __restrict__ A, const unsigned short* __restrict__ Bt,
    const float* __restrict__ as_, const float* __restrict__ ad_,
    unsigned short* __restrict__ hb, float* __restrict__ hs,
    float* __restrict__ hd) {
  __shared__ unsigned short sA[64][LDP];
  __shared__ unsigned short sB[128][LDP];
  int tid = threadIdx.x;
  int row0 = blockIdx.x * 64;
  {
    int r = tid >> 2, sg = (tid & 3) * 32;
    int grow = row0 + r;
    const ushort8_t* src = (const ushort8_t*)(A + (size_t)grow * HID + sg);
    ushort8_t z = {0, 0, 0, 0, 0, 0, 0, 0};
#pragma unroll
    for (int i = 0; i < 4; ++i)
      *(ushort8_t*)&sA[r][sg + i * 8] = (grow < NN) ? src[i] : z;
  }
  {
    int r = tid >> 1, sg = (tid & 1) * 64;
    const ushort8_t* src = (const ushort8_t*)(Bt + r * HID + sg);
#pragma unroll
    for (int i = 0; i < 8; ++i) *(ushort8_t*)&sB[r][sg + i * 8] = src[i];
  }
  __syncthreads();
  int w = tid >> 6, l = tid & 63;
  int lr = l & 15, lg = l >> 4;
  f32x4 acc[8] = {};
  const unsigned short* pa = &sA[w * 16 + lr][lg * 8];
  const unsigned short* pb = &sB[lr][lg * 8];
#pragma unroll
  for (int ks = 0; ks < 4; ++ks) {
    short8_t a = *(const short8_t*)(pa + ks * 32);
#pragma unroll
    for (int ct = 0; ct < 8; ++ct) {
      short8_t b = *(const short8_t*)(pb + ct * 16 * LDP + ks * 32);
      acc[ct] = __builtin_amdgcn_mfma_f32_16x16x32_bf16(a, b, acc[ct], 0, 0, 0);
    }
  }
  int orow = row0 + w * 16 + lg * 4;
#pragma unroll
  for (int ct = 0; ct < 8; ++ct) {
    int col = ct * 16 + lr;
#pragma unroll
    for (int r = 0; r < 4; ++r) {
      int grow = orow + r;
      if (grow < NN) hb[(size_t)grow * HID + col] = f2bf(acc[ct][r]);
    }
  }
  float asv[8], adv[8];
#pragma unroll
  for (int ct = 0; ct < 8; ++ct) {
    asv[ct] = as_[ct * 16 + lr];
    adv[ct] = ad_[ct * 16 + lr];
  }
#pragma unroll
  for (int r = 0; r < 4; ++r) {
    float ps = 0.f, pd = 0.f;
#pragma unroll
    for (int ct = 0; ct < 8; ++ct) {
      ps += acc[ct][r] * asv[ct];
      pd += acc[ct][r] * adv[ct];
    }
#pragma unroll
    for (int o = 1; o < 16; o <<= 1) {
      ps += __shfl_xor(ps, o, 64);
      pd += __shfl_xor(pd, o, 64);
    }
    int grow = orow + r;
    if (lr == 0 && grow < NN) {
      hs[grow] = ps;
      hd[grow] = pd;
    }
  }
}

__global__ __launch_bounds__(256) void k_gemmO(
    const unsigned short* __restrict__ A, const unsigned short* __restrict__ Bt,
    const float* __restrict__ bias, float* __restrict__ O,
    float* __restrict__ vnsum) {
  __shared__ unsigned short sA[64][LDP];
  __shared__ unsigned short sB[128][LDP];
  int tid = threadIdx.x;
  int row0 = blockIdx.x * 64;
  {
    int r = tid >> 2, sg = (tid & 3) * 32;
    int grow = row0 + r;
    const ushort8_t* src = (const ushort8_t*)(A + (size_t)grow * HID + sg);
    ushort8_t z = {0, 0, 0, 0, 0, 0, 0, 0};
#pragma unroll
    for (int i = 0; i < 4; ++i)
      *(ushort8_t*)&sA[r][sg + i * 8] = (grow < NN) ? src[i] : z;
  }
  {
    int r = tid >> 1, sg = (tid & 1) * 64;
    const ushort8_t* src = (const ushort8_t*)(Bt + r * HID + sg);
#pragma unroll
    for (int i = 0; i < 8; ++i) *(ushort8_t*)&sB[r][sg + i * 8] = src[i];
  }
  __syncthreads();
  int w = tid >> 6, l = tid & 63;
  int lr = l & 15, lg = l >> 4;
  f32x4 acc[8] = {};
  const unsigned short* pa = &sA[w * 16 + lr][lg * 8];
  const unsigned short* pb = &sB[lr][lg * 8];
#pragma unroll
  for (int ks = 0; ks < 4; ++ks) {
    short8_t a = *(const short8_t*)(pa + ks * 32);
#pragma unroll
    for (int ct = 0; ct < 8; ++ct) {
      short8_t b = *(const short8_t*)(pb + ct * 16 * LDP + ks * 32);
      acc[ct] = __builtin_amdgcn_mfma_f32_16x16x32_bf16(a, b, acc[ct], 0, 0, 0);
    }
  }
  int orow = row0 + w * 16 + lg * 4;
#pragma unroll
  for (int ct = 0; ct < 8; ++ct) {
    int col = ct * 16 + lr;
    float bv = bias[col];
#pragma unroll
    for (int r = 0; r < 4; ++r) {
      int grow = orow + r;
      if (grow < NN) O[(size_t)grow * HID + col] = acc[ct][r] + bv;
    }
  }
  if (tid < HID) {
    float s = 0.f;
#pragma unroll
    for (int r = 0; r < 64; ++r) s += bf2f(sA[r][tid]);
    atomicAdd(&vnsum[tid], s);
  }
}

// ---------------- aggregate: two-phase (parallel alpha, streamed gather) ---

__global__ __launch_bounds__(256) void k_aggregate5(
    const unsigned short* __restrict__ hb, const float* __restrict__ hs,
    const float* __restrict__ hd, const float* __restrict__ escl,
    const float* __restrict__ esl, const int* __restrict__ sperm,
    const int* __restrict__ off, const float* __restrict__ bias,
    unsigned short* __restrict__ outb, int act) {
  int i = blockIdx.x * 4 + (threadIdx.x >> 6);
  int lane = threadIdx.x & 63;
  if (i >= NN) return;
  int g = lane >> 4;
  int j = lane & 15;
  int s0 = off[i];
  int deg = off[i + 1] - s0;
  int nt = deg + 1;  // + self-loop
  float hdi = hd[i];
  float den_l = 0.f;
  float4 acc0 = make_float4(0.f, 0.f, 0.f, 0.f);
  float4 acc1 = make_float4(0.f, 0.f, 0.f, 0.f);
  for (int base = 0; base < nt; base += 64) {
    // phase A: all lanes compute w for edge (base+lane) in parallel
    int t = base + lane;
    int sv = i;
    float w = 0.f;
    if (t < nt) {
      float av;
      if (t < deg) {
        sv = sperm[s0 + t];
        av = hs[sv] + hdi + escl[s0 + t];
      } else {
        av = hs[i] + hdi + esl[i];
      }
      av = (av > 0.f) ? av : 0.2f * av;
      w = __expf(av);
      den_l += w;
    }
    // phase B: pure row-gather stream; w/src broadcast from registers
    int cnt = nt - base;
    if (cnt > 64) cnt = 64;
    for (int q = g; q < cnt; q += 4) {
      float wq = __shfl(w, q, 64);
      int sq = __shfl(sv, q, 64);
      ushort8_t hv = *(const ushort8_t*)(hb + (size_t)sq * HID + j * 8);
      acc0.x += wq * bf2f(hv[0]);
      acc0.y += wq * bf2f(hv[1]);
      acc0.z += wq * bf2f(hv[2]);
      acc0.w += wq * bf2f(hv[3]);
      acc1.x += wq * bf2f(hv[4]);
      acc1.y += wq * bf2f(hv[5]);
      acc1.z += wq * bf2f(hv[6]);
      acc1.w += wq * bf2f(hv[7]);
    }
  }
  // den: reduce over all 64 lanes (each edge counted once)
#pragma unroll
  for (int o = 1; o < 64; o <<= 1) den_l += __shfl_xor(den_l, o, 64);
  // acc: reduce across the 4 groups
#pragma unroll
  for (int o = 16; o <= 32; o <<= 1) {
    acc0.x += __shfl_xor(acc0.x, o, 64);
    acc0.y += __shfl_xor(acc0.y, o, 64);
    acc0.z += __shfl_xor(acc0.z, o, 64);
    acc0.w += __shfl_xor(acc0.w, o, 64);
    acc1.x += __shfl_xor(acc1.x, o, 64);
    acc1.y += __shfl_xor(acc1.y, o, 64);
    acc1.z += __shfl_xor(acc1.z, o, 64);
    acc1.w += __shfl_xor(acc1.w, o, 64);
  }
  if (g == 0) {
    float inv = 1.f / den_l;
    const float4* bp = (const float4*)(bias + j * 8);
    float4 b0 = bp[0], b1 = bp[1];
    float v[8];
    v[0] = acc0.x * inv + b0.x; v[1] = acc0.y * inv + b0.y;
    v[2] = acc0.z * inv + b0.z; v[3] = acc0.w * inv + b0.w;
    v[4] = acc1.x * inv + b1.x; v[5] = acc1.y * inv + b1.y;
    v[6] = acc1.z * inv + b1.z; v[7] = acc1.w * inv + b1.w;
    ushort8_t ob;
#pragma unroll
    for (int q = 0; q < 8; ++q) {
      float t = v[q];
      if (act) t = (t > 0.f) ? t : 0.01f * t;
      ob[q] = f2bf(t);
    }
    *(ushort8_t*)(outb + (size_t)i * HID + j * 8) = ob;
  }
}

// ---------------- virtual-node MLP ----------------

__global__ void k_mlp(const float* __restrict__ vnsum, const float* __restrict__ vn_w,
                      const float* __restrict__ w1, const float* __restrict__ b1,
                      const float* __restrict__ w2, const float* __restrict__ b2,
                      const float* __restrict__ w3, const float* __restrict__ b3,
                      const float* __restrict__ w4, const float* __restrict__ b4,
                      float* __restrict__ outv) {
  __shared__ float xb[HID], yb[HID];
  int t = threadIdx.x;
  xb[t] = vnsum[t] + vn_w[t];
  __syncthreads();
  const float* Ws[4] = {w1, w2, w3, w4};
  const float* Bs[4] = {b1, b2, b3, b4};
  float* cur = xb;
  float* nxt = yb;
  for (int l = 0; l < 4; ++l) {
    const float* W = Ws[l];
    const float* B = Bs[l];
    float acc = B[t];
    for (int d = 0; d < HID; ++d) acc += cur[d] * W[d * HID + t];
    nxt[t] = fmaxf(acc, 0.f);
    __syncthreads();
    float* tmp = cur; cur = nxt; nxt = tmp;
  }
  outv[t] = cur[t];
}

// ---------------- launch ----------------

extern "C" void kernel_launch(void* const* d_in, const int* in_sizes, int n_in,
                              void* d_out, int out_size, void* d_ws, size_t ws_size,
                              hipStream_t stream) {
  const float* x = (const float*)d_in[0];
  const int* ei = (const int*)d_in[1];
  const float* edge_attr = (const float*)d_in[2];
  const float *W[3], *as_[3], *ad_[3], *We[3], *ae[3], *bb[3];
  for (int l = 0; l < 3; ++l) {
    W[l]   = (const float*)d_in[3 + l * 6 + 0];
    as_[l] = (const float*)d_in[3 + l * 6 + 1];
    ad_[l] = (const float*)d_in[3 + l * 6 + 2];
    We[l]  = (const float*)d_in[3 + l * 6 + 3];
    ae[l]  = (const float*)d_in[3 + l * 6 + 4];
    bb[l]  = (const float*)d_in[3 + l * 6 + 5];
  }
  const float* vn_w = (const float*)d_in[21];
  const float* m1w1 = (const float*)d_in[22];
  const float* m1b1 = (const float*)d_in[23];
  const float* m1w2 = (const float*)d_in[24];
  const float* m1b2 = (const float*)d_in[25];
  const float* m2w1 = (const float*)d_in[26];
  const float* m2b1 = (const float*)d_in[27];
  const float* m2w2 = (const float*)d_in[28];
  const float* m2b2 = (const float*)d_in[29];
  const float* Wout = (const float*)d_in[30];
  const float* bout = (const float*)d_in[31];

  char* ws = (char*)d_ws;
  size_t o = 0;
  auto alloc = [&](size_t bytes) {
    o = (o + 255) & ~(size_t)255;
    void* p = ws + o;
    o += bytes;
    return p;
  };
  unsigned short* xb  = (unsigned short*)alloc((size_t)NN * HID * 2);
  unsigned short* hb  = (unsigned short*)alloc((size_t)NN * HID * 2);
  unsigned short* outb = (unsigned short*)alloc((size_t)NN * HID * 2);
  unsigned short* Wtb = (unsigned short*)alloc((size_t)4 * HID * HID * 2);
  float4* esc4   = (float4*)alloc((size_t)EE * 16);
  float* esc_csr = (float*)alloc((size_t)3 * EE * 4);
  float* escself = (float*)alloc((size_t)3 * NN * 4);
  float* hs      = (float*)alloc((size_t)NN * 4);
  float* hd      = (float*)alloc((size_t)NN * 4);
  float* vnsum   = (float*)alloc(HID * 4);
  float* weae    = (float*)alloc(3 * ED * 4);
  int* cnt       = (int*)alloc((size_t)NN * 4);
  int* off       = (int*)alloc((size_t)(NN + 1) * 4);
  int* cursor    = (int*)alloc((size_t)NN * 4);
  int* sperm     = (int*)alloc((size_t)EE * 4);
  int* eid       = (int*)alloc((size_t)EE * 4);
  int* bsum      = (int*)alloc((size_t)SCAN_G * 4);
  int* bexc      = (int*)alloc((size_t)SCAN_G * 4);

  const int* srcv = ei;
  const int* dstv = ei + EE;

  k_zero<<<(NN + 255) / 256, 256, 0, stream>>>(cnt, vnsum);
  k_count<<<(EE + 255) / 256, 256, 0, stream>>>(dstv, cnt);
  k_scan1<<<SCAN_G, 256, 0, stream>>>(cnt, bsum);
  k_scan2<<<1, 256, 0, stream>>>(bsum, bexc, off);
  k_scan3<<<SCAN_G, 256, 0, stream>>>(cnt, bexc, off, cursor);
  k_scatter<<<(EE + 255) / 256, 256, 0, stream>>>(srcv, dstv, cursor, sperm, eid);
  k_weae<<<1, 256, 0, stream>>>(We[0], We[1], We[2], ae[0], ae[1], ae[2], weae);
  k_tobf<<<(NN * HID / 4 + 255) / 256, 256, 0, stream>>>(x, xb, NN * HID / 4);
  k_prepw<<<256, 256, 0, stream>>>(W[0], W[1], W[2], Wout, Wtb);
  k_esc_eo<<<(EE + 63) / 64, 256, 0, stream>>>(edge_attr, weae, esc4);
  k_permself<<<(NN + 15) / 16, 256, 0, stream>>>(off, eid, esc4, esc_csr,
                                                 escself);

  const unsigned short* in_b = xb;
  for (int l = 0; l < 3; ++l) {
    k_gemmA<<<(NN + 63) / 64, 256, 0, stream>>>(
        in_b, Wtb + (size_t)l * HID * HID, as_[l], ad_[l], hb, hs, hd);
    k_aggregate5<<<(NN + 3) / 4, 256, 0, stream>>>(
        hb, hs, hd, esc_csr + (size_t)l * EE, escself + (size_t)l * NN, sperm,
        off, bb[l], outb, (l > 0) ? 1 : 0);
    in_b = outb;
  }

  float* node_out = (float*)d_out;
  k_gemmO<<<(NN + 63) / 64, 256, 0, stream>>>(
      outb, Wtb + (size_t)3 * HID * HID, bout, node_out, vnsum);
  k_mlp<<<1, 128, 0, stream>>>(vnsum, vn_w, m1w1, m1b1, m1w2, m1b2, m2w1, m2b1,
                               m2w2, m2b2, node_out + (size_t)NN * HID);
}

// Round 12
// 276.498 us; speedup vs baseline: 3.1139x; 1.0405x over previous
//
#include <hip/hip_runtime.h>

#define NN 50000
#define EE 400000
#define HID 128
#define ED 64
#define SCAN_G 196  // ceil(50000/256)
#define LDP 136     // padded LDS row stride (bf16 elems)

typedef __attribute__((ext_vector_type(8))) unsigned short ushort8_t;
typedef __attribute__((ext_vector_type(8))) short short8_t;
typedef __attribute__((ext_vector_type(4))) float f32x4;

// bf16 pack/unpack (RNE; values are finite)
static __device__ __forceinline__ unsigned short f2bf(float f) {
  unsigned u = __float_as_uint(f);
  unsigned r = (u + 0x7FFFu + ((u >> 16) & 1u)) >> 16;
  return (unsigned short)r;
}
static __device__ __forceinline__ float bf2f(unsigned short b) {
  return __uint_as_float((unsigned)b << 16);
}

// exclusive prefix of v across 256 threads; s must hold >=256 ints.
static __device__ __forceinline__ int block_excl_scan_256(int v, int* s) {
  int tid = threadIdx.x;
  s[tid] = v;
  __syncthreads();
  for (int d = 1; d < 256; d <<= 1) {
    int t = (tid >= d) ? s[tid - d] : 0;
    __syncthreads();
    s[tid] += t;
    __syncthreads();
  }
  return s[tid] - v;
}

// ---------------- fused setup: tobf | zero | prepw | weae ----------------
// block ranges: [0,6250) tobf ; [6250,6446) zero ; [6446,6702) prepw ; 6702 weae

__global__ __launch_bounds__(256) void k_misc(
    const float* __restrict__ x, unsigned short* __restrict__ xb,
    int* __restrict__ cnt, float* __restrict__ vnsum,
    const float* __restrict__ W0, const float* __restrict__ W1,
    const float* __restrict__ W2, const float* __restrict__ Wo,
    unsigned short* __restrict__ Wt, const float* __restrict__ We0,
    const float* __restrict__ We1, const float* __restrict__ We2,
    const float* __restrict__ ae0, const float* __restrict__ ae1,
    const float* __restrict__ ae2, float* __restrict__ weae) {
  int b = blockIdx.x;
  int t = threadIdx.x;
  if (b < 6250) {  // x fp32 -> bf16 (1,600,000 float4s)
    int i = b * 256 + t;
    float4 v = ((const float4*)x)[i];
    ushort4 o;
    o.x = f2bf(v.x); o.y = f2bf(v.y); o.z = f2bf(v.z); o.w = f2bf(v.w);
    ((ushort4*)xb)[i] = o;
  } else if (b < 6446) {  // zero cnt + vnsum
    int i = (b - 6250) * 256 + t;
    if (i < NN) cnt[i] = 0;
    if (b == 6250 && t < HID) vnsum[t] = 0.f;
  } else if (b < 6702) {  // weights fp32 [K][N] -> bf16 [N][K]
    int idx = (b - 6446) * 256 + t;
    int m = idx >> 14;
    int rem = idx & 16383;
    int k = rem >> 7;
    int n = rem & 127;
    const float* W = (m == 0) ? W0 : (m == 1) ? W1 : (m == 2) ? W2 : Wo;
    Wt[(size_t)m * 16384 + n * 128 + k] = f2bf(W[k * 128 + n]);
  } else {  // weae
    if (t >= 192) return;
    int l = t >> 6, j = t & 63;
    const float* We = (l == 0) ? We0 : (l == 1) ? We1 : We2;
    const float* ae = (l == 0) ? ae0 : (l == 1) ? ae1 : ae2;
    float acc = 0.f;
    for (int k = 0; k < HID; ++k) acc += We[j * HID + k] * ae[k];
    weae[l * ED + j] = acc;
  }
}

// ---------------- CSR build ----------------

__global__ void k_count(const int* __restrict__ dst, int* __restrict__ cnt) {
  int e = blockIdx.x * blockDim.x + threadIdx.x;
  if (e < EE) atomicAdd(&cnt[dst[e]], 1);
}

__global__ __launch_bounds__(256) void k_scan1(const int* __restrict__ cnt,
                                               int* __restrict__ bsum) {
  __shared__ int s[256];
  int idx = blockIdx.x * 256 + threadIdx.x;
  int v = (idx < NN) ? cnt[idx] : 0;
  s[threadIdx.x] = v;
  __syncthreads();
  for (int d = 128; d > 0; d >>= 1) {
    if (threadIdx.x < d) s[threadIdx.x] += s[threadIdx.x + d];
    __syncthreads();
  }
  if (threadIdx.x == 0) bsum[blockIdx.x] = s[0];
}

__global__ __launch_bounds__(256) void k_scan2(const int* __restrict__ bsum,
                                               int* __restrict__ bexc,
                                               int* __restrict__ off) {
  __shared__ int s[256];
  int t = threadIdx.x;
  int v = (t < SCAN_G) ? bsum[t] : 0;
  int exc = block_excl_scan_256(v, s);
  if (t < SCAN_G) bexc[t] = exc;
  if (t == 255) off[NN] = s[255];
}

__global__ __launch_bounds__(256) void k_scan3(const int* __restrict__ cnt,
                                               const int* __restrict__ bexc,
                                               int* __restrict__ off,
                                               int* __restrict__ cursor) {
  __shared__ int s[256];
  int idx = blockIdx.x * 256 + threadIdx.x;
  int v = (idx < NN) ? cnt[idx] : 0;
  int exc = block_excl_scan_256(v, s) + bexc[blockIdx.x];
  if (idx < NN) {
    off[idx] = exc;
    cursor[idx] = exc;
  }
}

__global__ void k_scatter(const int* __restrict__ src, const int* __restrict__ dst,
                          int* __restrict__ cursor, int* __restrict__ sperm,
                          int* __restrict__ eid) {
  int e = blockIdx.x * blockDim.x + threadIdx.x;
  if (e < EE) {
    int p = atomicAdd(&cursor[dst[e]], 1);
    sperm[p] = src[e];
    eid[p] = e;
  }
}

// per-REAL-edge scalars in EDGE order, packed float4 {e0,e1,e2,0}.
__global__ __launch_bounds__(256) void k_esc_eo(
    const float* __restrict__ edge_attr, const float* __restrict__ weae,
    float4* __restrict__ esc4) {
  __shared__ float4 sw[3][16];
  int tid = threadIdx.x;
  if (tid < 48) ((float4*)sw)[tid] = ((const float4*)weae)[tid];
  __syncthreads();
  int c = tid & 15;
  int r0 = tid >> 4;
  float4 w0 = sw[0][c], w1 = sw[1][c], w2 = sw[2][c];
#pragma unroll
  for (int pass = 0; pass < 4; ++pass) {
    int row = blockIdx.x * 64 + pass * 16 + r0;
    if (row < EE) {
      float4 v = ((const float4*)edge_attr)[(size_t)row * 16 + c];
      float a0 = v.x * w0.x + v.y * w0.y + v.z * w0.z + v.w * w0.w;
      float a1 = v.x * w1.x + v.y * w1.y + v.z * w1.z + v.w * w1.w;
      float a2 = v.x * w2.x + v.y * w2.y + v.z * w2.z + v.w * w2.w;
#pragma unroll
      for (int o = 1; o < 16; o <<= 1) {
        a0 += __shfl_xor(a0, o, 64);
        a1 += __shfl_xor(a1, o, 64);
        a2 += __shfl_xor(a2, o, 64);
      }
      if (c == 0) esc4[row] = make_float4(a0, a1, a2, 0.f);
    }
  }
}

// permute esc to CSR planes + self-loop mean. 16-lane group per node.
__global__ __launch_bounds__(256) void k_permself(
    const int* __restrict__ off, const int* __restrict__ eid,
    const float4* __restrict__ esc4, float* __restrict__ esc_csr,
    float* __restrict__ escself) {
  int i = blockIdx.x * 16 + (threadIdx.x >> 4);
  int g = threadIdx.x & 15;
  if (i >= NN) return;
  int s0 = off[i], s1 = off[i + 1];
  float a0 = 0.f, a1 = 0.f, a2 = 0.f;
  for (int p = s0 + g; p < s1; p += 16) {
    float4 v = esc4[eid[p]];
    esc_csr[p] = v.x;
    esc_csr[(size_t)EE + p] = v.y;
    esc_csr[(size_t)2 * EE + p] = v.z;
    a0 += v.x;
    a1 += v.y;
    a2 += v.z;
  }
#pragma unroll
  for (int o = 8; o > 0; o >>= 1) {
    a0 += __shfl_xor(a0, o, 64);
    a1 += __shfl_xor(a1, o, 64);
    a2 += __shfl_xor(a2, o, 64);
  }
  if (g == 0) {
    int deg = s1 - s0;
    float inv = 1.f / (float)(deg > 1 ? deg : 1);
    escself[i] = a0 * inv;
    escself[(size_t)NN + i] = a1 * inv;
    escself[(size_t)2 * NN + i] = a2 * inv;
  }
}

// ---------------- MFMA GEMM (64 rows x 128 cols per block, 4 waves) --------

__global__ __launch_bounds__(256) void k_gemmA(
    const unsigned short* __restrict__ A, const unsigned short* __restrict__ Bt,
    const float* __restrict__ as_, const float* __restrict__ ad_,
    unsigned short* __restrict__ hb, float* __restrict__ hs,
    float* __restrict__ hd) {
  __shared__ unsigned short sA[64][LDP];
  __shared__ unsigned short sB[128][LDP];
  int tid = threadIdx.x;
  int row0 = blockIdx.x * 64;
  {
    int r = tid >> 2, sg = (tid & 3) * 32;
    int grow = row0 + r;
    const ushort8_t* src = (const ushort8_t*)(A + (size_t)grow * HID + sg);
    ushort8_t z = {0, 0, 0, 0, 0, 0, 0, 0};
#pragma unroll
    for (int i = 0; i < 4; ++i)
      *(ushort8_t*)&sA[r][sg + i * 8] = (grow < NN) ? src[i] : z;
  }
  {
    int r = tid >> 1, sg = (tid & 1) * 64;
    const ushort8_t* src = (const ushort8_t*)(Bt + r * HID + sg);
#pragma unroll
    for (int i = 0; i < 8; ++i) *(ushort8_t*)&sB[r][sg + i * 8] = src[i];
  }
  __syncthreads();
  int w = tid >> 6, l = tid & 63;
  int lr = l & 15, lg = l >> 4;
  f32x4 acc[8] = {};
  const unsigned short* pa = &sA[w * 16 + lr][lg * 8];
  const unsigned short* pb = &sB[lr][lg * 8];
#pragma unroll
  for (int ks = 0; ks < 4; ++ks) {
    short8_t a = *(const short8_t*)(pa + ks * 32);
#pragma unroll
    for (int ct = 0; ct < 8; ++ct) {
      short8_t b = *(const short8_t*)(pb + ct * 16 * LDP + ks * 32);
      acc[ct] = __builtin_amdgcn_mfma_f32_16x16x32_bf16(a, b, acc[ct], 0, 0, 0);
    }
  }
  int orow = row0 + w * 16 + lg * 4;
#pragma unroll
  for (int ct = 0; ct < 8; ++ct) {
    int col = ct * 16 + lr;
#pragma unroll
    for (int r = 0; r < 4; ++r) {
      int grow = orow + r;
      if (grow < NN) hb[(size_t)grow * HID + col] = f2bf(acc[ct][r]);
    }
  }
  float asv[8], adv[8];
#pragma unroll
  for (int ct = 0; ct < 8; ++ct) {
    asv[ct] = as_[ct * 16 + lr];
    adv[ct] = ad_[ct * 16 + lr];
  }
#pragma unroll
  for (int r = 0; r < 4; ++r) {
    float ps = 0.f, pd = 0.f;
#pragma unroll
    for (int ct = 0; ct < 8; ++ct) {
      ps += acc[ct][r] * asv[ct];
      pd += acc[ct][r] * adv[ct];
    }
#pragma unroll
    for (int o = 1; o < 16; o <<= 1) {
      ps += __shfl_xor(ps, o, 64);
      pd += __shfl_xor(pd, o, 64);
    }
    int grow = orow + r;
    if (lr == 0 && grow < NN) {
      hs[grow] = ps;
      hd[grow] = pd;
    }
  }
}

__global__ __launch_bounds__(256) void k_gemmO(
    const unsigned short* __restrict__ A, const unsigned short* __restrict__ Bt,
    const float* __restrict__ bias, float* __restrict__ O,
    float* __restrict__ vnsum) {
  __shared__ unsigned short sA[64][LDP];
  __shared__ unsigned short sB[128][LDP];
  int tid = threadIdx.x;
  int row0 = blockIdx.x * 64;
  {
    int r = tid >> 2, sg = (tid & 3) * 32;
    int grow = row0 + r;
    const ushort8_t* src = (const ushort8_t*)(A + (size_t)grow * HID + sg);
    ushort8_t z = {0, 0, 0, 0, 0, 0, 0, 0};
#pragma unroll
    for (int i = 0; i < 4; ++i)
      *(ushort8_t*)&sA[r][sg + i * 8] = (grow < NN) ? src[i] : z;
  }
  {
    int r = tid >> 1, sg = (tid & 1) * 64;
    const ushort8_t* src = (const ushort8_t*)(Bt + r * HID + sg);
#pragma unroll
    for (int i = 0; i < 8; ++i) *(ushort8_t*)&sB[r][sg + i * 8] = src[i];
  }
  __syncthreads();
  int w = tid >> 6, l = tid & 63;
  int lr = l & 15, lg = l >> 4;
  f32x4 acc[8] = {};
  const unsigned short* pa = &sA[w * 16 + lr][lg * 8];
  const unsigned short* pb = &sB[lr][lg * 8];
#pragma unroll
  for (int ks = 0; ks < 4; ++ks) {
    short8_t a = *(const short8_t*)(pa + ks * 32);
#pragma unroll
    for (int ct = 0; ct < 8; ++ct) {
      short8_t b = *(const short8_t*)(pb + ct * 16 * LDP + ks * 32);
      acc[ct] = __builtin_amdgcn_mfma_f32_16x16x32_bf16(a, b, acc[ct], 0, 0, 0);
    }
  }
  int orow = row0 + w * 16 + lg * 4;
#pragma unroll
  for (int ct = 0; ct < 8; ++ct) {
    int col = ct * 16 + lr;
    float bv = bias[col];
#pragma unroll
    for (int r = 0; r < 4; ++r) {
      int grow = orow + r;
      if (grow < NN) O[(size_t)grow * HID + col] = acc[ct][r] + bv;
    }
  }
  if (tid < HID) {
    float s = 0.f;
#pragma unroll
    for (int r = 0; r < 64; ++r) s += bf2f(sA[r][tid]);
    atomicAdd(&vnsum[tid], s);
  }
}

// ------- aggregate: parallel alpha + software-pipelined gather stream ------

__global__ __launch_bounds__(256) void k_aggregate6(
    const unsigned short* __restrict__ hb, const float* __restrict__ hs,
    const float* __restrict__ hd, const float* __restrict__ escl,
    const float* __restrict__ esl, const int* __restrict__ sperm,
    const int* __restrict__ off, const float* __restrict__ bias,
    unsigned short* __restrict__ outb, int act) {
  int i = blockIdx.x * 4 + (threadIdx.x >> 6);
  int lane = threadIdx.x & 63;
  if (i >= NN) return;
  int g = lane >> 4;
  int j = lane & 15;
  int s0 = off[i];
  int deg = off[i + 1] - s0;
  int nt = deg + 1;  // + self-loop
  float hdi = hd[i];
  float den_l = 0.f;
  float4 acc0 = make_float4(0.f, 0.f, 0.f, 0.f);
  float4 acc1 = make_float4(0.f, 0.f, 0.f, 0.f);
  for (int base = 0; base < nt; base += 64) {
    // phase A: all lanes compute w for edge (base+lane) in parallel
    int t = base + lane;
    int sv = i;
    float w = 0.f;
    if (t < nt) {
      float av;
      if (t < deg) {
        sv = sperm[s0 + t];
        av = hs[sv] + hdi + escl[s0 + t];
      } else {
        av = hs[i] + hdi + esl[i];
      }
      av = (av > 0.f) ? av : 0.2f * av;
      w = __expf(av);
      den_l += w;
    }
    // phase B: pipelined row-gather stream (prefetch next before accumulate)
    int cnt2 = nt - base;
    if (cnt2 > 64) cnt2 = 64;
    int q = g;
    if (q < cnt2) {
      float wq = __shfl(w, q, 64);
      int sq = __shfl(sv, q, 64);
      ushort8_t hv = *(const ushort8_t*)(hb + (size_t)sq * HID + j * 8);
      for (int qn = q + 4; qn < cnt2; qn += 4) {
        float wn = __shfl(w, qn, 64);
        int sn = __shfl(sv, qn, 64);
        ushort8_t hn = *(const ushort8_t*)(hb + (size_t)sn * HID + j * 8);
        acc0.x += wq * bf2f(hv[0]);
        acc0.y += wq * bf2f(hv[1]);
        acc0.z += wq * bf2f(hv[2]);
        acc0.w += wq * bf2f(hv[3]);
        acc1.x += wq * bf2f(hv[4]);
        acc1.y += wq * bf2f(hv[5]);
        acc1.z += wq * bf2f(hv[6]);
        acc1.w += wq * bf2f(hv[7]);
        wq = wn;
        hv = hn;
      }
      acc0.x += wq * bf2f(hv[0]);
      acc0.y += wq * bf2f(hv[1]);
      acc0.z += wq * bf2f(hv[2]);
      acc0.w += wq * bf2f(hv[3]);
      acc1.x += wq * bf2f(hv[4]);
      acc1.y += wq * bf2f(hv[5]);
      acc1.z += wq * bf2f(hv[6]);
      acc1.w += wq * bf2f(hv[7]);
    }
  }
  // den: reduce over all 64 lanes (each edge counted once)
#pragma unroll
  for (int o = 1; o < 64; o <<= 1) den_l += __shfl_xor(den_l, o, 64);
  // acc: reduce across the 4 groups
#pragma unroll
  for (int o = 16; o <= 32; o <<= 1) {
    acc0.x += __shfl_xor(acc0.x, o, 64);
    acc0.y += __shfl_xor(acc0.y, o, 64);
    acc0.z += __shfl_xor(acc0.z, o, 64);
    acc0.w += __shfl_xor(acc0.w, o, 64);
    acc1.x += __shfl_xor(acc1.x, o, 64);
    acc1.y += __shfl_xor(acc1.y, o, 64);
    acc1.z += __shfl_xor(acc1.z, o, 64);
    acc1.w += __shfl_xor(acc1.w, o, 64);
  }
  if (g == 0) {
    float inv = 1.f / den_l;
    const float4* bp = (const float4*)(bias + j * 8);
    float4 b0 = bp[0], b1 = bp[1];
    float v[8];
    v[0] = acc0.x * inv + b0.x; v[1] = acc0.y * inv + b0.y;
    v[2] = acc0.z * inv + b0.z; v[3] = acc0.w * inv + b0.w;
    v[4] = acc1.x * inv + b1.x; v[5] = acc1.y * inv + b1.y;
    v[6] = acc1.z * inv + b1.z; v[7] = acc1.w * inv + b1.w;
    ushort8_t ob;
#pragma unroll
    for (int q = 0; q < 8; ++q) {
      float t = v[q];
      if (act) t = (t > 0.f) ? t : 0.01f * t;
      ob[q] = f2bf(t);
    }
    *(ushort8_t*)(outb + (size_t)i * HID + j * 8) = ob;
  }
}

// ---------------- virtual-node MLP ----------------

__global__ void k_mlp(const float* __restrict__ vnsum, const float* __restrict__ vn_w,
                      const float* __restrict__ w1, const float* __restrict__ b1,
                      const float* __restrict__ w2, const float* __restrict__ b2,
                      const float* __restrict__ w3, const float* __restrict__ b3,
                      const float* __restrict__ w4, const float* __restrict__ b4,
                      float* __restrict__ outv) {
  __shared__ float xb[HID], yb[HID];
  int t = threadIdx.x;
  xb[t] = vnsum[t] + vn_w[t];
  __syncthreads();
  const float* Ws[4] = {w1, w2, w3, w4};
  const float* Bs[4] = {b1, b2, b3, b4};
  float* cur = xb;
  float* nxt = yb;
  for (int l = 0; l < 4; ++l) {
    const float* W = Ws[l];
    const float* B = Bs[l];
    float acc = B[t];
    for (int d = 0; d < HID; ++d) acc += cur[d] * W[d * HID + t];
    nxt[t] = fmaxf(acc, 0.f);
    __syncthreads();
    float* tmp = cur; cur = nxt; nxt = tmp;
  }
  outv[t] = cur[t];
}

// ---------------- launch ----------------

extern "C" void kernel_launch(void* const* d_in, const int* in_sizes, int n_in,
                              void* d_out, int out_size, void* d_ws, size_t ws_size,
                              hipStream_t stream) {
  const float* x = (const float*)d_in[0];
  const int* ei = (const int*)d_in[1];
  const float* edge_attr = (const float*)d_in[2];
  const float *W[3], *as_[3], *ad_[3], *We[3], *ae[3], *bb[3];
  for (int l = 0; l < 3; ++l) {
    W[l]   = (const float*)d_in[3 + l * 6 + 0];
    as_[l] = (const float*)d_in[3 + l * 6 + 1];
    ad_[l] = (const float*)d_in[3 + l * 6 + 2];
    We[l]  = (const float*)d_in[3 + l * 6 + 3];
    ae[l]  = (const float*)d_in[3 + l * 6 + 4];
    bb[l]  = (const float*)d_in[3 + l * 6 + 5];
  }
  const float* vn_w = (const float*)d_in[21];
  const float* m1w1 = (const float*)d_in[22];
  const float* m1b1 = (const float*)d_in[23];
  const float* m1w2 = (const float*)d_in[24];
  const float* m1b2 = (const float*)d_in[25];
  const float* m2w1 = (const float*)d_in[26];
  const float* m2b1 = (const float*)d_in[27];
  const float* m2w2 = (const float*)d_in[28];
  const float* m2b2 = (const float*)d_in[29];
  const float* Wout = (const float*)d_in[30];
  const float* bout = (const float*)d_in[31];

  char* ws = (char*)d_ws;
  size_t o = 0;
  auto alloc = [&](size_t bytes) {
    o = (o + 255) & ~(size_t)255;
    void* p = ws + o;
    o += bytes;
    return p;
  };
  unsigned short* xb  = (unsigned short*)alloc((size_t)NN * HID * 2);
  unsigned short* hb  = (unsigned short*)alloc((size_t)NN * HID * 2);
  unsigned short* outb = (unsigned short*)alloc((size_t)NN * HID * 2);
  unsigned short* Wtb = (unsigned short*)alloc((size_t)4 * HID * HID * 2);
  float4* esc4   = (float4*)alloc((size_t)EE * 16);
  float* esc_csr = (float*)alloc((size_t)3 * EE * 4);
  float* escself = (float*)alloc((size_t)3 * NN * 4);
  float* hs      = (float*)alloc((size_t)NN * 4);
  float* hd      = (float*)alloc((size_t)NN * 4);
  float* vnsum   = (float*)alloc(HID * 4);
  float* weae    = (float*)alloc(3 * ED * 4);
  int* cnt       = (int*)alloc((size_t)NN * 4);
  int* off       = (int*)alloc((size_t)(NN + 1) * 4);
  int* cursor    = (int*)alloc((size_t)NN * 4);
  int* sperm     = (int*)alloc((size_t)EE * 4);
  int* eid       = (int*)alloc((size_t)EE * 4);
  int* bsum      = (int*)alloc((size_t)SCAN_G * 4);
  int* bexc      = (int*)alloc((size_t)SCAN_G * 4);

  const int* srcv = ei;
  const int* dstv = ei + EE;

  k_misc<<<6703, 256, 0, stream>>>(x, xb, cnt, vnsum, W[0], W[1], W[2], Wout,
                                   Wtb, We[0], We[1], We[2], ae[0], ae[1],
                                   ae[2], weae);
  k_count<<<(EE + 255) / 256, 256, 0, stream>>>(dstv, cnt);
  k_scan1<<<SCAN_G, 256, 0, stream>>>(cnt, bsum);
  k_scan2<<<1, 256, 0, stream>>>(bsum, bexc, off);
  k_scan3<<<SCAN_G, 256, 0, stream>>>(cnt, bexc, off, cursor);
  k_scatter<<<(EE + 255) / 256, 256, 0, stream>>>(srcv, dstv, cursor, sperm, eid);
  k_esc_eo<<<(EE + 63) / 64, 256, 0, stream>>>(edge_attr, weae, esc4);
  k_permself<<<(NN + 15) / 16, 256, 0, stream>>>(off, eid, esc4, esc_csr,
                                                 escself);

  const unsigned short* in_b = xb;
  for (int l = 0; l < 3; ++l) {
    k_gemmA<<<(NN + 63) / 64, 256, 0, stream>>>(
        in_b, Wtb + (size_t)l * HID * HID, as_[l], ad_[l], hb, hs, hd);
    k_aggregate6<<<(NN + 3) / 4, 256, 0, stream>>>(
        hb, hs, hd, esc_csr + (size_t)l * EE, escself + (size_t)l * NN, sperm,
        off, bb[l], outb, (l > 0) ? 1 : 0);
    in_b = outb;
  }

  float* node_out = (float*)d_out;
  k_gemmO<<<(NN + 63) / 64, 256, 0, stream>>>(
      outb, Wtb + (size_t)3 * HID * HID, bout, node_out, vnsum);
  k_mlp<<<1, 128, 0, stream>>>(vnsum, vn_w, m1w1, m1b1, m1w2, m1b2, m2w1, m2b1,
                               m2w2, m2b2, node_out + (size_t)NN * HID);
}